// Round 6
// baseline (3798.659 us; speedup 1.0000x reference)
//
#include <hip/hip_runtime.h>
#include <hip/hip_bf16.h>
#include <math.h>

// NOTE: resubmission — rounds 4/5 hit a dead container ("connection closed
// while sending first message", no timing block); this source never ran.

typedef __attribute__((ext_vector_type(8))) unsigned short u16x8;
typedef __attribute__((ext_vector_type(4))) unsigned short u16x4;

__device__ __forceinline__ float b2f(unsigned short u) {
    return __uint_as_float(((unsigned)u) << 16);
}

// ---------- generic loaders for GEMM ----------
__device__ __forceinline__ float4 ld4(const float* p) { return *(const float4*)p; }
__device__ __forceinline__ float4 ld4(const __hip_bfloat16* p) {
    u16x4 u = *(const u16x4*)p;
    return make_float4(b2f(u[0]), b2f(u[1]), b2f(u[2]), b2f(u[3]));
}
__device__ __forceinline__ void st4(float* p, float4 v) { *(float4*)p = v; }
__device__ __forceinline__ void st4(__hip_bfloat16* p, float4 v) {
    p[0] = __float2bfloat16(v.x); p[1] = __float2bfloat16(v.y);
    p[2] = __float2bfloat16(v.z); p[3] = __float2bfloat16(v.w);
}

// ---------- tiled GEMM: out[r][c] = sum_k A[r][k]*W[k][c], K=C=128 ----------
template <typename TA, typename TO>
__global__ __launch_bounds__(256) void gemm_t(const TA* __restrict__ A,
                                              const float* __restrict__ W,
                                              TO* __restrict__ out, int n_rows)
{
    __shared__ float a_sh[64][68];
    __shared__ float b_sh[64][64];
    const int tid = threadIdx.x;
    const int row0 = blockIdx.x * 64;
    const int cb   = blockIdx.y * 64;
    const int tr = (tid >> 4) * 4;
    const int tc = (tid & 15) * 4;
    float acc[4][4] = {};
    for (int kh = 0; kh < 2; ++kh) {
        __syncthreads();
        for (int i = 0; i < 4; ++i) {
            int f = tid + i * 256;
            int r = f >> 4, c4 = (f & 15) * 4;
            float4 v = make_float4(0.f, 0.f, 0.f, 0.f);
            if (row0 + r < n_rows)
                v = ld4(A + (size_t)(row0 + r) * 128 + kh * 64 + c4);
            *(float4*)&a_sh[r][c4] = v;
        }
        for (int i = 0; i < 4; ++i) {
            int f = tid + i * 256;
            int k = f >> 4, c4 = (f & 15) * 4;
            *(float4*)&b_sh[k][c4] = *(const float4*)(W + (size_t)(kh * 64 + k) * 128 + cb + c4);
        }
        __syncthreads();
        #pragma unroll
        for (int k4 = 0; k4 < 16; ++k4) {
            float4 a[4], b[4];
            #pragma unroll
            for (int i = 0; i < 4; ++i) a[i] = *(float4*)&a_sh[tr + i][k4 * 4];
            #pragma unroll
            for (int kk = 0; kk < 4; ++kk) b[kk] = *(float4*)&b_sh[k4 * 4 + kk][tc];
            #pragma unroll
            for (int i = 0; i < 4; ++i) {
                const float av[4] = {a[i].x, a[i].y, a[i].z, a[i].w};
                #pragma unroll
                for (int kk = 0; kk < 4; ++kk) {
                    acc[i][0] = fmaf(av[kk], b[kk].x, acc[i][0]);
                    acc[i][1] = fmaf(av[kk], b[kk].y, acc[i][1]);
                    acc[i][2] = fmaf(av[kk], b[kk].z, acc[i][2]);
                    acc[i][3] = fmaf(av[kk], b[kk].w, acc[i][3]);
                }
            }
        }
    }
    for (int i = 0; i < 4; ++i) {
        int r = row0 + tr + i;
        if (r < n_rows)
            st4(out + (size_t)r * 128 + cb + tc,
                make_float4(acc[i][0], acc[i][1], acc[i][2], acc[i][3]));
    }
}

// ---------- histogram / scan / fill machinery ----------
__global__ __launch_bounds__(256) void bin_count(const int* __restrict__ keys,
                                                 unsigned* __restrict__ cnt, int n)
{
    int i = blockIdx.x * 256 + threadIdx.x;
    if (i < n) atomicAdd(&cnt[keys[i]], 1u);
}

__global__ __launch_bounds__(256) void bin_count_m1(const int* __restrict__ keys,
                                                    unsigned* __restrict__ cnt, int n)
{
    int i = blockIdx.x * 256 + threadIdx.x;
    if (i < n) atomicAdd(&cnt[keys[i] - 1], 1u);
}

__global__ __launch_bounds__(1024) void scan1(const unsigned* __restrict__ in,
                                              unsigned* __restrict__ out,
                                              unsigned* __restrict__ bsum, int n)
{
    __shared__ unsigned sh[1024];
    int i = blockIdx.x * 1024 + threadIdx.x;
    unsigned v = (i < n) ? in[i] : 0u;
    sh[threadIdx.x] = v;
    __syncthreads();
    for (int off = 1; off < 1024; off <<= 1) {
        unsigned t = (threadIdx.x >= (unsigned)off) ? sh[threadIdx.x - off] : 0u;
        __syncthreads();
        sh[threadIdx.x] += t;
        __syncthreads();
    }
    if (i < n) out[i] = sh[threadIdx.x] - v;  // exclusive
    if (threadIdx.x == 1023) bsum[blockIdx.x] = sh[1023];
}

__global__ __launch_bounds__(1024) void scan2(unsigned* __restrict__ bsum, int nb)
{
    __shared__ unsigned sh[1024];
    unsigned v = (threadIdx.x < (unsigned)nb) ? bsum[threadIdx.x] : 0u;
    sh[threadIdx.x] = v;
    __syncthreads();
    for (int off = 1; off < 1024; off <<= 1) {
        unsigned t = (threadIdx.x >= (unsigned)off) ? sh[threadIdx.x - off] : 0u;
        __syncthreads();
        sh[threadIdx.x] += t;
        __syncthreads();
    }
    if (threadIdx.x < (unsigned)nb) bsum[threadIdx.x] = sh[threadIdx.x] - v;
}

__global__ __launch_bounds__(1024) void scan3(unsigned* __restrict__ out,
                                              const unsigned* __restrict__ bsum, int n)
{
    int i = blockIdx.x * 1024 + threadIdx.x;
    if (i < n) out[i] += bsum[blockIdx.x];
}

__global__ __launch_bounds__(256) void fill_user(const int* __restrict__ rows,
                                                 const int* __restrict__ cols,
                                                 const float* __restrict__ vals,
                                                 unsigned* __restrict__ cursor,
                                                 int* __restrict__ pcol,
                                                 float* __restrict__ pval, int n)
{
    int i = blockIdx.x * 256 + threadIdx.x;
    if (i >= n) return;
    unsigned p = atomicAdd(&cursor[rows[i]], 1u);
    pcol[p] = cols[i];
    pval[p] = vals[i];
}

__global__ __launch_bounds__(256) void fill_edge_islot(const int* __restrict__ keys,
                                                       unsigned* __restrict__ cursor,
                                                       int* __restrict__ islot, int n)
{
    int i = blockIdx.x * 256 + threadIdx.x;
    if (i >= n) return;
    unsigned p = atomicAdd(&cursor[keys[i]], 1u);
    islot[i] = (int)p;
}

__global__ __launch_bounds__(256) void fill_rel(const int* __restrict__ head,
                                                const int* __restrict__ tail,
                                                const int* __restrict__ etyp,
                                                const int* __restrict__ islot,
                                                unsigned* __restrict__ rcur,
                                                int4* __restrict__ emeta, int n)
{
    int i = blockIdx.x * 256 + threadIdx.x;
    if (i >= n) return;
    int r = etyp[i] - 1;
    unsigned p = atomicAdd(&rcur[r], 1u);
    emeta[p] = make_int4(head[i], tail[i], islot[i], r);
}

// ---------- score pass: rel-sorted edges, A in registers ----------
__global__ __launch_bounds__(256, 2) void score_pass(
    const __hip_bfloat16* __restrict__ Qb, const __hip_bfloat16* __restrict__ Kb,
    const float* __restrict__ att, const int4* __restrict__ emeta,
    float* __restrict__ SC, int E, int chunk)
{
    const int wave = (blockIdx.x * 256 + threadIdx.x) >> 6;
    const int l = threadIdx.x & 63;
    const int kk = l & 31;
    const int half = l >> 5;
    long j0 = (long)wave * chunk;
    if (j0 >= E) return;
    long j1 = j0 + chunk; if (j1 > E) j1 = E;

    float Areg[2][32];
    int currel = -1;
    for (long j = j0; j < j1; ++j) {
        const int4 md = emeta[j];
        const int hn = md.x, tn = md.y, slot = md.z, rel = md.w;
        if (rel != currel) {
            currel = rel;
            #pragma unroll
            for (int s = 0; s < 2; ++s) {
                const float* Ah = att + (size_t)rel * 4096 + (s * 2 + half) * 1024 + kk;
                #pragma unroll
                for (int d = 0; d < 32; ++d) Areg[s][d] = Ah[d * 32];
            }
        }
        #pragma unroll
        for (int s = 0; s < 2; ++s) {
            const int h = s * 2 + half;
            const __hip_bfloat16* kr = Kb + (size_t)tn * 128 + h * 32;
            float kp = 0.f;
            #pragma unroll
            for (int q = 0; q < 4; ++q) {
                u16x8 v8 = *(const u16x8*)(kr + q * 8);
                #pragma unroll
                for (int t = 0; t < 8; ++t) kp = fmaf(b2f(v8[t]), Areg[s][q * 8 + t], kp);
            }
            float qv = __bfloat162float(Qb[(size_t)hn * 128 + h * 32 + kk]);
            float p = kp * qv;
            #pragma unroll
            for (int off = 16; off >= 1; off >>= 1) p += __shfl_xor(p, off, 64);
            if (kk == 0) SC[(size_t)slot * 4 + h] = p * 0.17677669529663687f;
        }
    }
}

// ---------- msg pass (per head-pair ROUND): V' into slot order ----------
template <int ROUND>
__global__ __launch_bounds__(256, 2) void msg_pass(
    const __hip_bfloat16* __restrict__ Vb, const float* __restrict__ msg,
    const int4* __restrict__ emeta, __hip_bfloat16* __restrict__ VPh,
    int E, int chunk)
{
    const int wave = (blockIdx.x * 256 + threadIdx.x) >> 6;
    const int l = threadIdx.x & 63;
    const int kk = l & 31;
    const int half = l >> 5;
    const int h = ROUND * 2 + half;
    long j0 = (long)wave * chunk;
    if (j0 >= E) return;
    long j1 = j0 + chunk; if (j1 > E) j1 = E;

    float Mreg[32];
    int currel = -1;
    for (long j = j0; j < j1; ++j) {
        const int4 md = emeta[j];
        const int tn = md.y, slot = md.z, rel = md.w;
        if (rel != currel) {
            currel = rel;
            const float* Mh = msg + (size_t)rel * 4096 + h * 1024 + kk;
            #pragma unroll
            for (int d = 0; d < 32; ++d) Mreg[d] = Mh[d * 32];
        }
        const __hip_bfloat16* vr = Vb + (size_t)tn * 128 + h * 32;
        float vp = 0.f;
        #pragma unroll
        for (int q = 0; q < 4; ++q) {
            u16x8 v8 = *(const u16x8*)(vr + q * 8);
            #pragma unroll
            for (int t = 0; t < 8; ++t) vp = fmaf(b2f(v8[t]), Mreg[q * 8 + t], vp);
        }
        VPh[(size_t)slot * 64 + l] = __float2bfloat16(vp);
    }
}

// ---------- node pass (per head-pair ROUND): softmax + accumulate ----------
template <int ROUND>
__global__ __launch_bounds__(256) void node_pass(
    const float* __restrict__ SC, const __hip_bfloat16* __restrict__ VPh,
    const unsigned* __restrict__ ecur, __hip_bfloat16* __restrict__ M, int n)
{
    int node = (blockIdx.x * 256 + threadIdx.x) >> 6;
    if (node >= n) return;
    int l = threadIdx.x & 63;
    int half = l >> 5;
    const int h = ROUND * 2 + half;
    unsigned beg = node ? ecur[node - 1] : 0u;
    unsigned end = ecur[node];
    float mx = -INFINITY;
    for (unsigned j = beg; j < end; ++j) mx = fmaxf(mx, SC[(size_t)j * 4 + h]);
    float dn = 0.f;
    for (unsigned j = beg; j < end; ++j) dn += __expf(SC[(size_t)j * 4 + h] - mx);
    float inv = (end > beg) ? 1.f / dn : 0.f;
    float acc = 0.f;
    for (unsigned j = beg; j < end; ++j) {
        float w = __expf(SC[(size_t)j * 4 + h] - mx) * inv;
        acc = fmaf(w, __bfloat162float(VPh[(size_t)j * 64 + l]), acc);
    }
    M[(size_t)node * 128 + ROUND * 64 + l] = __float2bfloat16(acc);
}

// ---------- per-user gather ----------
__global__ __launch_bounds__(256) void user_gather(
    const float* __restrict__ emb, const unsigned* __restrict__ ucur,
    const int* __restrict__ pcol, const float* __restrict__ pval,
    float* __restrict__ out, int nu)
{
    int u = (blockIdx.x * 256 + threadIdx.x) >> 6;
    if (u >= nu) return;
    int l = threadIdx.x & 63;
    unsigned beg = u ? ucur[u - 1] : 0u;
    unsigned end = ucur[u];
    float a0 = 0.f, a1 = 0.f;
    for (unsigned j = beg; j < end; ++j) {
        int c = pcol[j];
        float v = pval[j];
        float2 e = *(const float2*)(emb + (size_t)c * 128 + l * 2);
        a0 = fmaf(e.x, v, a0);
        a1 = fmaf(e.y, v, a1);
    }
    *(float2*)(out + (size_t)u * 128 + l * 2) = make_float2(a0, a1);
}

extern "C" void kernel_launch(void* const* d_in, const int* in_sizes, int n_in,
                              void* d_out, int out_size, void* d_ws, size_t ws_size,
                              hipStream_t stream)
{
    const float* emb = (const float*)d_in[0];
    const float* W_Q = (const float*)d_in[1];
    const float* W_K = (const float*)d_in[2];
    const float* W_V = (const float*)d_in[3];
    const float* W_O = (const float*)d_in[4];
    const float* att = (const float*)d_in[5];
    const float* msg = (const float*)d_in[6];
    const int* eidx  = (const int*)d_in[8];
    const int* etyp  = (const int*)d_in[9];
    const int* irow  = (const int*)d_in[10];
    const int* icol  = (const int*)d_in[11];
    const float* ival = (const float*)d_in[12];

    const int N    = in_sizes[0] / 128;
    const int E    = in_sizes[8] / 2;
    const int NNZ  = in_sizes[10];
    const int NU   = out_size / 128 - N;
    const int NREL = in_sizes[5] / 4096;   // = NREL-1 actual relation slots

    const int* head = eidx;
    const int* tail = eidx + E;

    // ---- workspace layout (155.8 MB total; proven capacity >= 163.2 MB) ----
    const size_t NC = (size_t)N * 128;
    __hip_bfloat16* VPh = (__hip_bfloat16*)d_ws;          // E*64 bf16 (written after overlays die)
    __hip_bfloat16* Qb  = (__hip_bfloat16*)d_ws;          // N*128 bf16 (overlay in VPh region)
    __hip_bfloat16* Kb  = Qb + NC;                        // N*128 bf16 (overlay)
    int* islot          = (int*)(Kb + NC);                // E ints (overlay, dead after fill_rel)

    char* p = (char*)d_ws + (size_t)E * 64 * 2;
    __hip_bfloat16* Vb = (__hip_bfloat16*)p; p += NC * 2;           // N*128 bf16
    int4* emeta        = (int4*)p;           p += (size_t)E * 16;   // rel-sorted metadata
    float* SC          = (float*)p;          p += (size_t)E * 16;   // E*4 f32 scores
    unsigned* ecnt     = (unsigned*)p;       p += (size_t)N * 4;    // head-CSR offsets
    unsigned* rcnt     = (unsigned*)p;       p += 32 * 4;           // rel offsets
    unsigned* bsum     = (unsigned*)p;       p += 1024 * 4;         // scan scratch
    __hip_bfloat16* M  = (__hip_bfloat16*)p; p += NC * 2;           // N*128 bf16 aggregate
    unsigned* ucnt     = (unsigned*)p;       p += (size_t)((NU + 255) & ~255) * 4;
    unsigned* bsumU    = (unsigned*)p;       p += 1024 * 4;
    int* pcol          = (int*)p;            p += (size_t)NNZ * 4;
    float* pval        = (float*)p;          p += (size_t)NNZ * 4;

    float* out_ent = (float*)d_out;
    float* out_usr = out_ent + NC;

    hipMemsetAsync(ecnt, 0, (size_t)N * 4 + 32 * 4 + 1024 * 4, stream);
    hipMemsetAsync(ucnt, 0, (size_t)NU * 4, stream);

    // Q/K/V projections (f32 in, bf16 out)
    dim3 g_gemm((unsigned)((N + 63) / 64), 2);
    gemm_t<float, __hip_bfloat16><<<g_gemm, 256, 0, stream>>>(emb, W_Q, Qb, N);
    gemm_t<float, __hip_bfloat16><<<g_gemm, 256, 0, stream>>>(emb, W_K, Kb, N);
    gemm_t<float, __hip_bfloat16><<<g_gemm, 256, 0, stream>>>(emb, W_V, Vb, N);

    // head-CSR + rel-sorted metadata
    bin_count<<<(E + 255) / 256, 256, 0, stream>>>(head, ecnt, E);
    bin_count_m1<<<(E + 255) / 256, 256, 0, stream>>>(etyp, rcnt, E);
    scan1<<<1, 1024, 0, stream>>>(rcnt, rcnt, bsum, NREL);
    int nbE = (N + 1023) / 1024;
    scan1<<<nbE, 1024, 0, stream>>>(ecnt, ecnt, bsum, N);
    scan2<<<1, 1024, 0, stream>>>(bsum, nbE);
    scan3<<<nbE, 1024, 0, stream>>>(ecnt, bsum, N);
    fill_edge_islot<<<(E + 255) / 256, 256, 0, stream>>>(head, ecnt, islot, E);
    fill_rel<<<(E + 255) / 256, 256, 0, stream>>>(head, tail, etyp, islot, rcnt, emeta, E);
    // ecnt now holds end-boundaries per node

    const int NWAVE = 16384;
    int chunk = (E + NWAVE - 1) / NWAVE;
    score_pass<<<NWAVE / 4, 256, 0, stream>>>(Qb, Kb, att, emeta, SC, E, chunk);
    // Qb/Kb/islot dead -> VPh region free

    msg_pass<0><<<NWAVE / 4, 256, 0, stream>>>(Vb, msg, emeta, VPh, E, chunk);
    node_pass<0><<<(N + 3) / 4, 256, 0, stream>>>(SC, VPh, ecnt, M, N);
    msg_pass<1><<<NWAVE / 4, 256, 0, stream>>>(Vb, msg, emeta, VPh, E, chunk);
    node_pass<1><<<(N + 3) / 4, 256, 0, stream>>>(SC, VPh, ecnt, M, N);

    // entity output GEMM (bf16 A, f32 out)
    gemm_t<__hip_bfloat16, float><<<g_gemm, 256, 0, stream>>>(M, W_O, out_ent, N);

    // user aggregation via CSR gather
    bin_count<<<(NNZ + 255) / 256, 256, 0, stream>>>(irow, ucnt, NNZ);
    int nbU = (NU + 1023) / 1024;
    scan1<<<nbU, 1024, 0, stream>>>(ucnt, ucnt, bsumU, NU);
    scan2<<<1, 1024, 0, stream>>>(bsumU, nbU);
    scan3<<<nbU, 1024, 0, stream>>>(ucnt, bsumU, NU);
    fill_user<<<(NNZ + 255) / 256, 256, 0, stream>>>(irow, icol, ival, ucnt, pcol, pval, NNZ);
    user_gather<<<(NU + 3) / 4, 256, 0, stream>>>(emb, ucnt, pcol, pval, out_usr, NU);
}

// Round 7
// 1217.566 us; speedup vs baseline: 3.1199x; 3.1199x over previous
//
#include <hip/hip_runtime.h>
#include <hip/hip_bf16.h>
#include <math.h>

typedef __attribute__((ext_vector_type(8))) unsigned short u16x8;
typedef __attribute__((ext_vector_type(4))) unsigned short u16x4;

#define NRELMAX 32

__device__ __forceinline__ float b2f(unsigned short u) {
    return __uint_as_float(((unsigned)u) << 16);
}

// ---------- generic loaders for GEMM ----------
__device__ __forceinline__ float4 ld4(const float* p) { return *(const float4*)p; }
__device__ __forceinline__ float4 ld4(const __hip_bfloat16* p) {
    u16x4 u = *(const u16x4*)p;
    return make_float4(b2f(u[0]), b2f(u[1]), b2f(u[2]), b2f(u[3]));
}
__device__ __forceinline__ void st4(float* p, float4 v) { *(float4*)p = v; }
__device__ __forceinline__ void st4(__hip_bfloat16* p, float4 v) {
    p[0] = __float2bfloat16(v.x); p[1] = __float2bfloat16(v.y);
    p[2] = __float2bfloat16(v.z); p[3] = __float2bfloat16(v.w);
}

// ---------- tiled GEMM: out[r][c] = sum_k A[r][k]*W[k][c], K=C=128 ----------
template <typename TA, typename TO>
__global__ __launch_bounds__(256) void gemm_t(const TA* __restrict__ A,
                                              const float* __restrict__ W,
                                              TO* __restrict__ out, int n_rows)
{
    __shared__ float a_sh[64][68];
    __shared__ float b_sh[64][64];
    const int tid = threadIdx.x;
    const int row0 = blockIdx.x * 64;
    const int cb   = blockIdx.y * 64;
    const int tr = (tid >> 4) * 4;
    const int tc = (tid & 15) * 4;
    float acc[4][4] = {};
    for (int kh = 0; kh < 2; ++kh) {
        __syncthreads();
        for (int i = 0; i < 4; ++i) {
            int f = tid + i * 256;
            int r = f >> 4, c4 = (f & 15) * 4;
            float4 v = make_float4(0.f, 0.f, 0.f, 0.f);
            if (row0 + r < n_rows)
                v = ld4(A + (size_t)(row0 + r) * 128 + kh * 64 + c4);
            *(float4*)&a_sh[r][c4] = v;
        }
        for (int i = 0; i < 4; ++i) {
            int f = tid + i * 256;
            int k = f >> 4, c4 = (f & 15) * 4;
            *(float4*)&b_sh[k][c4] = *(const float4*)(W + (size_t)(kh * 64 + k) * 128 + cb + c4);
        }
        __syncthreads();
        #pragma unroll
        for (int k4 = 0; k4 < 16; ++k4) {
            float4 a[4], b[4];
            #pragma unroll
            for (int i = 0; i < 4; ++i) a[i] = *(float4*)&a_sh[tr + i][k4 * 4];
            #pragma unroll
            for (int kk = 0; kk < 4; ++kk) b[kk] = *(float4*)&b_sh[k4 * 4 + kk][tc];
            #pragma unroll
            for (int i = 0; i < 4; ++i) {
                const float av[4] = {a[i].x, a[i].y, a[i].z, a[i].w};
                #pragma unroll
                for (int kk = 0; kk < 4; ++kk) {
                    acc[i][0] = fmaf(av[kk], b[kk].x, acc[i][0]);
                    acc[i][1] = fmaf(av[kk], b[kk].y, acc[i][1]);
                    acc[i][2] = fmaf(av[kk], b[kk].z, acc[i][2]);
                    acc[i][3] = fmaf(av[kk], b[kk].w, acc[i][3]);
                }
            }
        }
    }
    for (int i = 0; i < 4; ++i) {
        int r = row0 + tr + i;
        if (r < n_rows)
            st4(out + (size_t)r * 128 + cb + tc,
                make_float4(acc[i][0], acc[i][1], acc[i][2], acc[i][3]));
    }
}

// ---------- histogram / scan / fill machinery ----------
__global__ __launch_bounds__(256) void bin_count(const int* __restrict__ keys,
                                                 unsigned* __restrict__ cnt, int n)
{
    int i = blockIdx.x * 256 + threadIdx.x;
    if (i < n) atomicAdd(&cnt[keys[i]], 1u);
}

// rel histogram: LDS-aggregated (keys-1 in [0,25); raw global atomics on 24
// addresses serialize catastrophically -- 1.3 ms measured in round 6)
__global__ __launch_bounds__(256) void rel_count(const int* __restrict__ etyp,
                                                 unsigned* __restrict__ cnt, int n)
{
    __shared__ unsigned lcnt[NRELMAX];
    const int tid = threadIdx.x;
    if (tid < NRELMAX) lcnt[tid] = 0;
    __syncthreads();
    int i = blockIdx.x * 256 + tid;
    if (i < n) atomicAdd(&lcnt[etyp[i] - 1], 1u);
    __syncthreads();
    if (tid < NRELMAX) {
        unsigned c = lcnt[tid];
        if (c) atomicAdd(&cnt[tid], c);
    }
}

__global__ __launch_bounds__(1024) void scan1(const unsigned* __restrict__ in,
                                              unsigned* __restrict__ out,
                                              unsigned* __restrict__ bsum, int n)
{
    __shared__ unsigned sh[1024];
    int i = blockIdx.x * 1024 + threadIdx.x;
    unsigned v = (i < n) ? in[i] : 0u;
    sh[threadIdx.x] = v;
    __syncthreads();
    for (int off = 1; off < 1024; off <<= 1) {
        unsigned t = (threadIdx.x >= (unsigned)off) ? sh[threadIdx.x - off] : 0u;
        __syncthreads();
        sh[threadIdx.x] += t;
        __syncthreads();
    }
    if (i < n) out[i] = sh[threadIdx.x] - v;  // exclusive
    if (threadIdx.x == 1023) bsum[blockIdx.x] = sh[1023];
}

__global__ __launch_bounds__(1024) void scan2(unsigned* __restrict__ bsum, int nb)
{
    __shared__ unsigned sh[1024];
    unsigned v = (threadIdx.x < (unsigned)nb) ? bsum[threadIdx.x] : 0u;
    sh[threadIdx.x] = v;
    __syncthreads();
    for (int off = 1; off < 1024; off <<= 1) {
        unsigned t = (threadIdx.x >= (unsigned)off) ? sh[threadIdx.x - off] : 0u;
        __syncthreads();
        sh[threadIdx.x] += t;
        __syncthreads();
    }
    if (threadIdx.x < (unsigned)nb) bsum[threadIdx.x] = sh[threadIdx.x] - v;
}

__global__ __launch_bounds__(1024) void scan3(unsigned* __restrict__ out,
                                              const unsigned* __restrict__ bsum, int n)
{
    int i = blockIdx.x * 1024 + threadIdx.x;
    if (i < n) out[i] += bsum[blockIdx.x];
}

__global__ __launch_bounds__(256) void fill_user(const int* __restrict__ rows,
                                                 const int* __restrict__ cols,
                                                 const float* __restrict__ vals,
                                                 unsigned* __restrict__ cursor,
                                                 int* __restrict__ pcol,
                                                 float* __restrict__ pval, int n)
{
    int i = blockIdx.x * 256 + threadIdx.x;
    if (i >= n) return;
    unsigned p = atomicAdd(&cursor[rows[i]], 1u);
    pcol[p] = cols[i];
    pval[p] = vals[i];
}

__global__ __launch_bounds__(256) void fill_edge_islot(const int* __restrict__ keys,
                                                       unsigned* __restrict__ cursor,
                                                       int* __restrict__ islot, int n)
{
    int i = blockIdx.x * 256 + threadIdx.x;
    if (i >= n) return;
    unsigned p = atomicAdd(&cursor[keys[i]], 1u);
    islot[i] = (int)p;
}

// rel-sorted fill: block-aggregated cursor update (25 global atomics per
// block instead of 256)
__global__ __launch_bounds__(256) void fill_rel(const int* __restrict__ head,
                                                const int* __restrict__ tail,
                                                const int* __restrict__ etyp,
                                                const int* __restrict__ islot,
                                                unsigned* __restrict__ rcur,
                                                int4* __restrict__ emeta, int n)
{
    __shared__ unsigned lcnt[NRELMAX];
    __shared__ unsigned lbase[NRELMAX];
    const int tid = threadIdx.x;
    if (tid < NRELMAX) lcnt[tid] = 0;
    __syncthreads();
    int i = blockIdx.x * 256 + tid;
    int r = 0;
    unsigned lpos = 0;
    if (i < n) {
        r = etyp[i] - 1;
        lpos = atomicAdd(&lcnt[r], 1u);
    }
    __syncthreads();
    if (tid < NRELMAX) {
        unsigned c = lcnt[tid];
        lbase[tid] = c ? atomicAdd(&rcur[tid], c) : 0u;
    }
    __syncthreads();
    if (i < n) {
        unsigned p = lbase[r] + lpos;
        emeta[p] = make_int4(head[i], tail[i], islot[i], r);
    }
}

// ---------- score pass: rel-sorted edges, A in registers ----------
__global__ __launch_bounds__(256, 2) void score_pass(
    const __hip_bfloat16* __restrict__ Qb, const __hip_bfloat16* __restrict__ Kb,
    const float* __restrict__ att, const int4* __restrict__ emeta,
    float* __restrict__ SC, int E, int chunk)
{
    const int wave = (blockIdx.x * 256 + threadIdx.x) >> 6;
    const int l = threadIdx.x & 63;
    const int kk = l & 31;
    const int half = l >> 5;
    long j0 = (long)wave * chunk;
    if (j0 >= E) return;
    long j1 = j0 + chunk; if (j1 > E) j1 = E;

    float Areg[2][32];
    int currel = -1;
    for (long j = j0; j < j1; ++j) {
        const int4 md = emeta[j];
        const int hn = md.x, tn = md.y, slot = md.z, rel = md.w;
        if (rel != currel) {
            currel = rel;
            #pragma unroll
            for (int s = 0; s < 2; ++s) {
                const float* Ah = att + (size_t)rel * 4096 + (s * 2 + half) * 1024 + kk;
                #pragma unroll
                for (int d = 0; d < 32; ++d) Areg[s][d] = Ah[d * 32];
            }
        }
        #pragma unroll
        for (int s = 0; s < 2; ++s) {
            const int h = s * 2 + half;
            const __hip_bfloat16* kr = Kb + (size_t)tn * 128 + h * 32;
            float kp = 0.f;
            #pragma unroll
            for (int q = 0; q < 4; ++q) {
                u16x8 v8 = *(const u16x8*)(kr + q * 8);
                #pragma unroll
                for (int t = 0; t < 8; ++t) kp = fmaf(b2f(v8[t]), Areg[s][q * 8 + t], kp);
            }
            float qv = __bfloat162float(Qb[(size_t)hn * 128 + h * 32 + kk]);
            float p = kp * qv;
            #pragma unroll
            for (int off = 16; off >= 1; off >>= 1) p += __shfl_xor(p, off, 64);
            if (kk == 0) SC[(size_t)slot * 4 + h] = p * 0.17677669529663687f;
        }
    }
}

// ---------- msg pass (per head-pair ROUND): V' into slot order ----------
template <int ROUND>
__global__ __launch_bounds__(256, 2) void msg_pass(
    const __hip_bfloat16* __restrict__ Vb, const float* __restrict__ msg,
    const int4* __restrict__ emeta, __hip_bfloat16* __restrict__ VPh,
    int E, int chunk)
{
    const int wave = (blockIdx.x * 256 + threadIdx.x) >> 6;
    const int l = threadIdx.x & 63;
    const int kk = l & 31;
    const int half = l >> 5;
    const int h = ROUND * 2 + half;
    long j0 = (long)wave * chunk;
    if (j0 >= E) return;
    long j1 = j0 + chunk; if (j1 > E) j1 = E;

    float Mreg[32];
    int currel = -1;
    for (long j = j0; j < j1; ++j) {
        const int4 md = emeta[j];
        const int tn = md.y, slot = md.z, rel = md.w;
        if (rel != currel) {
            currel = rel;
            const float* Mh = msg + (size_t)rel * 4096 + h * 1024 + kk;
            #pragma unroll
            for (int d = 0; d < 32; ++d) Mreg[d] = Mh[d * 32];
        }
        const __hip_bfloat16* vr = Vb + (size_t)tn * 128 + h * 32;
        float vp = 0.f;
        #pragma unroll
        for (int q = 0; q < 4; ++q) {
            u16x8 v8 = *(const u16x8*)(vr + q * 8);
            #pragma unroll
            for (int t = 0; t < 8; ++t) vp = fmaf(b2f(v8[t]), Mreg[q * 8 + t], vp);
        }
        VPh[(size_t)slot * 64 + l] = __float2bfloat16(vp);
    }
}

// ---------- node pass (per head-pair ROUND): softmax + accumulate ----------
template <int ROUND>
__global__ __launch_bounds__(256) void node_pass(
    const float* __restrict__ SC, const __hip_bfloat16* __restrict__ VPh,
    const unsigned* __restrict__ ecur, __hip_bfloat16* __restrict__ M, int n)
{
    int node = (blockIdx.x * 256 + threadIdx.x) >> 6;
    if (node >= n) return;
    int l = threadIdx.x & 63;
    int half = l >> 5;
    const int h = ROUND * 2 + half;
    unsigned beg = node ? ecur[node - 1] : 0u;
    unsigned end = ecur[node];
    float mx = -INFINITY;
    for (unsigned j = beg; j < end; ++j) mx = fmaxf(mx, SC[(size_t)j * 4 + h]);
    float dn = 0.f;
    for (unsigned j = beg; j < end; ++j) dn += __expf(SC[(size_t)j * 4 + h] - mx);
    float inv = (end > beg) ? 1.f / dn : 0.f;
    float acc = 0.f;
    for (unsigned j = beg; j < end; ++j) {
        float w = __expf(SC[(size_t)j * 4 + h] - mx) * inv;
        acc = fmaf(w, __bfloat162float(VPh[(size_t)j * 64 + l]), acc);
    }
    M[(size_t)node * 128 + ROUND * 64 + l] = __float2bfloat16(acc);
}

// ---------- per-user gather ----------
__global__ __launch_bounds__(256) void user_gather(
    const float* __restrict__ emb, const unsigned* __restrict__ ucur,
    const int* __restrict__ pcol, const float* __restrict__ pval,
    float* __restrict__ out, int nu)
{
    int u = (blockIdx.x * 256 + threadIdx.x) >> 6;
    if (u >= nu) return;
    int l = threadIdx.x & 63;
    unsigned beg = u ? ucur[u - 1] : 0u;
    unsigned end = ucur[u];
    float a0 = 0.f, a1 = 0.f;
    for (unsigned j = beg; j < end; ++j) {
        int c = pcol[j];
        float v = pval[j];
        float2 e = *(const float2*)(emb + (size_t)c * 128 + l * 2);
        a0 = fmaf(e.x, v, a0);
        a1 = fmaf(e.y, v, a1);
    }
    *(float2*)(out + (size_t)u * 128 + l * 2) = make_float2(a0, a1);
}

extern "C" void kernel_launch(void* const* d_in, const int* in_sizes, int n_in,
                              void* d_out, int out_size, void* d_ws, size_t ws_size,
                              hipStream_t stream)
{
    const float* emb = (const float*)d_in[0];
    const float* W_Q = (const float*)d_in[1];
    const float* W_K = (const float*)d_in[2];
    const float* W_V = (const float*)d_in[3];
    const float* W_O = (const float*)d_in[4];
    const float* att = (const float*)d_in[5];
    const float* msg = (const float*)d_in[6];
    const int* eidx  = (const int*)d_in[8];
    const int* etyp  = (const int*)d_in[9];
    const int* irow  = (const int*)d_in[10];
    const int* icol  = (const int*)d_in[11];
    const float* ival = (const float*)d_in[12];

    const int N    = in_sizes[0] / 128;
    const int E    = in_sizes[8] / 2;
    const int NNZ  = in_sizes[10];
    const int NU   = out_size / 128 - N;
    const int NREL = in_sizes[5] / 4096;   // = NREL-1 actual relation slots

    const int* head = eidx;
    const int* tail = eidx + E;

    // ---- workspace layout (155.8 MB total; proven capacity >= 163.2 MB) ----
    const size_t NC = (size_t)N * 128;
    __hip_bfloat16* VPh = (__hip_bfloat16*)d_ws;          // E*64 bf16 (written after overlays die)
    __hip_bfloat16* Qb  = (__hip_bfloat16*)d_ws;          // N*128 bf16 (overlay in VPh region)
    __hip_bfloat16* Kb  = Qb + NC;                        // N*128 bf16 (overlay)
    int* islot          = (int*)(Kb + NC);                // E ints (overlay, dead after fill_rel)

    char* p = (char*)d_ws + (size_t)E * 64 * 2;
    __hip_bfloat16* Vb = (__hip_bfloat16*)p; p += NC * 2;           // N*128 bf16
    int4* emeta        = (int4*)p;           p += (size_t)E * 16;   // rel-sorted metadata
    float* SC          = (float*)p;          p += (size_t)E * 16;   // E*4 f32 scores
    unsigned* ecnt     = (unsigned*)p;       p += (size_t)N * 4;    // head-CSR offsets
    unsigned* rcnt     = (unsigned*)p;       p += 32 * 4;           // rel offsets
    unsigned* bsum     = (unsigned*)p;       p += 1024 * 4;         // scan scratch
    __hip_bfloat16* M  = (__hip_bfloat16*)p; p += NC * 2;           // N*128 bf16 aggregate
    unsigned* ucnt     = (unsigned*)p;       p += (size_t)((NU + 255) & ~255) * 4;
    unsigned* bsumU    = (unsigned*)p;       p += 1024 * 4;
    int* pcol          = (int*)p;            p += (size_t)NNZ * 4;
    float* pval        = (float*)p;          p += (size_t)NNZ * 4;

    float* out_ent = (float*)d_out;
    float* out_usr = out_ent + NC;

    hipMemsetAsync(ecnt, 0, (size_t)N * 4 + 32 * 4 + 1024 * 4, stream);
    hipMemsetAsync(ucnt, 0, (size_t)NU * 4, stream);

    // Q/K/V projections (f32 in, bf16 out)
    dim3 g_gemm((unsigned)((N + 63) / 64), 2);
    gemm_t<float, __hip_bfloat16><<<g_gemm, 256, 0, stream>>>(emb, W_Q, Qb, N);
    gemm_t<float, __hip_bfloat16><<<g_gemm, 256, 0, stream>>>(emb, W_K, Kb, N);
    gemm_t<float, __hip_bfloat16><<<g_gemm, 256, 0, stream>>>(emb, W_V, Vb, N);

    // head-CSR + rel-sorted metadata
    bin_count<<<(E + 255) / 256, 256, 0, stream>>>(head, ecnt, E);
    rel_count<<<(E + 255) / 256, 256, 0, stream>>>(etyp, rcnt, E);
    scan1<<<1, 1024, 0, stream>>>(rcnt, rcnt, bsum, NREL);
    int nbE = (N + 1023) / 1024;
    scan1<<<nbE, 1024, 0, stream>>>(ecnt, ecnt, bsum, N);
    scan2<<<1, 1024, 0, stream>>>(bsum, nbE);
    scan3<<<nbE, 1024, 0, stream>>>(ecnt, bsum, N);
    fill_edge_islot<<<(E + 255) / 256, 256, 0, stream>>>(head, ecnt, islot, E);
    fill_rel<<<(E + 255) / 256, 256, 0, stream>>>(head, tail, etyp, islot, rcnt, emeta, E);
    // ecnt now holds end-boundaries per node

    const int NWAVE = 16384;
    int chunk = (E + NWAVE - 1) / NWAVE;
    score_pass<<<NWAVE / 4, 256, 0, stream>>>(Qb, Kb, att, emeta, SC, E, chunk);
    // Qb/Kb/islot dead -> VPh region free

    msg_pass<0><<<NWAVE / 4, 256, 0, stream>>>(Vb, msg, emeta, VPh, E, chunk);
    node_pass<0><<<(N + 3) / 4, 256, 0, stream>>>(SC, VPh, ecnt, M, N);
    msg_pass<1><<<NWAVE / 4, 256, 0, stream>>>(Vb, msg, emeta, VPh, E, chunk);
    node_pass<1><<<(N + 3) / 4, 256, 0, stream>>>(SC, VPh, ecnt, M, N);

    // entity output GEMM (bf16 A, f32 out)
    gemm_t<__hip_bfloat16, float><<<g_gemm, 256, 0, stream>>>(M, W_O, out_ent, N);

    // user aggregation via CSR gather
    bin_count<<<(NNZ + 255) / 256, 256, 0, stream>>>(irow, ucnt, NNZ);
    int nbU = (NU + 1023) / 1024;
    scan1<<<nbU, 1024, 0, stream>>>(ucnt, ucnt, bsumU, NU);
    scan2<<<1, 1024, 0, stream>>>(bsumU, nbU);
    scan3<<<nbU, 1024, 0, stream>>>(ucnt, bsumU, NU);
    fill_user<<<(NNZ + 255) / 256, 256, 0, stream>>>(irow, icol, ival, ucnt, pcol, pval, NNZ);
    user_gather<<<(NU + 3) / 4, 256, 0, stream>>>(emb, ucnt, pcol, pval, out_usr, NU);
}

// Round 9
// 873.357 us; speedup vs baseline: 4.3495x; 1.3941x over previous
//
#include <hip/hip_runtime.h>
#include <hip/hip_bf16.h>
#include <math.h>

// NOTE: resubmission — round 8 hit a dead container ("connection closed while
// sending first message", no timing block, same pod as rounds 4/5); the MFMA
// edge-pass source below never ran. Re-audited for hang paths: the grouping
// loop always advances (ballot bit 0 is self-true), all vector accesses are
// size-aligned, all writes CSR-bounded.

typedef __attribute__((ext_vector_type(8))) unsigned short u16x8;
typedef __attribute__((ext_vector_type(4))) unsigned short u16x4;
typedef __attribute__((ext_vector_type(8))) short bf16x8;   // MFMA A/B frag (8 bf16)
typedef __attribute__((ext_vector_type(4))) float f32x4;    // MFMA C/D frag

#define NRELMAX 32

__device__ __forceinline__ float b2f(unsigned short u) {
    return __uint_as_float(((unsigned)u) << 16);
}
__device__ __forceinline__ unsigned short f2b(float v) {
    __hip_bfloat16 b = __float2bfloat16(v);
    return *reinterpret_cast<unsigned short*>(&b);
}

// ---------- generic loaders for GEMM ----------
__device__ __forceinline__ float4 ld4(const float* p) { return *(const float4*)p; }
__device__ __forceinline__ float4 ld4(const __hip_bfloat16* p) {
    u16x4 u = *(const u16x4*)p;
    return make_float4(b2f(u[0]), b2f(u[1]), b2f(u[2]), b2f(u[3]));
}
__device__ __forceinline__ void st4(float* p, float4 v) { *(float4*)p = v; }
__device__ __forceinline__ void st4(__hip_bfloat16* p, float4 v) {
    p[0] = __float2bfloat16(v.x); p[1] = __float2bfloat16(v.y);
    p[2] = __float2bfloat16(v.z); p[3] = __float2bfloat16(v.w);
}

// ---------- tiled GEMM: out[r][c] = sum_k A[r][k]*W[k][c], K=C=128 ----------
template <typename TA, typename TO>
__global__ __launch_bounds__(256) void gemm_t(const TA* __restrict__ A,
                                              const float* __restrict__ W,
                                              TO* __restrict__ out, int n_rows)
{
    __shared__ float a_sh[64][68];
    __shared__ float b_sh[64][64];
    const int tid = threadIdx.x;
    const int row0 = blockIdx.x * 64;
    const int cb   = blockIdx.y * 64;
    const int tr = (tid >> 4) * 4;
    const int tc = (tid & 15) * 4;
    float acc[4][4] = {};
    for (int kh = 0; kh < 2; ++kh) {
        __syncthreads();
        for (int i = 0; i < 4; ++i) {
            int f = tid + i * 256;
            int r = f >> 4, c4 = (f & 15) * 4;
            float4 v = make_float4(0.f, 0.f, 0.f, 0.f);
            if (row0 + r < n_rows)
                v = ld4(A + (size_t)(row0 + r) * 128 + kh * 64 + c4);
            *(float4*)&a_sh[r][c4] = v;
        }
        for (int i = 0; i < 4; ++i) {
            int f = tid + i * 256;
            int k = f >> 4, c4 = (f & 15) * 4;
            *(float4*)&b_sh[k][c4] = *(const float4*)(W + (size_t)(kh * 64 + k) * 128 + cb + c4);
        }
        __syncthreads();
        #pragma unroll
        for (int k4 = 0; k4 < 16; ++k4) {
            float4 a[4], b[4];
            #pragma unroll
            for (int i = 0; i < 4; ++i) a[i] = *(float4*)&a_sh[tr + i][k4 * 4];
            #pragma unroll
            for (int kk = 0; kk < 4; ++kk) b[kk] = *(float4*)&b_sh[k4 * 4 + kk][tc];
            #pragma unroll
            for (int i = 0; i < 4; ++i) {
                const float av[4] = {a[i].x, a[i].y, a[i].z, a[i].w};
                #pragma unroll
                for (int kk = 0; kk < 4; ++kk) {
                    acc[i][0] = fmaf(av[kk], b[kk].x, acc[i][0]);
                    acc[i][1] = fmaf(av[kk], b[kk].y, acc[i][1]);
                    acc[i][2] = fmaf(av[kk], b[kk].z, acc[i][2]);
                    acc[i][3] = fmaf(av[kk], b[kk].w, acc[i][3]);
                }
            }
        }
    }
    for (int i = 0; i < 4; ++i) {
        int r = row0 + tr + i;
        if (r < n_rows)
            st4(out + (size_t)r * 128 + cb + tc,
                make_float4(acc[i][0], acc[i][1], acc[i][2], acc[i][3]));
    }
}

// ---------- histogram / scan / fill machinery ----------
__global__ __launch_bounds__(256) void bin_count(const int* __restrict__ keys,
                                                 unsigned* __restrict__ cnt, int n)
{
    int i = blockIdx.x * 256 + threadIdx.x;
    if (i < n) atomicAdd(&cnt[keys[i]], 1u);
}

__global__ __launch_bounds__(256) void rel_count(const int* __restrict__ etyp,
                                                 unsigned* __restrict__ cnt, int n)
{
    __shared__ unsigned lcnt[NRELMAX];
    const int tid = threadIdx.x;
    if (tid < NRELMAX) lcnt[tid] = 0;
    __syncthreads();
    int i = blockIdx.x * 256 + tid;
    if (i < n) atomicAdd(&lcnt[etyp[i] - 1], 1u);
    __syncthreads();
    if (tid < NRELMAX) {
        unsigned c = lcnt[tid];
        if (c) atomicAdd(&cnt[tid], c);
    }
}

__global__ __launch_bounds__(1024) void scan1(const unsigned* __restrict__ in,
                                              unsigned* __restrict__ out,
                                              unsigned* __restrict__ bsum, int n)
{
    __shared__ unsigned sh[1024];
    int i = blockIdx.x * 1024 + threadIdx.x;
    unsigned v = (i < n) ? in[i] : 0u;
    sh[threadIdx.x] = v;
    __syncthreads();
    for (int off = 1; off < 1024; off <<= 1) {
        unsigned t = (threadIdx.x >= (unsigned)off) ? sh[threadIdx.x - off] : 0u;
        __syncthreads();
        sh[threadIdx.x] += t;
        __syncthreads();
    }
    if (i < n) out[i] = sh[threadIdx.x] - v;  // exclusive
    if (threadIdx.x == 1023) bsum[blockIdx.x] = sh[1023];
}

__global__ __launch_bounds__(1024) void scan2(unsigned* __restrict__ bsum, int nb)
{
    __shared__ unsigned sh[1024];
    unsigned v = (threadIdx.x < (unsigned)nb) ? bsum[threadIdx.x] : 0u;
    sh[threadIdx.x] = v;
    __syncthreads();
    for (int off = 1; off < 1024; off <<= 1) {
        unsigned t = (threadIdx.x >= (unsigned)off) ? sh[threadIdx.x - off] : 0u;
        __syncthreads();
        sh[threadIdx.x] += t;
        __syncthreads();
    }
    if (threadIdx.x < (unsigned)nb) bsum[threadIdx.x] = sh[threadIdx.x] - v;
}

__global__ __launch_bounds__(1024) void scan3(unsigned* __restrict__ out,
                                              const unsigned* __restrict__ bsum, int n)
{
    int i = blockIdx.x * 1024 + threadIdx.x;
    if (i < n) out[i] += bsum[blockIdx.x];
}

__global__ __launch_bounds__(256) void fill_user(const int* __restrict__ rows,
                                                 const int* __restrict__ cols,
                                                 const float* __restrict__ vals,
                                                 unsigned* __restrict__ cursor,
                                                 int* __restrict__ pcol,
                                                 float* __restrict__ pval, int n)
{
    int i = blockIdx.x * 256 + threadIdx.x;
    if (i >= n) return;
    unsigned p = atomicAdd(&cursor[rows[i]], 1u);
    pcol[p] = cols[i];
    pval[p] = vals[i];
}

__global__ __launch_bounds__(256) void fill_edge_islot(const int* __restrict__ keys,
                                                       unsigned* __restrict__ cursor,
                                                       int* __restrict__ islot, int n)
{
    int i = blockIdx.x * 256 + threadIdx.x;
    if (i >= n) return;
    unsigned p = atomicAdd(&cursor[keys[i]], 1u);
    islot[i] = (int)p;
}

__global__ __launch_bounds__(256) void fill_rel(const int* __restrict__ head,
                                                const int* __restrict__ tail,
                                                const int* __restrict__ etyp,
                                                const int* __restrict__ islot,
                                                unsigned* __restrict__ rcur,
                                                int4* __restrict__ emeta, int n)
{
    __shared__ unsigned lcnt[NRELMAX];
    __shared__ unsigned lbase[NRELMAX];
    const int tid = threadIdx.x;
    if (tid < NRELMAX) lcnt[tid] = 0;
    __syncthreads();
    int i = blockIdx.x * 256 + tid;
    int r = 0;
    unsigned lpos = 0;
    if (i < n) {
        r = etyp[i] - 1;
        lpos = atomicAdd(&lcnt[r], 1u);
    }
    __syncthreads();
    if (tid < NRELMAX) {
        unsigned c = lcnt[tid];
        lbase[tid] = c ? atomicAdd(&rcur[tid], c) : 0u;
    }
    __syncthreads();
    if (i < n) {
        unsigned p = lbase[r] + lpos;
        emeta[p] = make_int4(head[i], tail[i], islot[i], r);
    }
}

// ---------- MFMA score pass: 16 same-rel edges per step ----------
// frag layout (gfx950 16x16x32 bf16): A row=lane%16, k-oct=lane/16;
// D col=lane&15, row=(lane>>4)*4+reg  [m89-verified]
__global__ __launch_bounds__(256, 2) void score_mfma(
    const __hip_bfloat16* __restrict__ Qb, const __hip_bfloat16* __restrict__ Kb,
    const float* __restrict__ att, const int4* __restrict__ emeta,
    float* __restrict__ SC, long E, int chunk)
{
    const int wv = (blockIdx.x * 256 + threadIdx.x) >> 6;
    const int l = threadIdx.x & 63;
    const int g = l >> 4;      // k-octet / dim-group
    const int c = l & 15;      // edge column
    long j0 = (long)wv * chunk;
    if (j0 >= E) return;
    long j1 = j0 + chunk; if (j1 > E) j1 = E;

    bf16x8 aK[4][2];
    int currel = -1;
    long pos = j0;
    while (pos < j1) {
        long e = pos + c;
        long ec = (e < j1) ? e : (j1 - 1);
        const int4 md = emeta[ec];
        int rel0 = __shfl(md.w, 0, 64);
        unsigned long long mask = __ballot(e < j1 && md.w == rel0);
        int cnt = (int)__builtin_ctzll(~(mask & 0xFFFFull));
        bool valid = c < cnt;
        if (rel0 != currel) {
            currel = rel0;
            const float* Ar = att + (size_t)rel0 * 4096;
            #pragma unroll
            for (int h = 0; h < 4; ++h)
                #pragma unroll
                for (int s2 = 0; s2 < 2; ++s2) {
                    const float* base = Ar + h * 1024 + s2 * 16 + c;
                    bf16x8 f;
                    #pragma unroll
                    for (int j = 0; j < 8; ++j)
                        f[j] = (short)f2b(base[(g * 8 + j) * 32]);
                    aK[h][s2] = f;
                }
        }
        const int tn = md.y, hn = md.x, slot = md.z;
        #pragma unroll
        for (int h = 0; h < 4; ++h) {
            bf16x8 bk = *(const bf16x8*)(Kb + (size_t)tn * 128 + h * 32 + g * 8);
            f32x4 z = {0.f, 0.f, 0.f, 0.f};
            f32x4 klo = __builtin_amdgcn_mfma_f32_16x16x32_bf16(aK[h][0], bk, z, 0, 0, 0);
            f32x4 khi = __builtin_amdgcn_mfma_f32_16x16x32_bf16(aK[h][1], bk, z, 0, 0, 0);
            const __hip_bfloat16* qp = Qb + (size_t)hn * 128 + h * 32;
            u16x4 q1 = *(const u16x4*)(qp + g * 4);
            u16x4 q2 = *(const u16x4*)(qp + 16 + g * 4);
            float p = 0.f;
            #pragma unroll
            for (int r = 0; r < 4; ++r)
                p += b2f(q1[r]) * klo[r] + b2f(q2[r]) * khi[r];
            p += __shfl_xor(p, 16, 64);
            p += __shfl_xor(p, 32, 64);
            if (g == 0 && valid) SC[(size_t)slot * 4 + h] = p * 0.17677669529663687f;
        }
        pos += cnt;
    }
}

// ---------- MFMA msg pass (per head-pair ROUND): V' into slot order ----------
template <int ROUND>
__global__ __launch_bounds__(256, 2) void msg_mfma(
    const __hip_bfloat16* __restrict__ Vb, const float* __restrict__ msg,
    const int4* __restrict__ emeta, __hip_bfloat16* __restrict__ VPh,
    long E, int chunk)
{
    const int wv = (blockIdx.x * 256 + threadIdx.x) >> 6;
    const int l = threadIdx.x & 63;
    const int g = l >> 4;
    const int c = l & 15;
    long j0 = (long)wv * chunk;
    if (j0 >= E) return;
    long j1 = j0 + chunk; if (j1 > E) j1 = E;

    bf16x8 aM[2][2];
    int currel = -1;
    long pos = j0;
    while (pos < j1) {
        long e = pos + c;
        long ec = (e < j1) ? e : (j1 - 1);
        const int4 md = emeta[ec];
        int rel0 = __shfl(md.w, 0, 64);
        unsigned long long mask = __ballot(e < j1 && md.w == rel0);
        int cnt = (int)__builtin_ctzll(~(mask & 0xFFFFull));
        bool valid = c < cnt;
        if (rel0 != currel) {
            currel = rel0;
            const float* Mr = msg + (size_t)rel0 * 4096;
            #pragma unroll
            for (int hl = 0; hl < 2; ++hl)
                #pragma unroll
                for (int s2 = 0; s2 < 2; ++s2) {
                    const float* base = Mr + (ROUND * 2 + hl) * 1024 + s2 * 16 + c;
                    bf16x8 f;
                    #pragma unroll
                    for (int j = 0; j < 8; ++j)
                        f[j] = (short)f2b(base[(g * 8 + j) * 32]);
                    aM[hl][s2] = f;
                }
        }
        const int tn = md.y, slot = md.z;
        #pragma unroll
        for (int hl = 0; hl < 2; ++hl) {
            const int h = ROUND * 2 + hl;
            bf16x8 bv = *(const bf16x8*)(Vb + (size_t)tn * 128 + h * 32 + g * 8);
            f32x4 z = {0.f, 0.f, 0.f, 0.f};
            f32x4 vlo = __builtin_amdgcn_mfma_f32_16x16x32_bf16(aM[hl][0], bv, z, 0, 0, 0);
            f32x4 vhi = __builtin_amdgcn_mfma_f32_16x16x32_bf16(aM[hl][1], bv, z, 0, 0, 0);
            if (valid) {
                u16x4 plo, phi;
                #pragma unroll
                for (int r = 0; r < 4; ++r) { plo[r] = f2b(vlo[r]); phi[r] = f2b(vhi[r]); }
                __hip_bfloat16* dst = VPh + (size_t)slot * 64 + hl * 32;
                *(u16x4*)(dst + g * 4) = plo;
                *(u16x4*)(dst + 16 + g * 4) = phi;
            }
        }
        pos += cnt;
    }
}

// ---------- node pass (per head-pair ROUND): softmax + accumulate ----------
template <int ROUND>
__global__ __launch_bounds__(256) void node_pass(
    const float* __restrict__ SC, const __hip_bfloat16* __restrict__ VPh,
    const unsigned* __restrict__ ecur, __hip_bfloat16* __restrict__ M, int n)
{
    int node = (blockIdx.x * 256 + threadIdx.x) >> 6;
    if (node >= n) return;
    int l = threadIdx.x & 63;
    int half = l >> 5;
    const int h = ROUND * 2 + half;
    unsigned beg = node ? ecur[node - 1] : 0u;
    unsigned end = ecur[node];
    float mx = -INFINITY;
    for (unsigned j = beg; j < end; ++j) mx = fmaxf(mx, SC[(size_t)j * 4 + h]);
    float dn = 0.f;
    for (unsigned j = beg; j < end; ++j) dn += __expf(SC[(size_t)j * 4 + h] - mx);
    float inv = (end > beg) ? 1.f / dn : 0.f;
    float acc = 0.f;
    for (unsigned j = beg; j < end; ++j) {
        float w = __expf(SC[(size_t)j * 4 + h] - mx) * inv;
        acc = fmaf(w, __bfloat162float(VPh[(size_t)j * 64 + l]), acc);
    }
    M[(size_t)node * 128 + ROUND * 64 + l] = __float2bfloat16(acc);
}

// ---------- per-user gather ----------
__global__ __launch_bounds__(256) void user_gather(
    const float* __restrict__ emb, const unsigned* __restrict__ ucur,
    const int* __restrict__ pcol, const float* __restrict__ pval,
    float* __restrict__ out, int nu)
{
    int u = (blockIdx.x * 256 + threadIdx.x) >> 6;
    if (u >= nu) return;
    int l = threadIdx.x & 63;
    unsigned beg = u ? ucur[u - 1] : 0u;
    unsigned end = ucur[u];
    float a0 = 0.f, a1 = 0.f;
    for (unsigned j = beg; j < end; ++j) {
        int c = pcol[j];
        float v = pval[j];
        float2 e = *(const float2*)(emb + (size_t)c * 128 + l * 2);
        a0 = fmaf(e.x, v, a0);
        a1 = fmaf(e.y, v, a1);
    }
    *(float2*)(out + (size_t)u * 128 + l * 2) = make_float2(a0, a1);
}

extern "C" void kernel_launch(void* const* d_in, const int* in_sizes, int n_in,
                              void* d_out, int out_size, void* d_ws, size_t ws_size,
                              hipStream_t stream)
{
    const float* emb = (const float*)d_in[0];
    const float* W_Q = (const float*)d_in[1];
    const float* W_K = (const float*)d_in[2];
    const float* W_V = (const float*)d_in[3];
    const float* W_O = (const float*)d_in[4];
    const float* att = (const float*)d_in[5];
    const float* msg = (const float*)d_in[6];
    const int* eidx  = (const int*)d_in[8];
    const int* etyp  = (const int*)d_in[9];
    const int* irow  = (const int*)d_in[10];
    const int* icol  = (const int*)d_in[11];
    const float* ival = (const float*)d_in[12];

    const int N    = in_sizes[0] / 128;
    const int E    = in_sizes[8] / 2;
    const int NNZ  = in_sizes[10];
    const int NU   = out_size / 128 - N;
    const int NREL = in_sizes[5] / 4096;   // = NREL-1 actual relation slots

    const int* head = eidx;
    const int* tail = eidx + E;

    // ---- workspace layout (155.8 MB total; proven capacity >= 163.2 MB) ----
    const size_t NC = (size_t)N * 128;
    __hip_bfloat16* VPh = (__hip_bfloat16*)d_ws;          // E*64 bf16 (written after overlays die)
    __hip_bfloat16* Qb  = (__hip_bfloat16*)d_ws;          // N*128 bf16 (overlay in VPh region)
    __hip_bfloat16* Kb  = Qb + NC;                        // N*128 bf16 (overlay)
    int* islot          = (int*)(Kb + NC);                // E ints (overlay, dead after fill_rel)

    char* p = (char*)d_ws + (size_t)E * 64 * 2;
    __hip_bfloat16* Vb = (__hip_bfloat16*)p; p += NC * 2;           // N*128 bf16
    int4* emeta        = (int4*)p;           p += (size_t)E * 16;   // rel-sorted metadata
    float* SC          = (float*)p;          p += (size_t)E * 16;   // E*4 f32 scores
    unsigned* ecnt     = (unsigned*)p;       p += (size_t)N * 4;    // head-CSR offsets
    unsigned* rcnt     = (unsigned*)p;       p += 32 * 4;           // rel offsets
    unsigned* bsum     = (unsigned*)p;       p += 1024 * 4;         // scan scratch
    __hip_bfloat16* M  = (__hip_bfloat16*)p; p += NC * 2;           // N*128 bf16 aggregate
    unsigned* ucnt     = (unsigned*)p;       p += (size_t)((NU + 255) & ~255) * 4;
    unsigned* bsumU    = (unsigned*)p;       p += 1024 * 4;
    int* pcol          = (int*)p;            p += (size_t)NNZ * 4;
    float* pval        = (float*)p;          p += (size_t)NNZ * 4;

    float* out_ent = (float*)d_out;
    float* out_usr = out_ent + NC;

    hipMemsetAsync(ecnt, 0, (size_t)N * 4 + 32 * 4 + 1024 * 4, stream);
    hipMemsetAsync(ucnt, 0, (size_t)NU * 4, stream);

    // Q/K/V projections (f32 in, bf16 out)
    dim3 g_gemm((unsigned)((N + 63) / 64), 2);
    gemm_t<float, __hip_bfloat16><<<g_gemm, 256, 0, stream>>>(emb, W_Q, Qb, N);
    gemm_t<float, __hip_bfloat16><<<g_gemm, 256, 0, stream>>>(emb, W_K, Kb, N);
    gemm_t<float, __hip_bfloat16><<<g_gemm, 256, 0, stream>>>(emb, W_V, Vb, N);

    // head-CSR + rel-sorted metadata
    bin_count<<<(E + 255) / 256, 256, 0, stream>>>(head, ecnt, E);
    rel_count<<<(E + 255) / 256, 256, 0, stream>>>(etyp, rcnt, E);
    scan1<<<1, 1024, 0, stream>>>(rcnt, rcnt, bsum, NREL);
    int nbE = (N + 1023) / 1024;
    scan1<<<nbE, 1024, 0, stream>>>(ecnt, ecnt, bsum, N);
    scan2<<<1, 1024, 0, stream>>>(bsum, nbE);
    scan3<<<nbE, 1024, 0, stream>>>(ecnt, bsum, N);
    fill_edge_islot<<<(E + 255) / 256, 256, 0, stream>>>(head, ecnt, islot, E);
    fill_rel<<<(E + 255) / 256, 256, 0, stream>>>(head, tail, etyp, islot, rcnt, emeta, E);
    // ecnt now holds end-boundaries per node

    const int NWAVE = 8192;
    int chunk = (E + NWAVE - 1) / NWAVE;
    score_mfma<<<NWAVE / 4, 256, 0, stream>>>(Qb, Kb, att, emeta, SC, E, chunk);
    // Qb/Kb/islot dead -> VPh region free

    msg_mfma<0><<<NWAVE / 4, 256, 0, stream>>>(Vb, msg, emeta, VPh, E, chunk);
    node_pass<0><<<(N + 3) / 4, 256, 0, stream>>>(SC, VPh, ecnt, M, N);
    msg_mfma<1><<<NWAVE / 4, 256, 0, stream>>>(Vb, msg, emeta, VPh, E, chunk);
    node_pass<1><<<(N + 3) / 4, 256, 0, stream>>>(SC, VPh, ecnt, M, N);

    // entity output GEMM (bf16 A, f32 out)
    gemm_t<__hip_bfloat16, float><<<g_gemm, 256, 0, stream>>>(M, W_O, out_ent, N);

    // user aggregation via CSR gather
    bin_count<<<(NNZ + 255) / 256, 256, 0, stream>>>(irow, ucnt, NNZ);
    int nbU = (NU + 1023) / 1024;
    scan1<<<nbU, 1024, 0, stream>>>(ucnt, ucnt, bsumU, NU);
    scan2<<<1, 1024, 0, stream>>>(bsumU, nbU);
    scan3<<<nbU, 1024, 0, stream>>>(ucnt, bsumU, NU);
    fill_user<<<(NNZ + 255) / 256, 256, 0, stream>>>(irow, icol, ival, ucnt, pcol, pval, NNZ);
    user_gather<<<(NU + 3) / 4, 256, 0, stream>>>(emb, ucnt, pcol, pval, out_usr, NU);
}

// Round 10
// 805.424 us; speedup vs baseline: 4.7163x; 1.0843x over previous
//
#include <hip/hip_runtime.h>
#include <hip/hip_bf16.h>
#include <math.h>

typedef __attribute__((ext_vector_type(8))) unsigned short u16x8;
typedef __attribute__((ext_vector_type(4))) unsigned short u16x4;
typedef __attribute__((ext_vector_type(8))) short bf16x8;   // MFMA A/B frag (8 bf16)
typedef __attribute__((ext_vector_type(4))) float f32x4;    // MFMA C/D frag

#define NRELMAX 32

__device__ __forceinline__ float b2f(unsigned short u) {
    return __uint_as_float(((unsigned)u) << 16);
}
__device__ __forceinline__ unsigned short f2b(float v) {
    __hip_bfloat16 b = __float2bfloat16(v);
    return *reinterpret_cast<unsigned short*>(&b);
}

// ---------- MFMA GEMM: out[r][c] = sum_k A[r][k] * W[k][c], K=C=128 ----------
// Wt is W transposed to [c][k] bf16 so B-frags are contiguous 16B lane loads.
// frag wiring (verified by score_mfma / m89): A lane(row=l%16, koct=l/16) holds
// A[row][koct*8+j]; B lane(col=l%16, koct) holds W[koct*8+j][col]; D lane reg r
// -> row=(l>>4)*4+r, col=l&15.
__device__ __forceinline__ bf16x8 lda_frag(const float* p) {
    float4 a = *(const float4*)p;
    float4 b = *(const float4*)(p + 4);
    bf16x8 f;
    f[0] = (short)f2b(a.x); f[1] = (short)f2b(a.y);
    f[2] = (short)f2b(a.z); f[3] = (short)f2b(a.w);
    f[4] = (short)f2b(b.x); f[5] = (short)f2b(b.y);
    f[6] = (short)f2b(b.z); f[7] = (short)f2b(b.w);
    return f;
}
__device__ __forceinline__ bf16x8 lda_frag(const __hip_bfloat16* p) {
    return *(const bf16x8*)p;
}
__device__ __forceinline__ void st_o(__hip_bfloat16* p, float v) { *p = __float2bfloat16(v); }
__device__ __forceinline__ void st_o(float* p, float v) { *p = v; }

template <typename TA, typename TO>
__global__ __launch_bounds__(256) void mfma_gemm(const TA* __restrict__ A,
                                                 const __hip_bfloat16* __restrict__ Wt,
                                                 TO* __restrict__ out, int n)
{
    const int tid = threadIdx.x;
    const int w = tid >> 6;
    const int l = tid & 63;
    const int q = l >> 4;
    const int c16 = l & 15;
    const int wr = (w >> 1) * 64;
    const int wc = (w & 1) * 64;
    const long row0 = (long)blockIdx.x * 128;

    f32x4 acc[4][4] = {};
    #pragma unroll
    for (int ks = 0; ks < 4; ++ks) {
        bf16x8 af[4];
        #pragma unroll
        for (int rb = 0; rb < 4; ++rb) {
            long r = row0 + wr + rb * 16 + c16;
            if (r >= n) r = n - 1;
            af[rb] = lda_frag(A + r * 128 + ks * 32 + q * 8);
        }
        #pragma unroll
        for (int cb = 0; cb < 4; ++cb) {
            bf16x8 wf = *(const bf16x8*)(Wt + (size_t)(wc + cb * 16 + c16) * 128 + ks * 32 + q * 8);
            #pragma unroll
            for (int rb = 0; rb < 4; ++rb)
                acc[rb][cb] = __builtin_amdgcn_mfma_f32_16x16x32_bf16(af[rb], wf, acc[rb][cb], 0, 0, 0);
        }
    }
    #pragma unroll
    for (int rb = 0; rb < 4; ++rb) {
        #pragma unroll
        for (int r = 0; r < 4; ++r) {
            long row = row0 + wr + rb * 16 + q * 4 + r;
            if (row < n) {
                #pragma unroll
                for (int cb = 0; cb < 4; ++cb)
                    st_o(out + row * 128 + wc + cb * 16 + c16, acc[rb][cb][r]);
            }
        }
    }
}

// ---------- W transpose+convert: Wt[c][k] = bf16(W[k][c]), 128x128 ----------
__global__ __launch_bounds__(256) void trans_w(const float* __restrict__ W,
                                               __hip_bfloat16* __restrict__ Wt)
{
    int t = blockIdx.x * 256 + threadIdx.x;   // 16384 threads
    int k = t >> 7, c = t & 127;
    Wt[(size_t)c * 128 + k] = __float2bfloat16(W[(size_t)k * 128 + c]);
}

// ---------- emb f32 -> bf16 convert (into dead M region) ----------
__global__ __launch_bounds__(256) void conv_emb(const float* __restrict__ emb,
                                                __hip_bfloat16* __restrict__ embb, long n4)
{
    long i = ((long)blockIdx.x * 256 + threadIdx.x) * 4;
    if (i >= n4 * 4) return;
    float4 v = *(const float4*)(emb + i);
    u16x4 o;
    o[0] = f2b(v.x); o[1] = f2b(v.y); o[2] = f2b(v.z); o[3] = f2b(v.w);
    *(u16x4*)(embb + i) = o;
}

// ---------- histogram / scan / fill machinery ----------
__global__ __launch_bounds__(256) void bin_count(const int* __restrict__ keys,
                                                 unsigned* __restrict__ cnt, int n)
{
    int i = blockIdx.x * 256 + threadIdx.x;
    if (i < n) atomicAdd(&cnt[keys[i]], 1u);
}

__global__ __launch_bounds__(256) void rel_count(const int* __restrict__ etyp,
                                                 unsigned* __restrict__ cnt, int n)
{
    __shared__ unsigned lcnt[NRELMAX];
    const int tid = threadIdx.x;
    if (tid < NRELMAX) lcnt[tid] = 0;
    __syncthreads();
    int i = blockIdx.x * 256 + tid;
    if (i < n) atomicAdd(&lcnt[etyp[i] - 1], 1u);
    __syncthreads();
    if (tid < NRELMAX) {
        unsigned c = lcnt[tid];
        if (c) atomicAdd(&cnt[tid], c);
    }
}

__global__ __launch_bounds__(1024) void scan1(const unsigned* __restrict__ in,
                                              unsigned* __restrict__ out,
                                              unsigned* __restrict__ bsum, int n)
{
    __shared__ unsigned sh[1024];
    int i = blockIdx.x * 1024 + threadIdx.x;
    unsigned v = (i < n) ? in[i] : 0u;
    sh[threadIdx.x] = v;
    __syncthreads();
    for (int off = 1; off < 1024; off <<= 1) {
        unsigned t = (threadIdx.x >= (unsigned)off) ? sh[threadIdx.x - off] : 0u;
        __syncthreads();
        sh[threadIdx.x] += t;
        __syncthreads();
    }
    if (i < n) out[i] = sh[threadIdx.x] - v;  // exclusive
    if (threadIdx.x == 1023) bsum[blockIdx.x] = sh[1023];
}

__global__ __launch_bounds__(1024) void scan2(unsigned* __restrict__ bsum, int nb)
{
    __shared__ unsigned sh[1024];
    unsigned v = (threadIdx.x < (unsigned)nb) ? bsum[threadIdx.x] : 0u;
    sh[threadIdx.x] = v;
    __syncthreads();
    for (int off = 1; off < 1024; off <<= 1) {
        unsigned t = (threadIdx.x >= (unsigned)off) ? sh[threadIdx.x - off] : 0u;
        __syncthreads();
        sh[threadIdx.x] += t;
        __syncthreads();
    }
    if (threadIdx.x < (unsigned)nb) bsum[threadIdx.x] = sh[threadIdx.x] - v;
}

__global__ __launch_bounds__(1024) void scan3(unsigned* __restrict__ out,
                                              const unsigned* __restrict__ bsum, int n)
{
    int i = blockIdx.x * 1024 + threadIdx.x;
    if (i < n) out[i] += bsum[blockIdx.x];
}

__global__ __launch_bounds__(256) void fill_user(const int* __restrict__ rows,
                                                 const int* __restrict__ cols,
                                                 const float* __restrict__ vals,
                                                 unsigned* __restrict__ cursor,
                                                 int* __restrict__ pcol,
                                                 float* __restrict__ pval, int n)
{
    int i = blockIdx.x * 256 + threadIdx.x;
    if (i >= n) return;
    unsigned p = atomicAdd(&cursor[rows[i]], 1u);
    pcol[p] = cols[i];
    pval[p] = vals[i];
}

__global__ __launch_bounds__(256) void fill_edge_islot(const int* __restrict__ keys,
                                                       unsigned* __restrict__ cursor,
                                                       int* __restrict__ islot, int n)
{
    int i = blockIdx.x * 256 + threadIdx.x;
    if (i >= n) return;
    unsigned p = atomicAdd(&cursor[keys[i]], 1u);
    islot[i] = (int)p;
}

__global__ __launch_bounds__(256) void fill_rel(const int* __restrict__ head,
                                                const int* __restrict__ tail,
                                                const int* __restrict__ etyp,
                                                const int* __restrict__ islot,
                                                unsigned* __restrict__ rcur,
                                                int4* __restrict__ emeta, int n)
{
    __shared__ unsigned lcnt[NRELMAX];
    __shared__ unsigned lbase[NRELMAX];
    const int tid = threadIdx.x;
    if (tid < NRELMAX) lcnt[tid] = 0;
    __syncthreads();
    int i = blockIdx.x * 256 + tid;
    int r = 0;
    unsigned lpos = 0;
    if (i < n) {
        r = etyp[i] - 1;
        lpos = atomicAdd(&lcnt[r], 1u);
    }
    __syncthreads();
    if (tid < NRELMAX) {
        unsigned c = lcnt[tid];
        lbase[tid] = c ? atomicAdd(&rcur[tid], c) : 0u;
    }
    __syncthreads();
    if (i < n) {
        unsigned p = lbase[r] + lpos;
        emeta[p] = make_int4(head[i], tail[i], islot[i], r);
    }
}

// ---------- MFMA score pass: 16 same-rel edges per step ----------
__global__ __launch_bounds__(256, 2) void score_mfma(
    const __hip_bfloat16* __restrict__ Qb, const __hip_bfloat16* __restrict__ Kb,
    const float* __restrict__ att, const int4* __restrict__ emeta,
    float* __restrict__ SC, long E, int chunk)
{
    const int wv = (blockIdx.x * 256 + threadIdx.x) >> 6;
    const int l = threadIdx.x & 63;
    const int g = l >> 4;      // k-octet / dim-group
    const int c = l & 15;      // edge column
    long j0 = (long)wv * chunk;
    if (j0 >= E) return;
    long j1 = j0 + chunk; if (j1 > E) j1 = E;

    bf16x8 aK[4][2];
    int currel = -1;
    long pos = j0;
    while (pos < j1) {
        long e = pos + c;
        long ec = (e < j1) ? e : (j1 - 1);
        const int4 md = emeta[ec];
        int rel0 = __shfl(md.w, 0, 64);
        unsigned long long mask = __ballot(e < j1 && md.w == rel0);
        int cnt = (int)__builtin_ctzll(~(mask & 0xFFFFull));
        bool valid = c < cnt;
        if (rel0 != currel) {
            currel = rel0;
            const float* Ar = att + (size_t)rel0 * 4096;
            #pragma unroll
            for (int h = 0; h < 4; ++h)
                #pragma unroll
                for (int s2 = 0; s2 < 2; ++s2) {
                    const float* base = Ar + h * 1024 + s2 * 16 + c;
                    bf16x8 f;
                    #pragma unroll
                    for (int j = 0; j < 8; ++j)
                        f[j] = (short)f2b(base[(g * 8 + j) * 32]);
                    aK[h][s2] = f;
                }
        }
        const int tn = md.y, hn = md.x, slot = md.z;
        #pragma unroll
        for (int h = 0; h < 4; ++h) {
            bf16x8 bk = *(const bf16x8*)(Kb + (size_t)tn * 128 + h * 32 + g * 8);
            f32x4 z = {0.f, 0.f, 0.f, 0.f};
            f32x4 klo = __builtin_amdgcn_mfma_f32_16x16x32_bf16(aK[h][0], bk, z, 0, 0, 0);
            f32x4 khi = __builtin_amdgcn_mfma_f32_16x16x32_bf16(aK[h][1], bk, z, 0, 0, 0);
            const __hip_bfloat16* qp = Qb + (size_t)hn * 128 + h * 32;
            u16x4 q1 = *(const u16x4*)(qp + g * 4);
            u16x4 q2 = *(const u16x4*)(qp + 16 + g * 4);
            float p = 0.f;
            #pragma unroll
            for (int r = 0; r < 4; ++r)
                p += b2f(q1[r]) * klo[r] + b2f(q2[r]) * khi[r];
            p += __shfl_xor(p, 16, 64);
            p += __shfl_xor(p, 32, 64);
            if (g == 0 && valid) SC[(size_t)slot * 4 + h] = p * 0.17677669529663687f;
        }
        pos += cnt;
    }
}

// ---------- MFMA msg pass (per head-pair ROUND): V' into slot order ----------
template <int ROUND>
__global__ __launch_bounds__(256, 2) void msg_mfma(
    const __hip_bfloat16* __restrict__ Vb, const float* __restrict__ msg,
    const int4* __restrict__ emeta, __hip_bfloat16* __restrict__ VPh,
    long E, int chunk)
{
    const int wv = (blockIdx.x * 256 + threadIdx.x) >> 6;
    const int l = threadIdx.x & 63;
    const int g = l >> 4;
    const int c = l & 15;
    long j0 = (long)wv * chunk;
    if (j0 >= E) return;
    long j1 = j0 + chunk; if (j1 > E) j1 = E;

    bf16x8 aM[2][2];
    int currel = -1;
    long pos = j0;
    while (pos < j1) {
        long e = pos + c;
        long ec = (e < j1) ? e : (j1 - 1);
        const int4 md = emeta[ec];
        int rel0 = __shfl(md.w, 0, 64);
        unsigned long long mask = __ballot(e < j1 && md.w == rel0);
        int cnt = (int)__builtin_ctzll(~(mask & 0xFFFFull));
        bool valid = c < cnt;
        if (rel0 != currel) {
            currel = rel0;
            const float* Mr = msg + (size_t)rel0 * 4096;
            #pragma unroll
            for (int hl = 0; hl < 2; ++hl)
                #pragma unroll
                for (int s2 = 0; s2 < 2; ++s2) {
                    const float* base = Mr + (ROUND * 2 + hl) * 1024 + s2 * 16 + c;
                    bf16x8 f;
                    #pragma unroll
                    for (int j = 0; j < 8; ++j)
                        f[j] = (short)f2b(base[(g * 8 + j) * 32]);
                    aM[hl][s2] = f;
                }
        }
        const int tn = md.y, slot = md.z;
        #pragma unroll
        for (int hl = 0; hl < 2; ++hl) {
            const int h = ROUND * 2 + hl;
            bf16x8 bv = *(const bf16x8*)(Vb + (size_t)tn * 128 + h * 32 + g * 8);
            f32x4 z = {0.f, 0.f, 0.f, 0.f};
            f32x4 vlo = __builtin_amdgcn_mfma_f32_16x16x32_bf16(aM[hl][0], bv, z, 0, 0, 0);
            f32x4 vhi = __builtin_amdgcn_mfma_f32_16x16x32_bf16(aM[hl][1], bv, z, 0, 0, 0);
            if (valid) {
                u16x4 plo, phi;
                #pragma unroll
                for (int r = 0; r < 4; ++r) { plo[r] = f2b(vlo[r]); phi[r] = f2b(vhi[r]); }
                __hip_bfloat16* dst = VPh + (size_t)slot * 64 + hl * 32;
                *(u16x4*)(dst + g * 4) = plo;
                *(u16x4*)(dst + 16 + g * 4) = phi;
            }
        }
        pos += cnt;
    }
}

// ---------- node pass (per head-pair ROUND): softmax + accumulate ----------
template <int ROUND>
__global__ __launch_bounds__(256) void node_pass(
    const float* __restrict__ SC, const __hip_bfloat16* __restrict__ VPh,
    const unsigned* __restrict__ ecur, __hip_bfloat16* __restrict__ M, int n)
{
    int node = (blockIdx.x * 256 + threadIdx.x) >> 6;
    if (node >= n) return;
    int l = threadIdx.x & 63;
    int half = l >> 5;
    const int h = ROUND * 2 + half;
    unsigned beg = node ? ecur[node - 1] : 0u;
    unsigned end = ecur[node];
    float mx = -INFINITY;
    for (unsigned j = beg; j < end; ++j) mx = fmaxf(mx, SC[(size_t)j * 4 + h]);
    float dn = 0.f;
    for (unsigned j = beg; j < end; ++j) dn += __expf(SC[(size_t)j * 4 + h] - mx);
    float inv = (end > beg) ? 1.f / dn : 0.f;
    float acc = 0.f;
    for (unsigned j = beg; j < end; ++j) {
        float w = __expf(SC[(size_t)j * 4 + h] - mx) * inv;
        acc = fmaf(w, __bfloat162float(VPh[(size_t)j * 64 + l]), acc);
    }
    M[(size_t)node * 128 + ROUND * 64 + l] = __float2bfloat16(acc);
}

// ---------- per-user gather (bf16 emb: 256B/row) ----------
__global__ __launch_bounds__(256) void user_gather(
    const __hip_bfloat16* __restrict__ embb, const unsigned* __restrict__ ucur,
    const int* __restrict__ pcol, const float* __restrict__ pval,
    float* __restrict__ out, int nu)
{
    int u = (blockIdx.x * 256 + threadIdx.x) >> 6;
    if (u >= nu) return;
    int l = threadIdx.x & 63;
    unsigned beg = u ? ucur[u - 1] : 0u;
    unsigned end = ucur[u];
    float a0 = 0.f, a1 = 0.f;
    for (unsigned j = beg; j < end; ++j) {
        int c = pcol[j];
        float v = pval[j];
        unsigned e = *((const unsigned*)(embb + (size_t)c * 128) + l);
        a0 = fmaf(b2f((unsigned short)(e & 0xFFFF)), v, a0);
        a1 = fmaf(b2f((unsigned short)(e >> 16)), v, a1);
    }
    *(float2*)(out + (size_t)u * 128 + l * 2) = make_float2(a0, a1);
}

extern "C" void kernel_launch(void* const* d_in, const int* in_sizes, int n_in,
                              void* d_out, int out_size, void* d_ws, size_t ws_size,
                              hipStream_t stream)
{
    const float* emb = (const float*)d_in[0];
    const float* W_Q = (const float*)d_in[1];
    const float* W_K = (const float*)d_in[2];
    const float* W_V = (const float*)d_in[3];
    const float* W_O = (const float*)d_in[4];
    const float* att = (const float*)d_in[5];
    const float* msg = (const float*)d_in[6];
    const int* eidx  = (const int*)d_in[8];
    const int* etyp  = (const int*)d_in[9];
    const int* irow  = (const int*)d_in[10];
    const int* icol  = (const int*)d_in[11];
    const float* ival = (const float*)d_in[12];

    const int N    = in_sizes[0] / 128;
    const int E    = in_sizes[8] / 2;
    const int NNZ  = in_sizes[10];
    const int NU   = out_size / 128 - N;
    const int NREL = in_sizes[5] / 4096;   // = NREL-1 actual relation slots

    const int* head = eidx;
    const int* tail = eidx + E;

    // ---- workspace layout (~156 MB total; proven capacity >= 166 MB) ----
    const size_t NC = (size_t)N * 128;
    __hip_bfloat16* VPh = (__hip_bfloat16*)d_ws;          // E*64 bf16 (written after overlays die)
    __hip_bfloat16* Qb  = (__hip_bfloat16*)d_ws;          // N*128 bf16 (overlay in VPh region)
    __hip_bfloat16* Kb  = Qb + NC;                        // N*128 bf16 (overlay)
    int* islot          = (int*)(Kb + NC);                // E ints (overlay, dead after fill_rel)

    char* p = (char*)d_ws + (size_t)E * 64 * 2;
    __hip_bfloat16* Vb = (__hip_bfloat16*)p; p += NC * 2;           // N*128 bf16
    int4* emeta        = (int4*)p;           p += (size_t)E * 16;   // rel-sorted metadata
    float* SC          = (float*)p;          p += (size_t)E * 16;   // E*4 f32 scores
    unsigned* ecnt     = (unsigned*)p;       p += (size_t)N * 4;    // head-CSR offsets
    unsigned* rcnt     = (unsigned*)p;       p += 32 * 4;           // rel offsets
    unsigned* bsum     = (unsigned*)p;       p += 1024 * 4;         // scan scratch
    __hip_bfloat16* M  = (__hip_bfloat16*)p; p += NC * 2;           // N*128 bf16 (reused as embb)
    unsigned* ucnt     = (unsigned*)p;       p += (size_t)((NU + 255) & ~255) * 4;
    unsigned* bsumU    = (unsigned*)p;       p += 1024 * 4;
    int* pcol          = (int*)p;            p += (size_t)NNZ * 4;
    float* pval        = (float*)p;          p += (size_t)NNZ * 4;
    __hip_bfloat16* WtQ = (__hip_bfloat16*)p; p += 16384 * 2;       // 4 transposed bf16 weights
    __hip_bfloat16* WtK = (__hip_bfloat16*)p; p += 16384 * 2;
    __hip_bfloat16* WtV = (__hip_bfloat16*)p; p += 16384 * 2;
    __hip_bfloat16* WtO = (__hip_bfloat16*)p; p += 16384 * 2;
    __hip_bfloat16* embb = M;   // alias: M dead after W_O GEMM

    float* out_ent = (float*)d_out;
    float* out_usr = out_ent + NC;

    hipMemsetAsync(ecnt, 0, (size_t)N * 4 + 32 * 4 + 1024 * 4, stream);
    hipMemsetAsync(ucnt, 0, (size_t)NU * 4, stream);

    // weight transposes (bf16)
    trans_w<<<64, 256, 0, stream>>>(W_Q, WtQ);
    trans_w<<<64, 256, 0, stream>>>(W_K, WtK);
    trans_w<<<64, 256, 0, stream>>>(W_V, WtV);
    trans_w<<<64, 256, 0, stream>>>(W_O, WtO);

    // Q/K/V projections via MFMA (f32 A, bf16 out)
    int gg = (N + 127) / 128;
    mfma_gemm<float, __hip_bfloat16><<<gg, 256, 0, stream>>>(emb, WtQ, Qb, N);
    mfma_gemm<float, __hip_bfloat16><<<gg, 256, 0, stream>>>(emb, WtK, Kb, N);
    mfma_gemm<float, __hip_bfloat16><<<gg, 256, 0, stream>>>(emb, WtV, Vb, N);

    // head-CSR + rel-sorted metadata
    bin_count<<<(E + 255) / 256, 256, 0, stream>>>(head, ecnt, E);
    rel_count<<<(E + 255) / 256, 256, 0, stream>>>(etyp, rcnt, E);
    scan1<<<1, 1024, 0, stream>>>(rcnt, rcnt, bsum, NREL);
    int nbE = (N + 1023) / 1024;
    scan1<<<nbE, 1024, 0, stream>>>(ecnt, ecnt, bsum, N);
    scan2<<<1, 1024, 0, stream>>>(bsum, nbE);
    scan3<<<nbE, 1024, 0, stream>>>(ecnt, bsum, N);
    fill_edge_islot<<<(E + 255) / 256, 256, 0, stream>>>(head, ecnt, islot, E);
    fill_rel<<<(E + 255) / 256, 256, 0, stream>>>(head, tail, etyp, islot, rcnt, emeta, E);
    // ecnt now holds end-boundaries per node

    const int NWAVE = 8192;
    int chunk = (E + NWAVE - 1) / NWAVE;
    score_mfma<<<NWAVE / 4, 256, 0, stream>>>(Qb, Kb, att, emeta, SC, E, chunk);
    // Qb/Kb/islot dead -> VPh region free

    msg_mfma<0><<<NWAVE / 4, 256, 0, stream>>>(Vb, msg, emeta, VPh, E, chunk);
    node_pass<0><<<(N + 3) / 4, 256, 0, stream>>>(SC, VPh, ecnt, M, N);
    msg_mfma<1><<<NWAVE / 4, 256, 0, stream>>>(Vb, msg, emeta, VPh, E, chunk);
    node_pass<1><<<(N + 3) / 4, 256, 0, stream>>>(SC, VPh, ecnt, M, N);

    // entity output GEMM via MFMA (bf16 A, f32 out)
    mfma_gemm<__hip_bfloat16, float><<<gg, 256, 0, stream>>>(M, WtO, out_ent, N);

    // emb -> bf16 into M region (M dead now)
    conv_emb<<<(int)((NC / 4 + 255) / 256), 256, 0, stream>>>(emb, embb, (long)(NC / 4));

    // user aggregation via CSR gather
    bin_count<<<(NNZ + 255) / 256, 256, 0, stream>>>(irow, ucnt, NNZ);
    int nbU = (NU + 1023) / 1024;
    scan1<<<nbU, 1024, 0, stream>>>(ucnt, ucnt, bsumU, NU);
    scan2<<<1, 1024, 0, stream>>>(bsumU, nbU);
    scan3<<<nbU, 1024, 0, stream>>>(ucnt, bsumU, NU);
    fill_user<<<(NNZ + 255) / 256, 256, 0, stream>>>(irow, icol, ival, ucnt, pcol, pval, NNZ);
    user_gather<<<(NU + 3) / 4, 256, 0, stream>>>(embb, ucnt, pcol, pval, out_usr, NU);
}

// Round 11
// 701.852 us; speedup vs baseline: 5.4123x; 1.1476x over previous
//
#include <hip/hip_runtime.h>
#include <hip/hip_bf16.h>
#include <math.h>

typedef __attribute__((ext_vector_type(8))) unsigned short u16x8;
typedef __attribute__((ext_vector_type(4))) unsigned short u16x4;
typedef __attribute__((ext_vector_type(8))) short bf16x8;   // MFMA A/B frag (8 bf16)
typedef __attribute__((ext_vector_type(4))) float f32x4;    // MFMA C/D frag

#define NRELMAX 32

__device__ __forceinline__ float b2f(unsigned short u) {
    return __uint_as_float(((unsigned)u) << 16);
}
__device__ __forceinline__ unsigned short f2b(float v) {
    __hip_bfloat16 b = __float2bfloat16(v);
    return *reinterpret_cast<unsigned short*>(&b);
}

// ---------- MFMA GEMM frag loaders ----------
__device__ __forceinline__ bf16x8 lda_frag(const float* p) {
    float4 a = *(const float4*)p;
    float4 b = *(const float4*)(p + 4);
    bf16x8 f;
    f[0] = (short)f2b(a.x); f[1] = (short)f2b(a.y);
    f[2] = (short)f2b(a.z); f[3] = (short)f2b(a.w);
    f[4] = (short)f2b(b.x); f[5] = (short)f2b(b.y);
    f[6] = (short)f2b(b.z); f[7] = (short)f2b(b.w);
    return f;
}
__device__ __forceinline__ bf16x8 lda_frag(const __hip_bfloat16* p) {
    return *(const bf16x8*)p;
}
__device__ __forceinline__ void st_o(__hip_bfloat16* p, float v) { *p = __float2bfloat16(v); }
__device__ __forceinline__ void st_o(float* p, float v) { *p = v; }

// ---------- fused QKV MFMA GEMM: 3 outputs, one pass over A ----------
__global__ __launch_bounds__(256) void qkv_gemm(
    const float* __restrict__ A,
    const __hip_bfloat16* __restrict__ WtQ, const __hip_bfloat16* __restrict__ WtK,
    const __hip_bfloat16* __restrict__ WtV,
    __hip_bfloat16* __restrict__ Qb, __hip_bfloat16* __restrict__ Kb,
    __hip_bfloat16* __restrict__ Vb, int n)
{
    const int tid = threadIdx.x;
    const int w = tid >> 6;
    const int l = tid & 63;
    const int q = l >> 4;
    const int c16 = l & 15;
    const int wr = (w >> 1) * 64;
    const int wc = (w & 1) * 64;
    const long row0 = (long)blockIdx.x * 128;

    const __hip_bfloat16* Wt[3] = {WtQ, WtK, WtV};
    f32x4 acc[3][4][4] = {};
    #pragma unroll
    for (int ks = 0; ks < 4; ++ks) {
        bf16x8 af[4];
        #pragma unroll
        for (int rb = 0; rb < 4; ++rb) {
            long r = row0 + wr + rb * 16 + c16;
            if (r >= n) r = n - 1;
            af[rb] = lda_frag(A + r * 128 + ks * 32 + q * 8);
        }
        #pragma unroll
        for (int o = 0; o < 3; ++o) {
            #pragma unroll
            for (int cb = 0; cb < 4; ++cb) {
                bf16x8 wf = *(const bf16x8*)(Wt[o] + (size_t)(wc + cb * 16 + c16) * 128 + ks * 32 + q * 8);
                #pragma unroll
                for (int rb = 0; rb < 4; ++rb)
                    acc[o][rb][cb] = __builtin_amdgcn_mfma_f32_16x16x32_bf16(af[rb], wf, acc[o][rb][cb], 0, 0, 0);
            }
        }
    }
    __hip_bfloat16* Out[3] = {Qb, Kb, Vb};
    #pragma unroll
    for (int o = 0; o < 3; ++o) {
        #pragma unroll
        for (int rb = 0; rb < 4; ++rb) {
            #pragma unroll
            for (int r = 0; r < 4; ++r) {
                long row = row0 + wr + rb * 16 + q * 4 + r;
                if (row < n) {
                    #pragma unroll
                    for (int cb = 0; cb < 4; ++cb)
                        st_o(Out[o] + row * 128 + wc + cb * 16 + c16, acc[o][rb][cb][r]);
                }
            }
        }
    }
}

// ---------- single MFMA GEMM (for W_O) ----------
template <typename TA, typename TO>
__global__ __launch_bounds__(256) void mfma_gemm(const TA* __restrict__ A,
                                                 const __hip_bfloat16* __restrict__ Wt,
                                                 TO* __restrict__ out, int n)
{
    const int tid = threadIdx.x;
    const int w = tid >> 6;
    const int l = tid & 63;
    const int q = l >> 4;
    const int c16 = l & 15;
    const int wr = (w >> 1) * 64;
    const int wc = (w & 1) * 64;
    const long row0 = (long)blockIdx.x * 128;

    f32x4 acc[4][4] = {};
    #pragma unroll
    for (int ks = 0; ks < 4; ++ks) {
        bf16x8 af[4];
        #pragma unroll
        for (int rb = 0; rb < 4; ++rb) {
            long r = row0 + wr + rb * 16 + c16;
            if (r >= n) r = n - 1;
            af[rb] = lda_frag(A + r * 128 + ks * 32 + q * 8);
        }
        #pragma unroll
        for (int cb = 0; cb < 4; ++cb) {
            bf16x8 wf = *(const bf16x8*)(Wt + (size_t)(wc + cb * 16 + c16) * 128 + ks * 32 + q * 8);
            #pragma unroll
            for (int rb = 0; rb < 4; ++rb)
                acc[rb][cb] = __builtin_amdgcn_mfma_f32_16x16x32_bf16(af[rb], wf, acc[rb][cb], 0, 0, 0);
        }
    }
    #pragma unroll
    for (int rb = 0; rb < 4; ++rb) {
        #pragma unroll
        for (int r = 0; r < 4; ++r) {
            long row = row0 + wr + rb * 16 + q * 4 + r;
            if (row < n) {
                #pragma unroll
                for (int cb = 0; cb < 4; ++cb)
                    st_o(out + row * 128 + wc + cb * 16 + c16, acc[rb][cb][r]);
            }
        }
    }
}

// ---------- all-4 W transpose+convert: Wt[c][k] = bf16(W[k][c]) ----------
__global__ __launch_bounds__(256) void trans_w4(
    const float* __restrict__ W0, const float* __restrict__ W1,
    const float* __restrict__ W2, const float* __restrict__ W3,
    __hip_bfloat16* __restrict__ T0, __hip_bfloat16* __restrict__ T1,
    __hip_bfloat16* __restrict__ T2, __hip_bfloat16* __restrict__ T3)
{
    int t = blockIdx.x * 256 + threadIdx.x;   // 65536 threads
    int w = t >> 14, r = t & 16383;
    const float* W = (w == 0) ? W0 : (w == 1) ? W1 : (w == 2) ? W2 : W3;
    __hip_bfloat16* T = (w == 0) ? T0 : (w == 1) ? T1 : (w == 2) ? T2 : T3;
    int k = r >> 7, c = r & 127;
    T[(size_t)c * 128 + k] = __float2bfloat16(W[(size_t)k * 128 + c]);
}

// ---------- emb f32 -> bf16 convert (into dead M region) ----------
__global__ __launch_bounds__(256) void conv_emb(const float* __restrict__ emb,
                                                __hip_bfloat16* __restrict__ embb, long n4)
{
    long i = ((long)blockIdx.x * 256 + threadIdx.x) * 4;
    if (i >= n4 * 4) return;
    float4 v = *(const float4*)(emb + i);
    u16x4 o;
    o[0] = f2b(v.x); o[1] = f2b(v.y); o[2] = f2b(v.z); o[3] = f2b(v.w);
    *(u16x4*)(embb + i) = o;
}

// ---------- histogram / scan / fill machinery ----------
__global__ __launch_bounds__(256) void bin_count(const int* __restrict__ keys,
                                                 unsigned* __restrict__ cnt, int n)
{
    int i = blockIdx.x * 256 + threadIdx.x;
    if (i < n) atomicAdd(&cnt[keys[i]], 1u);
}

// fused: head histogram (global atomics, 100K addrs) + rel histogram (LDS-agg)
__global__ __launch_bounds__(256) void count_both(const int* __restrict__ head,
                                                  const int* __restrict__ etyp,
                                                  unsigned* __restrict__ ecnt,
                                                  unsigned* __restrict__ rcnt, int n)
{
    __shared__ unsigned lcnt[NRELMAX];
    const int tid = threadIdx.x;
    if (tid < NRELMAX) lcnt[tid] = 0;
    __syncthreads();
    int i = blockIdx.x * 256 + tid;
    if (i < n) {
        atomicAdd(&ecnt[head[i]], 1u);
        atomicAdd(&lcnt[etyp[i] - 1], 1u);
    }
    __syncthreads();
    if (tid < NRELMAX) {
        unsigned c = lcnt[tid];
        if (c) atomicAdd(&rcnt[tid], c);
    }
}

__global__ __launch_bounds__(1024) void scan1(const unsigned* __restrict__ in,
                                              unsigned* __restrict__ out,
                                              unsigned* __restrict__ bsum, int n)
{
    __shared__ unsigned sh[1024];
    int i = blockIdx.x * 1024 + threadIdx.x;
    unsigned v = (i < n) ? in[i] : 0u;
    sh[threadIdx.x] = v;
    __syncthreads();
    for (int off = 1; off < 1024; off <<= 1) {
        unsigned t = (threadIdx.x >= (unsigned)off) ? sh[threadIdx.x - off] : 0u;
        __syncthreads();
        sh[threadIdx.x] += t;
        __syncthreads();
    }
    if (i < n) out[i] = sh[threadIdx.x] - v;  // exclusive
    if (threadIdx.x == 1023) bsum[blockIdx.x] = sh[1023];
}

__global__ __launch_bounds__(1024) void scan2(unsigned* __restrict__ bsum, int nb)
{
    __shared__ unsigned sh[1024];
    unsigned v = (threadIdx.x < (unsigned)nb) ? bsum[threadIdx.x] : 0u;
    sh[threadIdx.x] = v;
    __syncthreads();
    for (int off = 1; off < 1024; off <<= 1) {
        unsigned t = (threadIdx.x >= (unsigned)off) ? sh[threadIdx.x - off] : 0u;
        __syncthreads();
        sh[threadIdx.x] += t;
        __syncthreads();
    }
    if (threadIdx.x < (unsigned)nb) bsum[threadIdx.x] = sh[threadIdx.x] - v;
}

__global__ __launch_bounds__(1024) void scan3(unsigned* __restrict__ out,
                                              const unsigned* __restrict__ bsum, int n)
{
    int i = blockIdx.x * 1024 + threadIdx.x;
    if (i < n) out[i] += bsum[blockIdx.x];
}

__global__ __launch_bounds__(256) void fill_user(const int* __restrict__ rows,
                                                 const int* __restrict__ cols,
                                                 const float* __restrict__ vals,
                                                 unsigned* __restrict__ cursor,
                                                 int* __restrict__ pcol,
                                                 float* __restrict__ pval, int n)
{
    int i = blockIdx.x * 256 + threadIdx.x;
    if (i >= n) return;
    unsigned p = atomicAdd(&cursor[rows[i]], 1u);
    pcol[p] = cols[i];
    pval[p] = vals[i];
}

// fused edge fill: head-cursor atomic (slot) + LDS-agg rel-cursor -> emeta
__global__ __launch_bounds__(256) void fill_both(const int* __restrict__ head,
                                                 const int* __restrict__ tail,
                                                 const int* __restrict__ etyp,
                                                 unsigned* __restrict__ ecur,
                                                 unsigned* __restrict__ rcur,
                                                 int4* __restrict__ emeta, int n)
{
    __shared__ unsigned lcnt[NRELMAX];
    __shared__ unsigned lbase[NRELMAX];
    const int tid = threadIdx.x;
    if (tid < NRELMAX) lcnt[tid] = 0;
    __syncthreads();
    int i = blockIdx.x * 256 + tid;
    int r = 0;
    unsigned lpos = 0;
    if (i < n) {
        r = etyp[i] - 1;
        lpos = atomicAdd(&lcnt[r], 1u);
    }
    __syncthreads();
    if (tid < NRELMAX) {
        unsigned c = lcnt[tid];
        lbase[tid] = c ? atomicAdd(&rcur[tid], c) : 0u;
    }
    __syncthreads();
    if (i < n) {
        int hn = head[i];
        unsigned slot = atomicAdd(&ecur[hn], 1u);
        emeta[lbase[r] + lpos] = make_int4(hn, tail[i], (int)slot, r);
    }
}

// ---------- MFMA score pass: 16 same-rel edges per step ----------
__global__ __launch_bounds__(256, 2) void score_mfma(
    const __hip_bfloat16* __restrict__ Qb, const __hip_bfloat16* __restrict__ Kb,
    const float* __restrict__ att, const int4* __restrict__ emeta,
    float* __restrict__ SC, long E, int chunk)
{
    const int wv = (blockIdx.x * 256 + threadIdx.x) >> 6;
    const int l = threadIdx.x & 63;
    const int g = l >> 4;      // k-octet / dim-group
    const int c = l & 15;      // edge column
    long j0 = (long)wv * chunk;
    if (j0 >= E) return;
    long j1 = j0 + chunk; if (j1 > E) j1 = E;

    bf16x8 aK[4][2];
    int currel = -1;
    long pos = j0;
    while (pos < j1) {
        long e = pos + c;
        long ec = (e < j1) ? e : (j1 - 1);
        const int4 md = emeta[ec];
        int rel0 = __shfl(md.w, 0, 64);
        unsigned long long mask = __ballot(e < j1 && md.w == rel0);
        int cnt = (int)__builtin_ctzll(~(mask & 0xFFFFull));
        bool valid = c < cnt;
        if (rel0 != currel) {
            currel = rel0;
            const float* Ar = att + (size_t)rel0 * 4096;
            #pragma unroll
            for (int h = 0; h < 4; ++h)
                #pragma unroll
                for (int s2 = 0; s2 < 2; ++s2) {
                    const float* base = Ar + h * 1024 + s2 * 16 + c;
                    bf16x8 f;
                    #pragma unroll
                    for (int j = 0; j < 8; ++j)
                        f[j] = (short)f2b(base[(g * 8 + j) * 32]);
                    aK[h][s2] = f;
                }
        }
        const int tn = md.y, hn = md.x, slot = md.z;
        #pragma unroll
        for (int h = 0; h < 4; ++h) {
            bf16x8 bk = *(const bf16x8*)(Kb + (size_t)tn * 128 + h * 32 + g * 8);
            f32x4 z = {0.f, 0.f, 0.f, 0.f};
            f32x4 klo = __builtin_amdgcn_mfma_f32_16x16x32_bf16(aK[h][0], bk, z, 0, 0, 0);
            f32x4 khi = __builtin_amdgcn_mfma_f32_16x16x32_bf16(aK[h][1], bk, z, 0, 0, 0);
            const __hip_bfloat16* qp = Qb + (size_t)hn * 128 + h * 32;
            u16x4 q1 = *(const u16x4*)(qp + g * 4);
            u16x4 q2 = *(const u16x4*)(qp + 16 + g * 4);
            float p = 0.f;
            #pragma unroll
            for (int r = 0; r < 4; ++r)
                p += b2f(q1[r]) * klo[r] + b2f(q2[r]) * khi[r];
            p += __shfl_xor(p, 16, 64);
            p += __shfl_xor(p, 32, 64);
            if (g == 0 && valid) SC[(size_t)slot * 4 + h] = p * 0.17677669529663687f;
        }
        pos += cnt;
    }
}

// ---------- MFMA msg pass (per head-pair ROUND): V' into slot order ----------
template <int ROUND>
__global__ __launch_bounds__(256, 2) void msg_mfma(
    const __hip_bfloat16* __restrict__ Vb, const float* __restrict__ msg,
    const int4* __restrict__ emeta, __hip_bfloat16* __restrict__ VPh,
    long E, int chunk)
{
    const int wv = (blockIdx.x * 256 + threadIdx.x) >> 6;
    const int l = threadIdx.x & 63;
    const int g = l >> 4;
    const int c = l & 15;
    long j0 = (long)wv * chunk;
    if (j0 >= E) return;
    long j1 = j0 + chunk; if (j1 > E) j1 = E;

    bf16x8 aM[2][2];
    int currel = -1;
    long pos = j0;
    while (pos < j1) {
        long e = pos + c;
        long ec = (e < j1) ? e : (j1 - 1);
        const int4 md = emeta[ec];
        int rel0 = __shfl(md.w, 0, 64);
        unsigned long long mask = __ballot(e < j1 && md.w == rel0);
        int cnt = (int)__builtin_ctzll(~(mask & 0xFFFFull));
        bool valid = c < cnt;
        if (rel0 != currel) {
            currel = rel0;
            const float* Mr = msg + (size_t)rel0 * 4096;
            #pragma unroll
            for (int hl = 0; hl < 2; ++hl)
                #pragma unroll
                for (int s2 = 0; s2 < 2; ++s2) {
                    const float* base = Mr + (ROUND * 2 + hl) * 1024 + s2 * 16 + c;
                    bf16x8 f;
                    #pragma unroll
                    for (int j = 0; j < 8; ++j)
                        f[j] = (short)f2b(base[(g * 8 + j) * 32]);
                    aM[hl][s2] = f;
                }
        }
        const int tn = md.y, slot = md.z;
        #pragma unroll
        for (int hl = 0; hl < 2; ++hl) {
            const int h = ROUND * 2 + hl;
            bf16x8 bv = *(const bf16x8*)(Vb + (size_t)tn * 128 + h * 32 + g * 8);
            f32x4 z = {0.f, 0.f, 0.f, 0.f};
            f32x4 vlo = __builtin_amdgcn_mfma_f32_16x16x32_bf16(aM[hl][0], bv, z, 0, 0, 0);
            f32x4 vhi = __builtin_amdgcn_mfma_f32_16x16x32_bf16(aM[hl][1], bv, z, 0, 0, 0);
            if (valid) {
                u16x4 plo, phi;
                #pragma unroll
                for (int r = 0; r < 4; ++r) { plo[r] = f2b(vlo[r]); phi[r] = f2b(vhi[r]); }
                __hip_bfloat16* dst = VPh + (size_t)slot * 64 + hl * 32;
                *(u16x4*)(dst + g * 4) = plo;
                *(u16x4*)(dst + 16 + g * 4) = phi;
            }
        }
        pos += cnt;
    }
}

// ---------- node pass (per head-pair ROUND): online softmax + accumulate ----------
template <int ROUND>
__global__ __launch_bounds__(256) void node_pass(
    const float* __restrict__ SC, const __hip_bfloat16* __restrict__ VPh,
    const unsigned* __restrict__ ecur, __hip_bfloat16* __restrict__ M, int n)
{
    int node = (blockIdx.x * 256 + threadIdx.x) >> 6;
    if (node >= n) return;
    int l = threadIdx.x & 63;
    int half = l >> 5;
    const int h = ROUND * 2 + half;
    unsigned beg = node ? ecur[node - 1] : 0u;
    unsigned end = ecur[node];
    float mx = -INFINITY, dn = 0.f;
    for (unsigned j = beg; j < end; ++j) {
        float s = SC[(size_t)j * 4 + h];
        float m2 = fmaxf(mx, s);
        dn = dn * __expf(mx - m2) + __expf(s - m2);
        mx = m2;
    }
    float inv = (end > beg) ? 1.f / dn : 0.f;
    float acc = 0.f;
    for (unsigned j = beg; j < end; ++j) {
        float w = __expf(SC[(size_t)j * 4 + h] - mx) * inv;
        acc = fmaf(w, __bfloat162float(VPh[(size_t)j * 64 + l]), acc);
    }
    M[(size_t)node * 128 + ROUND * 64 + l] = __float2bfloat16(acc);
}

// ---------- per-user gather: 2 users/wave, 32 lanes x 8B ----------
__global__ __launch_bounds__(256) void user_gather(
    const __hip_bfloat16* __restrict__ embb, const unsigned* __restrict__ ucur,
    const int* __restrict__ pcol, const float* __restrict__ pval,
    float* __restrict__ out, int nu)
{
    int u = (blockIdx.x * 256 + threadIdx.x) >> 5;
    if (u >= nu) return;
    int l = threadIdx.x & 31;
    unsigned beg = u ? ucur[u - 1] : 0u;
    unsigned end = ucur[u];
    float a0 = 0.f, a1 = 0.f, a2 = 0.f, a3 = 0.f;
    for (unsigned j = beg; j < end; ++j) {
        int c = pcol[j];
        float v = pval[j];
        uint2 e = *(const uint2*)((const unsigned*)(embb + (size_t)c * 128) + l * 2);
        a0 = fmaf(b2f((unsigned short)(e.x & 0xFFFF)), v, a0);
        a1 = fmaf(b2f((unsigned short)(e.x >> 16)), v, a1);
        a2 = fmaf(b2f((unsigned short)(e.y & 0xFFFF)), v, a2);
        a3 = fmaf(b2f((unsigned short)(e.y >> 16)), v, a3);
    }
    *(float4*)(out + (size_t)u * 128 + l * 4) = make_float4(a0, a1, a2, a3);
}

extern "C" void kernel_launch(void* const* d_in, const int* in_sizes, int n_in,
                              void* d_out, int out_size, void* d_ws, size_t ws_size,
                              hipStream_t stream)
{
    const float* emb = (const float*)d_in[0];
    const float* W_Q = (const float*)d_in[1];
    const float* W_K = (const float*)d_in[2];
    const float* W_V = (const float*)d_in[3];
    const float* W_O = (const float*)d_in[4];
    const float* att = (const float*)d_in[5];
    const float* msg = (const float*)d_in[6];
    const int* eidx  = (const int*)d_in[8];
    const int* etyp  = (const int*)d_in[9];
    const int* irow  = (const int*)d_in[10];
    const int* icol  = (const int*)d_in[11];
    const float* ival = (const float*)d_in[12];

    const int N    = in_sizes[0] / 128;
    const int E    = in_sizes[8] / 2;
    const int NNZ  = in_sizes[10];
    const int NU   = out_size / 128 - N;
    const int NREL = in_sizes[5] / 4096;   // = NREL-1 actual relation slots

    const int* head = eidx;
    const int* tail = eidx + E;

    // ---- workspace layout (~154 MB total; proven capacity >= 163 MB) ----
    const size_t NC = (size_t)N * 128;
    __hip_bfloat16* VPh = (__hip_bfloat16*)d_ws;          // E*64 bf16 (written after overlays die)
    __hip_bfloat16* Qb  = (__hip_bfloat16*)d_ws;          // N*128 bf16 (overlay in VPh region)
    __hip_bfloat16* Kb  = Qb + NC;                        // N*128 bf16 (overlay)

    char* p = (char*)d_ws + (size_t)E * 64 * 2;
    __hip_bfloat16* Vb = (__hip_bfloat16*)p; p += NC * 2;           // N*128 bf16
    int4* emeta        = (int4*)p;           p += (size_t)E * 16;   // rel-sorted metadata
    float* SC          = (float*)p;          p += (size_t)E * 16;   // E*4 f32 scores
    unsigned* ecnt     = (unsigned*)p;       p += (size_t)N * 4;    // head-CSR offsets
    unsigned* rcnt     = (unsigned*)p;       p += 32 * 4;           // rel offsets
    unsigned* bsum     = (unsigned*)p;       p += 1024 * 4;         // scan scratch
    __hip_bfloat16* M  = (__hip_bfloat16*)p; p += NC * 2;           // N*128 bf16 (reused as embb)
    unsigned* ucnt     = (unsigned*)p;       p += (size_t)((NU + 255) & ~255) * 4;
    unsigned* bsumU    = (unsigned*)p;       p += 1024 * 4;
    int* pcol          = (int*)p;            p += (size_t)NNZ * 4;
    float* pval        = (float*)p;          p += (size_t)NNZ * 4;
    __hip_bfloat16* WtQ = (__hip_bfloat16*)p; p += 16384 * 2;       // 4 transposed bf16 weights
    __hip_bfloat16* WtK = (__hip_bfloat16*)p; p += 16384 * 2;
    __hip_bfloat16* WtV = (__hip_bfloat16*)p; p += 16384 * 2;
    __hip_bfloat16* WtO = (__hip_bfloat16*)p; p += 16384 * 2;
    __hip_bfloat16* embb = M;   // alias: M dead after W_O GEMM

    float* out_ent = (float*)d_out;
    float* out_usr = out_ent + NC;

    hipMemsetAsync(ecnt, 0, (size_t)N * 4 + 32 * 4 + 1024 * 4, stream);
    hipMemsetAsync(ucnt, 0, (size_t)NU * 4, stream);

    // weight transposes (bf16), one kernel
    trans_w4<<<256, 256, 0, stream>>>(W_Q, W_K, W_V, W_O, WtQ, WtK, WtV, WtO);

    // fused Q/K/V projection (read emb once)
    int gg = (N + 127) / 128;
    qkv_gemm<<<gg, 256, 0, stream>>>(emb, WtQ, WtK, WtV, Qb, Kb, Vb, N);

    // head-CSR + rel histograms (one pass), scans, fused fill
    count_both<<<(E + 255) / 256, 256, 0, stream>>>(head, etyp, ecnt, rcnt, E);
    scan1<<<1, 1024, 0, stream>>>(rcnt, rcnt, bsum, NREL);
    int nbE = (N + 1023) / 1024;
    scan1<<<nbE, 1024, 0, stream>>>(ecnt, ecnt, bsum, N);
    scan2<<<1, 1024, 0, stream>>>(bsum, nbE);
    scan3<<<nbE, 1024, 0, stream>>>(ecnt, bsum, N);
    fill_both<<<(E + 255) / 256, 256, 0, stream>>>(head, tail, etyp, ecnt, rcnt, emeta, E);
    // ecnt now holds end-boundaries per node

    const int NWAVE = 8192;
    int chunk = (E + NWAVE - 1) / NWAVE;
    score_mfma<<<NWAVE / 4, 256, 0, stream>>>(Qb, Kb, att, emeta, SC, E, chunk);
    // Qb/Kb dead -> VPh region free

    msg_mfma<0><<<NWAVE / 4, 256, 0, stream>>>(Vb, msg, emeta, VPh, E, chunk);
    node_pass<0><<<(N + 3) / 4, 256, 0, stream>>>(SC, VPh, ecnt, M, N);
    msg_mfma<1><<<NWAVE / 4, 256, 0, stream>>>(Vb, msg, emeta, VPh, E, chunk);
    node_pass<1><<<(N + 3) / 4, 256, 0, stream>>>(SC, VPh, ecnt, M, N);

    // entity output GEMM via MFMA (bf16 A, f32 out)
    mfma_gemm<__hip_bfloat16, float><<<gg, 256, 0, stream>>>(M, WtO, out_ent, N);

    // emb -> bf16 into M region (M dead now)
    conv_emb<<<(int)((NC / 4 + 255) / 256), 256, 0, stream>>>(emb, embb, (long)(NC / 4));

    // user aggregation via CSR gather
    bin_count<<<(NNZ + 255) / 256, 256, 0, stream>>>(irow, ucnt, NNZ);
    int nbU = (NU + 1023) / 1024;
    scan1<<<nbU, 1024, 0, stream>>>(ucnt, ucnt, bsumU, NU);
    scan2<<<1, 1024, 0, stream>>>(bsumU, nbU);
    scan3<<<nbU, 1024, 0, stream>>>(ucnt, bsumU, NU);
    fill_user<<<(NNZ + 255) / 256, 256, 0, stream>>>(irow, icol, ival, ucnt, pcol, pval, NNZ);
    user_gather<<<(NU + 7) / 8, 256, 0, stream>>>(embb, ucnt, pcol, pval, out_usr, NU);
}

// Round 12
// 680.566 us; speedup vs baseline: 5.5816x; 1.0313x over previous
//
#include <hip/hip_runtime.h>
#include <hip/hip_bf16.h>
#include <math.h>

typedef __attribute__((ext_vector_type(8))) unsigned short u16x8;
typedef __attribute__((ext_vector_type(4))) unsigned short u16x4;
typedef __attribute__((ext_vector_type(8))) short bf16x8;   // MFMA A/B frag (8 bf16)
typedef __attribute__((ext_vector_type(4))) float f32x4;    // MFMA C/D frag

#define NRELMAX 32

__device__ __forceinline__ float b2f(unsigned short u) {
    return __uint_as_float(((unsigned)u) << 16);
}
__device__ __forceinline__ unsigned short f2b(float v) {
    __hip_bfloat16 b = __float2bfloat16(v);
    return *reinterpret_cast<unsigned short*>(&b);
}

// ---------- MFMA GEMM frag loaders ----------
__device__ __forceinline__ bf16x8 lda_frag(const __hip_bfloat16* p) {
    return *(const bf16x8*)p;
}
__device__ __forceinline__ void st_o(__hip_bfloat16* p, float v) { *p = __float2bfloat16(v); }
__device__ __forceinline__ void st_o(float* p, float v) { *p = v; }

// ---------- MFMA GEMM: out[r][c] = sum_k A[r][k]*W[k][c]; Wt = W^T bf16 ----------
// frag wiring (m89-verified): A lane(row=l%16, koct=l/16) = A[row][koct*8+j];
// B lane(col=l%16, koct) = W[koct*8+j][col]; D reg r -> row=(l>>4)*4+r, col=l&15.
template <typename TO>
__global__ __launch_bounds__(256) void mfma_gemm(const __hip_bfloat16* __restrict__ A,
                                                 const __hip_bfloat16* __restrict__ Wt,
                                                 TO* __restrict__ out, int n)
{
    const int tid = threadIdx.x;
    const int w = tid >> 6;
    const int l = tid & 63;
    const int q = l >> 4;
    const int c16 = l & 15;
    const int wr = (w >> 1) * 64;
    const int wc = (w & 1) * 64;
    const long row0 = (long)blockIdx.x * 128;

    f32x4 acc[4][4] = {};
    #pragma unroll
    for (int ks = 0; ks < 4; ++ks) {
        bf16x8 af[4];
        #pragma unroll
        for (int rb = 0; rb < 4; ++rb) {
            long r = row0 + wr + rb * 16 + c16;
            if (r >= n) r = n - 1;
            af[rb] = lda_frag(A + r * 128 + ks * 32 + q * 8);
        }
        #pragma unroll
        for (int cb = 0; cb < 4; ++cb) {
            bf16x8 wf = *(const bf16x8*)(Wt + (size_t)(wc + cb * 16 + c16) * 128 + ks * 32 + q * 8);
            #pragma unroll
            for (int rb = 0; rb < 4; ++rb)
                acc[rb][cb] = __builtin_amdgcn_mfma_f32_16x16x32_bf16(af[rb], wf, acc[rb][cb], 0, 0, 0);
        }
    }
    #pragma unroll
    for (int rb = 0; rb < 4; ++rb) {
        #pragma unroll
        for (int r = 0; r < 4; ++r) {
            long row = row0 + wr + rb * 16 + q * 4 + r;
            if (row < n) {
                #pragma unroll
                for (int cb = 0; cb < 4; ++cb)
                    st_o(out + row * 128 + wc + cb * 16 + c16, acc[rb][cb][r]);
            }
        }
    }
}

// ---------- all-4 W transpose+convert: Wt[c][k] = bf16(W[k][c]) ----------
__global__ __launch_bounds__(256) void trans_w4(
    const float* __restrict__ W0, const float* __restrict__ W1,
    const float* __restrict__ W2, const float* __restrict__ W3,
    __hip_bfloat16* __restrict__ T0, __hip_bfloat16* __restrict__ T1,
    __hip_bfloat16* __restrict__ T2, __hip_bfloat16* __restrict__ T3)
{
    int t = blockIdx.x * 256 + threadIdx.x;   // 65536 threads
    int w = t >> 14, r = t & 16383;
    const float* W = (w == 0) ? W0 : (w == 1) ? W1 : (w == 2) ? W2 : W3;
    __hip_bfloat16* T = (w == 0) ? T0 : (w == 1) ? T1 : (w == 2) ? T2 : T3;
    int k = r >> 7, c = r & 127;
    T[(size_t)c * 128 + k] = __float2bfloat16(W[(size_t)k * 128 + c]);
}

// ---------- emb f32 -> bf16 ----------
__global__ __launch_bounds__(256) void conv_emb(const float* __restrict__ emb,
                                                __hip_bfloat16* __restrict__ embb, long n4)
{
    long i = ((long)blockIdx.x * 256 + threadIdx.x) * 4;
    if (i >= n4 * 4) return;
    float4 v = *(const float4*)(emb + i);
    u16x4 o;
    o[0] = f2b(v.x); o[1] = f2b(v.y); o[2] = f2b(v.z); o[3] = f2b(v.w);
    *(u16x4*)(embb + i) = o;
}

// ---------- histogram / scan / fill machinery ----------
__global__ __launch_bounds__(256) void bin_count(const int* __restrict__ keys,
                                                 unsigned* __restrict__ cnt, int n)
{
    int i = blockIdx.x * 256 + threadIdx.x;
    if (i < n) atomicAdd(&cnt[keys[i]], 1u);
}

__global__ __launch_bounds__(256) void count_both(const int* __restrict__ head,
                                                  const int* __restrict__ etyp,
                                                  unsigned* __restrict__ ecnt,
                                                  unsigned* __restrict__ rcnt, int n)
{
    __shared__ unsigned lcnt[NRELMAX];
    const int tid = threadIdx.x;
    if (tid < NRELMAX) lcnt[tid] = 0;
    __syncthreads();
    int i = blockIdx.x * 256 + tid;
    if (i < n) {
        atomicAdd(&ecnt[head[i]], 1u);
        atomicAdd(&lcnt[etyp[i] - 1], 1u);
    }
    __syncthreads();
    if (tid < NRELMAX) {
        unsigned c = lcnt[tid];
        if (c) atomicAdd(&rcnt[tid], c);
    }
}

__global__ __launch_bounds__(1024) void scan1(const unsigned* __restrict__ in,
                                              unsigned* __restrict__ out,
                                              unsigned* __restrict__ bsum, int n)
{
    __shared__ unsigned sh[1024];
    int i = blockIdx.x * 1024 + threadIdx.x;
    unsigned v = (i < n) ? in[i] : 0u;
    sh[threadIdx.x] = v;
    __syncthreads();
    for (int off = 1; off < 1024; off <<= 1) {
        unsigned t = (threadIdx.x >= (unsigned)off) ? sh[threadIdx.x - off] : 0u;
        __syncthreads();
        sh[threadIdx.x] += t;
        __syncthreads();
    }
    if (i < n) out[i] = sh[threadIdx.x] - v;  // exclusive
    if (threadIdx.x == 1023) bsum[blockIdx.x] = sh[1023];
}

__global__ __launch_bounds__(1024) void scan2(unsigned* __restrict__ bsum, int nb)
{
    __shared__ unsigned sh[1024];
    unsigned v = (threadIdx.x < (unsigned)nb) ? bsum[threadIdx.x] : 0u;
    sh[threadIdx.x] = v;
    __syncthreads();
    for (int off = 1; off < 1024; off <<= 1) {
        unsigned t = (threadIdx.x >= (unsigned)off) ? sh[threadIdx.x - off] : 0u;
        __syncthreads();
        sh[threadIdx.x] += t;
        __syncthreads();
    }
    if (threadIdx.x < (unsigned)nb) bsum[threadIdx.x] = sh[threadIdx.x] - v;
}

__global__ __launch_bounds__(1024) void scan3(unsigned* __restrict__ out,
                                              const unsigned* __restrict__ bsum, int n)
{
    int i = blockIdx.x * 1024 + threadIdx.x;
    if (i < n) out[i] += bsum[blockIdx.x];
}

__global__ __launch_bounds__(256) void fill_user(const int* __restrict__ rows,
                                                 const int* __restrict__ cols,
                                                 const float* __restrict__ vals,
                                                 unsigned* __restrict__ cursor,
                                                 int* __restrict__ pcol,
                                                 float* __restrict__ pval, int n)
{
    int i = blockIdx.x * 256 + threadIdx.x;
    if (i >= n) return;
    unsigned p = atomicAdd(&cursor[rows[i]], 1u);
    pcol[p] = cols[i];
    pval[p] = vals[i];
}

__global__ __launch_bounds__(256) void fill_both(const int* __restrict__ head,
                                                 const int* __restrict__ tail,
                                                 const int* __restrict__ etyp,
                                                 unsigned* __restrict__ ecur,
                                                 unsigned* __restrict__ rcur,
                                                 int4* __restrict__ emeta, int n)
{
    __shared__ unsigned lcnt[NRELMAX];
    __shared__ unsigned lbase[NRELMAX];
    const int tid = threadIdx.x;
    if (tid < NRELMAX) lcnt[tid] = 0;
    __syncthreads();
    int i = blockIdx.x * 256 + tid;
    int r = 0;
    unsigned lpos = 0;
    if (i < n) {
        r = etyp[i] - 1;
        lpos = atomicAdd(&lcnt[r], 1u);
    }
    __syncthreads();
    if (tid < NRELMAX) {
        unsigned c = lcnt[tid];
        lbase[tid] = c ? atomicAdd(&rcur[tid], c) : 0u;
    }
    __syncthreads();
    if (i < n) {
        int hn = head[i];
        unsigned slot = atomicAdd(&ecur[hn], 1u);
        emeta[lbase[r] + lpos] = make_int4(hn, tail[i], (int)slot, r);
    }
}

// ---------- MFMA score pass: 16 same-rel edges per step ----------
__global__ __launch_bounds__(256, 2) void score_mfma(
    const __hip_bfloat16* __restrict__ Qb, const __hip_bfloat16* __restrict__ Kb,
    const float* __restrict__ att, const int4* __restrict__ emeta,
    float* __restrict__ SC, long E, int chunk)
{
    const int wv = (blockIdx.x * 256 + threadIdx.x) >> 6;
    const int l = threadIdx.x & 63;
    const int g = l >> 4;      // k-octet / dim-group
    const int c = l & 15;      // edge column
    long j0 = (long)wv * chunk;
    if (j0 >= E) return;
    long j1 = j0 + chunk; if (j1 > E) j1 = E;

    bf16x8 aK[4][2];
    int currel = -1;
    long pos = j0;
    while (pos < j1) {
        long e = pos + c;
        long ec = (e < j1) ? e : (j1 - 1);
        const int4 md = emeta[ec];
        int rel0 = __shfl(md.w, 0, 64);
        unsigned long long mask = __ballot(e < j1 && md.w == rel0);
        int cnt = (int)__builtin_ctzll(~(mask & 0xFFFFull));
        bool valid = c < cnt;
        if (rel0 != currel) {
            currel = rel0;
            const float* Ar = att + (size_t)rel0 * 4096;
            #pragma unroll
            for (int h = 0; h < 4; ++h)
                #pragma unroll
                for (int s2 = 0; s2 < 2; ++s2) {
                    const float* base = Ar + h * 1024 + s2 * 16 + c;
                    bf16x8 f;
                    #pragma unroll
                    for (int j = 0; j < 8; ++j)
                        f[j] = (short)f2b(base[(g * 8 + j) * 32]);
                    aK[h][s2] = f;
                }
        }
        const int tn = md.y, hn = md.x, slot = md.z;
        #pragma unroll
        for (int h = 0; h < 4; ++h) {
            bf16x8 bk = *(const bf16x8*)(Kb + (size_t)tn * 128 + h * 32 + g * 8);
            f32x4 z = {0.f, 0.f, 0.f, 0.f};
            f32x4 klo = __builtin_amdgcn_mfma_f32_16x16x32_bf16(aK[h][0], bk, z, 0, 0, 0);
            f32x4 khi = __builtin_amdgcn_mfma_f32_16x16x32_bf16(aK[h][1], bk, z, 0, 0, 0);
            const __hip_bfloat16* qp = Qb + (size_t)hn * 128 + h * 32;
            u16x4 q1 = *(const u16x4*)(qp + g * 4);
            u16x4 q2 = *(const u16x4*)(qp + 16 + g * 4);
            float p = 0.f;
            #pragma unroll
            for (int r = 0; r < 4; ++r)
                p += b2f(q1[r]) * klo[r] + b2f(q2[r]) * khi[r];
            p += __shfl_xor(p, 16, 64);
            p += __shfl_xor(p, 32, 64);
            if (g == 0 && valid) SC[(size_t)slot * 4 + h] = p * 0.17677669529663687f;
        }
        pos += cnt;
    }
}

// ---------- MFMA msg pass (per head-pair ROUND): V' into slot order ----------
template <int ROUND>
__global__ __launch_bounds__(256, 2) void msg_mfma(
    const __hip_bfloat16* __restrict__ Vb, const float* __restrict__ msg,
    const int4* __restrict__ emeta, __hip_bfloat16* __restrict__ VPh,
    long E, int chunk)
{
    const int wv = (blockIdx.x * 256 + threadIdx.x) >> 6;
    const int l = threadIdx.x & 63;
    const int g = l >> 4;
    const int c = l & 15;
    long j0 = (long)wv * chunk;
    if (j0 >= E) return;
    long j1 = j0 + chunk; if (j1 > E) j1 = E;

    bf16x8 aM[2][2];
    int currel = -1;
    long pos = j0;
    while (pos < j1) {
        long e = pos + c;
        long ec = (e < j1) ? e : (j1 - 1);
        const int4 md = emeta[ec];
        int rel0 = __shfl(md.w, 0, 64);
        unsigned long long mask = __ballot(e < j1 && md.w == rel0);
        int cnt = (int)__builtin_ctzll(~(mask & 0xFFFFull));
        bool valid = c < cnt;
        if (rel0 != currel) {
            currel = rel0;
            const float* Mr = msg + (size_t)rel0 * 4096;
            #pragma unroll
            for (int hl = 0; hl < 2; ++hl)
                #pragma unroll
                for (int s2 = 0; s2 < 2; ++s2) {
                    const float* base = Mr + (ROUND * 2 + hl) * 1024 + s2 * 16 + c;
                    bf16x8 f;
                    #pragma unroll
                    for (int j = 0; j < 8; ++j)
                        f[j] = (short)f2b(base[(g * 8 + j) * 32]);
                    aM[hl][s2] = f;
                }
        }
        const int tn = md.y, slot = md.z;
        #pragma unroll
        for (int hl = 0; hl < 2; ++hl) {
            const int h = ROUND * 2 + hl;
            bf16x8 bv = *(const bf16x8*)(Vb + (size_t)tn * 128 + h * 32 + g * 8);
            f32x4 z = {0.f, 0.f, 0.f, 0.f};
            f32x4 vlo = __builtin_amdgcn_mfma_f32_16x16x32_bf16(aM[hl][0], bv, z, 0, 0, 0);
            f32x4 vhi = __builtin_amdgcn_mfma_f32_16x16x32_bf16(aM[hl][1], bv, z, 0, 0, 0);
            if (valid) {
                u16x4 plo, phi;
                #pragma unroll
                for (int r = 0; r < 4; ++r) { plo[r] = f2b(vlo[r]); phi[r] = f2b(vhi[r]); }
                __hip_bfloat16* dst = VPh + (size_t)slot * 64 + hl * 32;
                *(u16x4*)(dst + g * 4) = plo;
                *(u16x4*)(dst + 16 + g * 4) = phi;
            }
        }
        pos += cnt;
    }
}

// ---------- node pass (per head-pair ROUND): online softmax + accumulate ----------
template <int ROUND>
__global__ __launch_bounds__(256) void node_pass(
    const float* __restrict__ SC, const __hip_bfloat16* __restrict__ VPh,
    const unsigned* __restrict__ ecur, __hip_bfloat16* __restrict__ M, int n)
{
    int node = (blockIdx.x * 256 + threadIdx.x) >> 6;
    if (node >= n) return;
    int l = threadIdx.x & 63;
    int half = l >> 5;
    const int h = ROUND * 2 + half;
    unsigned beg = node ? ecur[node - 1] : 0u;
    unsigned end = ecur[node];
    float mx = -INFINITY, dn = 0.f;
    for (unsigned j = beg; j < end; ++j) {
        float s = SC[(size_t)j * 4 + h];
        float m2 = fmaxf(mx, s);
        dn = dn * __expf(mx - m2) + __expf(s - m2);
        mx = m2;
    }
    float inv = (end > beg) ? 1.f / dn : 0.f;
    float acc = 0.f;
    for (unsigned j = beg; j < end; ++j) {
        float w = __expf(SC[(size_t)j * 4 + h] - mx) * inv;
        acc = fmaf(w, __bfloat162float(VPh[(size_t)j * 64 + l]), acc);
    }
    M[(size_t)node * 128 + ROUND * 64 + l] = __float2bfloat16(acc);
}

// ---------- per-user gather: 2 users/wave, unroll-2 for MLP ----------
__global__ __launch_bounds__(256) void user_gather(
    const __hip_bfloat16* __restrict__ embb, const unsigned* __restrict__ ucur,
    const int* __restrict__ pcol, const float* __restrict__ pval,
    float* __restrict__ out, int nu)
{
    int u = (blockIdx.x * 256 + threadIdx.x) >> 5;
    if (u >= nu) return;
    int l = threadIdx.x & 31;
    unsigned beg = u ? ucur[u - 1] : 0u;
    unsigned end = ucur[u];
    float a0 = 0.f, a1 = 0.f, a2 = 0.f, a3 = 0.f;
    float b0 = 0.f, b1 = 0.f, b2 = 0.f, b3 = 0.f;
    unsigned j = beg;
    for (; j + 1 < end; j += 2) {
        int c0 = pcol[j], c1 = pcol[j + 1];
        float v0 = pval[j], v1 = pval[j + 1];
        uint2 e0 = *(const uint2*)((const unsigned*)(embb + (size_t)c0 * 128) + l * 2);
        uint2 e1 = *(const uint2*)((const unsigned*)(embb + (size_t)c1 * 128) + l * 2);
        a0 = fmaf(b2f((unsigned short)(e0.x & 0xFFFF)), v0, a0);
        a1 = fmaf(b2f((unsigned short)(e0.x >> 16)), v0, a1);
        a2 = fmaf(b2f((unsigned short)(e0.y & 0xFFFF)), v0, a2);
        a3 = fmaf(b2f((unsigned short)(e0.y >> 16)), v0, a3);
        b0 = fmaf(b2f((unsigned short)(e1.x & 0xFFFF)), v1, b0);
        b1 = fmaf(b2f((unsigned short)(e1.x >> 16)), v1, b1);
        b2 = fmaf(b2f((unsigned short)(e1.y & 0xFFFF)), v1, b2);
        b3 = fmaf(b2f((unsigned short)(e1.y >> 16)), v1, b3);
    }
    if (j < end) {
        int c0 = pcol[j];
        float v0 = pval[j];
        uint2 e0 = *(const uint2*)((const unsigned*)(embb + (size_t)c0 * 128) + l * 2);
        a0 = fmaf(b2f((unsigned short)(e0.x & 0xFFFF)), v0, a0);
        a1 = fmaf(b2f((unsigned short)(e0.x >> 16)), v0, a1);
        a2 = fmaf(b2f((unsigned short)(e0.y & 0xFFFF)), v0, a2);
        a3 = fmaf(b2f((unsigned short)(e0.y >> 16)), v0, a3);
    }
    *(float4*)(out + (size_t)u * 128 + l * 4) =
        make_float4(a0 + b0, a1 + b1, a2 + b2, a3 + b3);
}

extern "C" void kernel_launch(void* const* d_in, const int* in_sizes, int n_in,
                              void* d_out, int out_size, void* d_ws, size_t ws_size,
                              hipStream_t stream)
{
    const float* emb = (const float*)d_in[0];
    const float* W_Q = (const float*)d_in[1];
    const float* W_K = (const float*)d_in[2];
    const float* W_V = (const float*)d_in[3];
    const float* W_O = (const float*)d_in[4];
    const float* att = (const float*)d_in[5];
    const float* msg = (const float*)d_in[6];
    const int* eidx  = (const int*)d_in[8];
    const int* etyp  = (const int*)d_in[9];
    const int* irow  = (const int*)d_in[10];
    const int* icol  = (const int*)d_in[11];
    const float* ival = (const float*)d_in[12];

    const int N    = in_sizes[0] / 128;
    const int E    = in_sizes[8] / 2;
    const int NNZ  = in_sizes[10];
    const int NU   = out_size / 128 - N;
    const int NREL = in_sizes[5] / 4096;   // = NREL-1 actual relation slots

    const int* head = eidx;
    const int* tail = eidx + E;

    // ---- workspace layout (~154 MB; proven capacity >= 163 MB) ----
    const size_t NC = (size_t)N * 128;
    __hip_bfloat16* VPh = (__hip_bfloat16*)d_ws;          // E*64 bf16 (written after overlays die)
    __hip_bfloat16* Qb  = (__hip_bfloat16*)d_ws;          // N*128 bf16 (overlay in VPh region)
    __hip_bfloat16* Kb  = Qb + NC;                        // N*128 bf16 (overlay)

    char* p = (char*)d_ws + (size_t)E * 64 * 2;
    __hip_bfloat16* Vb = (__hip_bfloat16*)p; p += NC * 2;           // N*128 bf16
    int4* emeta        = (int4*)p;           p += (size_t)E * 16;   // rel-sorted metadata
    float* SC          = (float*)p;          p += (size_t)E * 16;   // E*4 f32 scores
    unsigned* ecnt     = (unsigned*)p;       p += (size_t)N * 4;    // head-CSR offsets
    unsigned* rcnt     = (unsigned*)p;       p += 32 * 4;           // rel offsets
    unsigned* bsum     = (unsigned*)p;       p += 1024 * 4;         // scan scratch
    __hip_bfloat16* M  = (__hip_bfloat16*)p; p += NC * 2;           // N*128 bf16 aggregate
    unsigned* ucnt     = (unsigned*)p;       p += (size_t)((NU + 255) & ~255) * 4;
    unsigned* bsumU    = (unsigned*)p;       p += 1024 * 4;
    int* pcol          = (int*)p;            p += (size_t)NNZ * 4;
    float* pval        = (float*)p;          p += (size_t)NNZ * 4;
    __hip_bfloat16* WtQ = (__hip_bfloat16*)p; p += 16384 * 2;       // 4 transposed bf16 weights
    __hip_bfloat16* WtK = (__hip_bfloat16*)p; p += 16384 * 2;
    __hip_bfloat16* WtV = (__hip_bfloat16*)p; p += 16384 * 2;
    __hip_bfloat16* WtO = (__hip_bfloat16*)p; p += 16384 * 2;

    float* out_ent = (float*)d_out;
    float* out_usr = out_ent + NC;
    // embb lives in the out_ent region (51.2 MB f32, only written by the final
    // W_O GEMM) — everything reading embb must run before that GEMM.
    __hip_bfloat16* embb = (__hip_bfloat16*)out_ent;

    hipMemsetAsync(ecnt, 0, (size_t)N * 4 + 32 * 4 + 1024 * 4, stream);
    hipMemsetAsync(ucnt, 0, (size_t)NU * 4, stream);

    // weight transposes (bf16) + emb -> bf16
    trans_w4<<<256, 256, 0, stream>>>(W_Q, W_K, W_V, W_O, WtQ, WtK, WtV, WtO);
    conv_emb<<<(int)((NC / 4 + 255) / 256), 256, 0, stream>>>(emb, embb, (long)(NC / 4));

    // Q/K/V projections via MFMA (bf16 A; low VGPR -> good occupancy)
    int gg = (N + 127) / 128;
    mfma_gemm<__hip_bfloat16><<<gg, 256, 0, stream>>>(embb, WtQ, Qb, N);
    mfma_gemm<__hip_bfloat16><<<gg, 256, 0, stream>>>(embb, WtK, Kb, N);
    mfma_gemm<__hip_bfloat16><<<gg, 256, 0, stream>>>(embb, WtV, Vb, N);

    // head-CSR + rel histograms (one pass), scans, fused fill
    count_both<<<(E + 255) / 256, 256, 0, stream>>>(head, etyp, ecnt, rcnt, E);
    scan1<<<1, 1024, 0, stream>>>(rcnt, rcnt, bsum, NREL);
    int nbE = (N + 1023) / 1024;
    scan1<<<nbE, 1024, 0, stream>>>(ecnt, ecnt, bsum, N);
    scan2<<<1, 1024, 0, stream>>>(bsum, nbE);
    scan3<<<nbE, 1024, 0, stream>>>(ecnt, bsum, N);
    fill_both<<<(E + 255) / 256, 256, 0, stream>>>(head, tail, etyp, ecnt, rcnt, emeta, E);
    // ecnt now holds end-boundaries per node

    const int NWAVE = 8192;
    int chunk = (E + NWAVE - 1) / NWAVE;
    score_mfma<<<NWAVE / 4, 256, 0, stream>>>(Qb, Kb, att, emeta, SC, E, chunk);
    // Qb/Kb dead -> VPh region free

    msg_mfma<0><<<NWAVE / 4, 256, 0, stream>>>(Vb, msg, emeta, VPh, E, chunk);
    node_pass<0><<<(N + 3) / 4, 256, 0, stream>>>(SC, VPh, ecnt, M, N);
    msg_mfma<1><<<NWAVE / 4, 256, 0, stream>>>(Vb, msg, emeta, VPh, E, chunk);
    node_pass<1><<<(N + 3) / 4, 256, 0, stream>>>(SC, VPh, ecnt, M, N);

    // user aggregation (reads embb) BEFORE the W_O GEMM overwrites out_ent
    bin_count<<<(NNZ + 255) / 256, 256, 0, stream>>>(irow, ucnt, NNZ);
    int nbU = (NU + 1023) / 1024;
    scan1<<<nbU, 1024, 0, stream>>>(ucnt, ucnt, bsumU, NU);
    scan2<<<1, 1024, 0, stream>>>(bsumU, nbU);
    scan3<<<nbU, 1024, 0, stream>>>(ucnt, bsumU, NU);
    fill_user<<<(NNZ + 255) / 256, 256, 0, stream>>>(irow, icol, ival, ucnt, pcol, pval, NNZ);
    user_gather<<<(NU + 7) / 8, 256, 0, stream>>>(embb, ucnt, pcol, pval, out_usr, NU);

    // entity output GEMM via MFMA (bf16 A, f32 out) — overwrites embb region (dead)
    mfma_gemm<float><<<gg, 256, 0, stream>>>(M, WtO, out_ent, N);
}

// Round 13
// 678.898 us; speedup vs baseline: 5.5953x; 1.0025x over previous
//
#include <hip/hip_runtime.h>
#include <hip/hip_bf16.h>
#include <math.h>

typedef __attribute__((ext_vector_type(8))) unsigned short u16x8;
typedef __attribute__((ext_vector_type(4))) unsigned short u16x4;
typedef __attribute__((ext_vector_type(8))) short bf16x8;   // MFMA A/B frag (8 bf16)
typedef __attribute__((ext_vector_type(4))) float f32x4;    // MFMA C/D frag

#define NRELMAX 32

__device__ __forceinline__ float b2f(unsigned short u) {
    return __uint_as_float(((unsigned)u) << 16);
}
__device__ __forceinline__ unsigned short f2b(float v) {
    __hip_bfloat16 b = __float2bfloat16(v);
    return *reinterpret_cast<unsigned short*>(&b);
}

// ---------- MFMA GEMM (m89-verified wiring) ----------
__device__ __forceinline__ bf16x8 lda_frag(const __hip_bfloat16* p) {
    return *(const bf16x8*)p;
}
__device__ __forceinline__ void st_o(__hip_bfloat16* p, float v) { *p = __float2bfloat16(v); }
__device__ __forceinline__ void st_o(float* p, float v) { *p = v; }

template <typename TO>
__global__ __launch_bounds__(256) void mfma_gemm(const __hip_bfloat16* __restrict__ A,
                                                 const __hip_bfloat16* __restrict__ Wt,
                                                 TO* __restrict__ out, int n)
{
    const int tid = threadIdx.x;
    const int w = tid >> 6;
    const int l = tid & 63;
    const int q = l >> 4;
    const int c16 = l & 15;
    const int wr = (w >> 1) * 64;
    const int wc = (w & 1) * 64;
    const long row0 = (long)blockIdx.x * 128;

    f32x4 acc[4][4] = {};
    #pragma unroll
    for (int ks = 0; ks < 4; ++ks) {
        bf16x8 af[4];
        #pragma unroll
        for (int rb = 0; rb < 4; ++rb) {
            long r = row0 + wr + rb * 16 + c16;
            if (r >= n) r = n - 1;
            af[rb] = lda_frag(A + r * 128 + ks * 32 + q * 8);
        }
        #pragma unroll
        for (int cb = 0; cb < 4; ++cb) {
            bf16x8 wf = *(const bf16x8*)(Wt + (size_t)(wc + cb * 16 + c16) * 128 + ks * 32 + q * 8);
            #pragma unroll
            for (int rb = 0; rb < 4; ++rb)
                acc[rb][cb] = __builtin_amdgcn_mfma_f32_16x16x32_bf16(af[rb], wf, acc[rb][cb], 0, 0, 0);
        }
    }
    #pragma unroll
    for (int rb = 0; rb < 4; ++rb) {
        #pragma unroll
        for (int r = 0; r < 4; ++r) {
            long row = row0 + wr + rb * 16 + q * 4 + r;
            if (row < n) {
                #pragma unroll
                for (int cb = 0; cb < 4; ++cb)
                    st_o(out + row * 128 + wc + cb * 16 + c16, acc[rb][cb][r]);
            }
        }
    }
}

// ---------- all-4 W transpose+convert ----------
__global__ __launch_bounds__(256) void trans_w4(
    const float* __restrict__ W0, const float* __restrict__ W1,
    const float* __restrict__ W2, const float* __restrict__ W3,
    __hip_bfloat16* __restrict__ T0, __hip_bfloat16* __restrict__ T1,
    __hip_bfloat16* __restrict__ T2, __hip_bfloat16* __restrict__ T3)
{
    int t = blockIdx.x * 256 + threadIdx.x;   // 65536 threads
    int w = t >> 14, r = t & 16383;
    const float* W = (w == 0) ? W0 : (w == 1) ? W1 : (w == 2) ? W2 : W3;
    __hip_bfloat16* T = (w == 0) ? T0 : (w == 1) ? T1 : (w == 2) ? T2 : T3;
    int k = r >> 7, c = r & 127;
    T[(size_t)c * 128 + k] = __float2bfloat16(W[(size_t)k * 128 + c]);
}

// ---------- emb f32 -> bf16 ----------
__global__ __launch_bounds__(256) void conv_emb(const float* __restrict__ emb,
                                                __hip_bfloat16* __restrict__ embb, long n4)
{
    long i = ((long)blockIdx.x * 256 + threadIdx.x) * 4;
    if (i >= n4 * 4) return;
    float4 v = *(const float4*)(emb + i);
    u16x4 o;
    o[0] = f2b(v.x); o[1] = f2b(v.y); o[2] = f2b(v.z); o[3] = f2b(v.w);
    *(u16x4*)(embb + i) = o;
}

// ---------- A/M tables -> bf16 frag layout ----------
// dst[(((rel*4+h)*2+s2)*64 + lane)*8 + j] = bf16(src[rel*4096 + h*1024 + s2*16 + (g*8+j)*32 + c])
__global__ __launch_bounds__(256) void conv_tab(const float* __restrict__ att,
                                                const float* __restrict__ msg,
                                                __hip_bfloat16* __restrict__ Atab,
                                                __hip_bfloat16* __restrict__ Mtab, int nrel)
{
    int t = blockIdx.x * 256 + threadIdx.x;
    int tot = nrel * 4096;
    if (t >= 2 * tot) return;
    const float* src = (t < tot) ? att : msg;
    __hip_bfloat16* dst = (t < tot) ? Atab : Mtab;
    int u = (t < tot) ? t : t - tot;
    int rel = u >> 12, rem = u & 4095;
    int h = rem >> 10;  rem &= 1023;
    int s2 = rem >> 9;  rem &= 511;
    int lane = rem >> 3, j = rem & 7;
    int g = lane >> 4, c = lane & 15;
    dst[u] = __float2bfloat16(src[(size_t)rel * 4096 + h * 1024 + s2 * 16 + (g * 8 + j) * 32 + c]);
}

// ---------- fused histograms: head (E), rel (E, LDS-agg), user-row (NNZ) ----------
__global__ __launch_bounds__(256) void count_all(const int* __restrict__ head,
                                                 const int* __restrict__ etyp,
                                                 const int* __restrict__ irow,
                                                 unsigned* __restrict__ ecnt,
                                                 unsigned* __restrict__ rcnt,
                                                 unsigned* __restrict__ ucnt,
                                                 int E, int NNZ)
{
    __shared__ unsigned lcnt[NRELMAX];
    const int tid = threadIdx.x;
    if (tid < NRELMAX) lcnt[tid] = 0;
    __syncthreads();
    int i = blockIdx.x * 256 + tid;
    if (i < E) {
        atomicAdd(&ecnt[head[i]], 1u);
        atomicAdd(&lcnt[etyp[i] - 1], 1u);
    }
    if (i < NNZ) atomicAdd(&ucnt[irow[i]], 1u);
    __syncthreads();
    if (tid < NRELMAX) {
        unsigned c = lcnt[tid];
        if (c) atomicAdd(&rcnt[tid], c);
    }
}

// ---------- rel scan with 16-padding ----------
__global__ void rel_scan(const unsigned* __restrict__ rcnt, unsigned* __restrict__ rcur,
                         unsigned* __restrict__ rend, unsigned* __restrict__ rnext, int nrel)
{
    if (threadIdx.x == 0 && blockIdx.x == 0) {
        unsigned acc = 0;
        for (int r = 0; r < nrel; ++r) {
            rcur[r] = acc;
            rend[r] = acc + rcnt[r];
            acc += (rcnt[r] + 15u) & ~15u;
            rnext[r] = acc;
        }
    }
}

// ---------- fill pad slots with dummies (slot=-1) ----------
__global__ __launch_bounds__(256) void fill_pads(const unsigned* __restrict__ rend,
                                                 const unsigned* __restrict__ rnext,
                                                 int4* __restrict__ emeta, int nrel, long emax)
{
    for (int r = 0; r < nrel; ++r) {
        unsigned s = rend[r], e2 = rnext[r];
        for (unsigned i = s + threadIdx.x; i < e2; i += 256)
            emeta[i] = make_int4(0, 0, -1, r);
    }
    long ep = rnext[nrel - 1];
    for (long i = ep + threadIdx.x; i < emax; i += 256)
        emeta[i] = make_int4(0, 0, -1, nrel - 1);
}

// ---------- scans ----------
__global__ __launch_bounds__(1024) void scan1(const unsigned* __restrict__ in,
                                              unsigned* __restrict__ out,
                                              unsigned* __restrict__ bsum, int n)
{
    __shared__ unsigned sh[1024];
    int i = blockIdx.x * 1024 + threadIdx.x;
    unsigned v = (i < n) ? in[i] : 0u;
    sh[threadIdx.x] = v;
    __syncthreads();
    for (int off = 1; off < 1024; off <<= 1) {
        unsigned t = (threadIdx.x >= (unsigned)off) ? sh[threadIdx.x - off] : 0u;
        __syncthreads();
        sh[threadIdx.x] += t;
        __syncthreads();
    }
    if (i < n) out[i] = sh[threadIdx.x] - v;  // exclusive
    if (threadIdx.x == 1023) bsum[blockIdx.x] = sh[1023];
}

__global__ __launch_bounds__(1024) void scan2(unsigned* __restrict__ bsum, int nb)
{
    __shared__ unsigned sh[1024];
    unsigned v = (threadIdx.x < (unsigned)nb) ? bsum[threadIdx.x] : 0u;
    sh[threadIdx.x] = v;
    __syncthreads();
    for (int off = 1; off < 1024; off <<= 1) {
        unsigned t = (threadIdx.x >= (unsigned)off) ? sh[threadIdx.x - off] : 0u;
        __syncthreads();
        sh[threadIdx.x] += t;
        __syncthreads();
    }
    if (threadIdx.x < (unsigned)nb) bsum[threadIdx.x] = sh[threadIdx.x] - v;
}

__global__ __launch_bounds__(1024) void scan3(unsigned* __restrict__ out,
                                              const unsigned* __restrict__ bsum, int n)
{
    int i = blockIdx.x * 1024 + threadIdx.x;
    if (i < n) out[i] += bsum[blockIdx.x];
}

__global__ __launch_bounds__(256) void fill_user(const int* __restrict__ rows,
                                                 const int* __restrict__ cols,
                                                 const float* __restrict__ vals,
                                                 unsigned* __restrict__ cursor,
                                                 int* __restrict__ pcol,
                                                 float* __restrict__ pval, int n)
{
    int i = blockIdx.x * 256 + threadIdx.x;
    if (i >= n) return;
    unsigned p = atomicAdd(&cursor[rows[i]], 1u);
    pcol[p] = cols[i];
    pval[p] = vals[i];
}

// fused edge fill: head-cursor atomic (slot) + LDS-agg rel-cursor -> emeta
__global__ __launch_bounds__(256) void fill_both(const int* __restrict__ head,
                                                 const int* __restrict__ tail,
                                                 const int* __restrict__ etyp,
                                                 unsigned* __restrict__ ecur,
                                                 unsigned* __restrict__ rcur,
                                                 int4* __restrict__ emeta, int n)
{
    __shared__ unsigned lcnt[NRELMAX];
    __shared__ unsigned lbase[NRELMAX];
    const int tid = threadIdx.x;
    if (tid < NRELMAX) lcnt[tid] = 0;
    __syncthreads();
    int i = blockIdx.x * 256 + tid;
    int r = 0;
    unsigned lpos = 0;
    if (i < n) {
        r = etyp[i] - 1;
        lpos = atomicAdd(&lcnt[r], 1u);
    }
    __syncthreads();
    if (tid < NRELMAX) {
        unsigned c = lcnt[tid];
        lbase[tid] = c ? atomicAdd(&rcur[tid], c) : 0u;
    }
    __syncthreads();
    if (i < n) {
        int hn = head[i];
        unsigned slot = atomicAdd(&ecur[hn], 1u);
        emeta[lbase[r] + lpos] = make_int4(hn, tail[i], (int)slot, r);
    }
}

// ---------- fused edge pass (per head-pair ROUND): score + V' ----------
// Static 16-edge rel-uniform groups (padded); no ballot, no dynamic advance.
template <int ROUND>
__global__ __launch_bounds__(256, 2) void edge_pass(
    const __hip_bfloat16* __restrict__ Qb, const __hip_bfloat16* __restrict__ Kb,
    const __hip_bfloat16* __restrict__ Vb,
    const __hip_bfloat16* __restrict__ Atab, const __hip_bfloat16* __restrict__ Mtab,
    const int4* __restrict__ emeta, float* __restrict__ SC,
    __hip_bfloat16* __restrict__ VPh, long Epad, int chunk)
{
    const int wv = (blockIdx.x * 256 + threadIdx.x) >> 6;
    const int l = threadIdx.x & 63;
    const int g = l >> 4;
    const int c = l & 15;
    long j0 = (long)wv * chunk;
    if (j0 >= Epad) return;
    long j1 = j0 + chunk; if (j1 > Epad) j1 = Epad;

    bf16x8 aK[2][2], aM[2][2];
    int currel = -1;
    for (long pos = j0; pos < j1; pos += 16) {
        const int4 md = emeta[pos + c];
        const int rel0 = __shfl(md.w, 0, 64);   // rel-uniform group by construction
        if (rel0 != currel) {
            currel = rel0;
            #pragma unroll
            for (int hl = 0; hl < 2; ++hl) {
                const int h = ROUND * 2 + hl;
                #pragma unroll
                for (int s2 = 0; s2 < 2; ++s2) {
                    size_t idx = ((((size_t)rel0 * 4 + h) * 2 + s2) * 64 + l) * 8;
                    aK[hl][s2] = *(const bf16x8*)(Atab + idx);
                    aM[hl][s2] = *(const bf16x8*)(Mtab + idx);
                }
            }
        }
        const int tn = md.y, hn = md.x, slot = md.z;
        #pragma unroll
        for (int hl = 0; hl < 2; ++hl) {
            const int h = ROUND * 2 + hl;
            bf16x8 bk = *(const bf16x8*)(Kb + (size_t)tn * 128 + h * 32 + g * 8);
            bf16x8 bv = *(const bf16x8*)(Vb + (size_t)tn * 128 + h * 32 + g * 8);
            f32x4 z = {0.f, 0.f, 0.f, 0.f};
            f32x4 klo = __builtin_amdgcn_mfma_f32_16x16x32_bf16(aK[hl][0], bk, z, 0, 0, 0);
            f32x4 khi = __builtin_amdgcn_mfma_f32_16x16x32_bf16(aK[hl][1], bk, z, 0, 0, 0);
            f32x4 vlo = __builtin_amdgcn_mfma_f32_16x16x32_bf16(aM[hl][0], bv, z, 0, 0, 0);
            f32x4 vhi = __builtin_amdgcn_mfma_f32_16x16x32_bf16(aM[hl][1], bv, z, 0, 0, 0);
            const __hip_bfloat16* qp = Qb + (size_t)hn * 128 + h * 32;
            u16x4 q1 = *(const u16x4*)(qp + g * 4);
            u16x4 q2 = *(const u16x4*)(qp + 16 + g * 4);
            float p = 0.f;
            #pragma unroll
            for (int r = 0; r < 4; ++r)
                p += b2f(q1[r]) * klo[r] + b2f(q2[r]) * khi[r];
            p += __shfl_xor(p, 16, 64);
            p += __shfl_xor(p, 32, 64);
            if (slot >= 0) {
                if (g == 0) SC[(size_t)slot * 4 + h] = p * 0.17677669529663687f;
                u16x4 plo, phi;
                #pragma unroll
                for (int r = 0; r < 4; ++r) { plo[r] = f2b(vlo[r]); phi[r] = f2b(vhi[r]); }
                __hip_bfloat16* dst = VPh + (size_t)slot * 64 + hl * 32;
                *(u16x4*)(dst + g * 4) = plo;
                *(u16x4*)(dst + 16 + g * 4) = phi;
            }
        }
    }
}

// ---------- node pass (per head-pair ROUND): online softmax + accumulate ----------
template <int ROUND>
__global__ __launch_bounds__(256) void node_pass(
    const float* __restrict__ SC, const __hip_bfloat16* __restrict__ VPh,
    const unsigned* __restrict__ ecur, __hip_bfloat16* __restrict__ M, int n)
{
    int node = (blockIdx.x * 256 + threadIdx.x) >> 6;
    if (node >= n) return;
    int l = threadIdx.x & 63;
    int half = l >> 5;
    const int h = ROUND * 2 + half;
    unsigned beg = node ? ecur[node - 1] : 0u;
    unsigned end = ecur[node];
    float mx = -INFINITY, dn = 0.f;
    for (unsigned j = beg; j < end; ++j) {
        float s = SC[(size_t)j * 4 + h];
        float m2 = fmaxf(mx, s);
        dn = dn * __expf(mx - m2) + __expf(s - m2);
        mx = m2;
    }
    float inv = (end > beg) ? 1.f / dn : 0.f;
    float acc = 0.f;
    for (unsigned j = beg; j < end; ++j) {
        float w = __expf(SC[(size_t)j * 4 + h] - mx) * inv;
        acc = fmaf(w, __bfloat162float(VPh[(size_t)j * 64 + l]), acc);
    }
    M[(size_t)node * 128 + ROUND * 64 + l] = __float2bfloat16(acc);
}

// ---------- per-user gather: 2 users/wave, unroll-4 ----------
__global__ __launch_bounds__(256) void user_gather(
    const __hip_bfloat16* __restrict__ embb, const unsigned* __restrict__ ucur,
    const int* __restrict__ pcol, const float* __restrict__ pval,
    float* __restrict__ out, int nu)
{
    int u = (blockIdx.x * 256 + threadIdx.x) >> 5;
    if (u >= nu) return;
    int l = threadIdx.x & 31;
    unsigned beg = u ? ucur[u - 1] : 0u;
    unsigned end = ucur[u];
    float a0 = 0.f, a1 = 0.f, a2 = 0.f, a3 = 0.f;
    float b0 = 0.f, b1 = 0.f, b2 = 0.f, b3 = 0.f;
    unsigned j = beg;
    for (; j + 3 < end; j += 4) {
        int c0 = pcol[j], c1 = pcol[j + 1], c2 = pcol[j + 2], c3 = pcol[j + 3];
        float v0 = pval[j], v1 = pval[j + 1], v2 = pval[j + 2], v3 = pval[j + 3];
        uint2 e0 = *(const uint2*)((const unsigned*)(embb + (size_t)c0 * 128) + l * 2);
        uint2 e1 = *(const uint2*)((const unsigned*)(embb + (size_t)c1 * 128) + l * 2);
        uint2 e2 = *(const uint2*)((const unsigned*)(embb + (size_t)c2 * 128) + l * 2);
        uint2 e3 = *(const uint2*)((const unsigned*)(embb + (size_t)c3 * 128) + l * 2);
        a0 = fmaf(b2f((unsigned short)(e0.x & 0xFFFF)), v0, a0);
        a1 = fmaf(b2f((unsigned short)(e0.x >> 16)), v0, a1);
        a2 = fmaf(b2f((unsigned short)(e0.y & 0xFFFF)), v0, a2);
        a3 = fmaf(b2f((unsigned short)(e0.y >> 16)), v0, a3);
        b0 = fmaf(b2f((unsigned short)(e1.x & 0xFFFF)), v1, b0);
        b1 = fmaf(b2f((unsigned short)(e1.x >> 16)), v1, b1);
        b2 = fmaf(b2f((unsigned short)(e1.y & 0xFFFF)), v1, b2);
        b3 = fmaf(b2f((unsigned short)(e1.y >> 16)), v1, b3);
        a0 = fmaf(b2f((unsigned short)(e2.x & 0xFFFF)), v2, a0);
        a1 = fmaf(b2f((unsigned short)(e2.x >> 16)), v2, a1);
        a2 = fmaf(b2f((unsigned short)(e2.y & 0xFFFF)), v2, a2);
        a3 = fmaf(b2f((unsigned short)(e2.y >> 16)), v2, a3);
        b0 = fmaf(b2f((unsigned short)(e3.x & 0xFFFF)), v3, b0);
        b1 = fmaf(b2f((unsigned short)(e3.x >> 16)), v3, b1);
        b2 = fmaf(b2f((unsigned short)(e3.y & 0xFFFF)), v3, b2);
        b3 = fmaf(b2f((unsigned short)(e3.y >> 16)), v3, b3);
    }
    for (; j < end; ++j) {
        int c0 = pcol[j];
        float v0 = pval[j];
        uint2 e0 = *(const uint2*)((const unsigned*)(embb + (size_t)c0 * 128) + l * 2);
        a0 = fmaf(b2f((unsigned short)(e0.x & 0xFFFF)), v0, a0);
        a1 = fmaf(b2f((unsigned short)(e0.x >> 16)), v0, a1);
        a2 = fmaf(b2f((unsigned short)(e0.y & 0xFFFF)), v0, a2);
        a3 = fmaf(b2f((unsigned short)(e0.y >> 16)), v0, a3);
    }
    *(float4*)(out + (size_t)u * 128 + l * 4) =
        make_float4(a0 + b0, a1 + b1, a2 + b2, a3 + b3);
}

extern "C" void kernel_launch(void* const* d_in, const int* in_sizes, int n_in,
                              void* d_out, int out_size, void* d_ws, size_t ws_size,
                              hipStream_t stream)
{
    const float* emb = (const float*)d_in[0];
    const float* W_Q = (const float*)d_in[1];
    const float* W_K = (const float*)d_in[2];
    const float* W_V = (const float*)d_in[3];
    const float* W_O = (const float*)d_in[4];
    const float* att = (const float*)d_in[5];
    const float* msg = (const float*)d_in[6];
    const int* eidx  = (const int*)d_in[8];
    const int* etyp  = (const int*)d_in[9];
    const int* irow  = (const int*)d_in[10];
    const int* icol  = (const int*)d_in[11];
    const float* ival = (const float*)d_in[12];

    const int N    = in_sizes[0] / 128;
    const int E    = in_sizes[8] / 2;
    const int NNZ  = in_sizes[10];
    const int NU   = out_size / 128 - N;
    const int NREL = in_sizes[5] / 4096;   // actual relation slots (24)

    const int* head = eidx;
    const int* tail = eidx + E;

    // ---- d_ws layout (~162.3 MB; proven capacity >= 163.2 MB) ----
    const size_t NC = (size_t)N * 128;
    char* p = (char*)d_ws;
    __hip_bfloat16* VPh = (__hip_bfloat16*)p; p += (size_t)E * 64 * 2;  // 76.8 MB
    __hip_bfloat16* Kb  = (__hip_bfloat16*)p; p += NC * 2;              // 25.6 MB
    __hip_bfloat16* Vb  = (__hip_bfloat16*)p; p += NC * 2;              // 25.6 MB
    __hip_bfloat16* M   = (__hip_bfloat16*)p; p += NC * 2;              // 25.6 MB
    unsigned* rcnt  = (unsigned*)p; p += 32 * 4;
    unsigned* ucnt  = (unsigned*)p; p += (size_t)((NU + 255) & ~255) * 4;
    unsigned* rcur  = (unsigned*)p; p += 32 * 4;
    unsigned* rend  = (unsigned*)p; p += 32 * 4;
    unsigned* rnext = (unsigned*)p; p += 32 * 4;
    unsigned* bsum  = (unsigned*)p; p += 1024 * 4;
    unsigned* bsumU = (unsigned*)p; p += 1024 * 4;
    int* pcol       = (int*)p;      p += (size_t)NNZ * 4;
    float* pval     = (float*)p;    p += (size_t)NNZ * 4;
    __hip_bfloat16* WtQ = (__hip_bfloat16*)p; p += 16384 * 2;
    __hip_bfloat16* WtK = (__hip_bfloat16*)p; p += 16384 * 2;
    __hip_bfloat16* WtV = (__hip_bfloat16*)p; p += 16384 * 2;
    __hip_bfloat16* WtO = (__hip_bfloat16*)p; p += 16384 * 2;
    __hip_bfloat16* Atab = (__hip_bfloat16*)p; p += (size_t)NREL * 4096 * 2;
    __hip_bfloat16* Mtab = (__hip_bfloat16*)p; p += (size_t)NREL * 4096 * 2;

    // ---- d_out overlays (all regions fully rewritten by final kernels) ----
    float* out_ent = (float*)d_out;                 // N*128 f32 (51.2 MB)
    float* out_usr = out_ent + NC;                  // NU*128 f32 (25.6 MB)
    __hip_bfloat16* embb = (__hip_bfloat16*)out_ent;               // 25.6 MB
    __hip_bfloat16* Qb   = (__hip_bfloat16*)((char*)d_out + NC * 2); // 25.6 MB
    const long Emax = E + 512;                      // padded emeta upper bound
    float* SC   = out_usr;                                          // E*4 f32
    int4* emeta = (int4*)(out_usr + (size_t)E * 4);                 // Emax int4
    unsigned* ecnt = (unsigned*)((char*)emeta + (size_t)Emax * 16); // N u32

    hipMemsetAsync(ecnt, 0, (size_t)N * 4, stream);
    hipMemsetAsync(rcnt, 0, 32 * 4 + (size_t)((NU + 255) & ~255) * 4, stream);

    // prep: weights, emb bf16, A/M frag tables
    trans_w4<<<256, 256, 0, stream>>>(W_Q, W_K, W_V, W_O, WtQ, WtK, WtV, WtO);
    conv_emb<<<(int)((NC / 4 + 255) / 256), 256, 0, stream>>>(emb, embb, (long)(NC / 4));
    conv_tab<<<(2 * NREL * 4096 + 255) / 256, 256, 0, stream>>>(att, msg, Atab, Mtab, NREL);

    // Q/K/V projections
    int gg = (N + 127) / 128;
    mfma_gemm<__hip_bfloat16><<<gg, 256, 0, stream>>>(embb, WtQ, Qb, N);
    mfma_gemm<__hip_bfloat16><<<gg, 256, 0, stream>>>(embb, WtK, Kb, N);
    mfma_gemm<__hip_bfloat16><<<gg, 256, 0, stream>>>(embb, WtV, Vb, N);

    // CSR build (padded rel buckets)
    int gmax = ((NNZ > E ? NNZ : E) + 255) / 256;
    count_all<<<gmax, 256, 0, stream>>>(head, etyp, irow, ecnt, rcnt, ucnt, E, NNZ);
    rel_scan<<<1, 64, 0, stream>>>(rcnt, rcur, rend, rnext, NREL);
    fill_pads<<<1, 256, 0, stream>>>(rend, rnext, emeta, NREL, Emax);
    int nbE = (N + 1023) / 1024;
    scan1<<<nbE, 1024, 0, stream>>>(ecnt, ecnt, bsum, N);
    scan2<<<1, 1024, 0, stream>>>(bsum, nbE);
    scan3<<<nbE, 1024, 0, stream>>>(ecnt, bsum, N);
    fill_both<<<(E + 255) / 256, 256, 0, stream>>>(head, tail, etyp, ecnt, rcur, emeta, E);
    // ecnt now holds end-boundaries per node

    // fused edge + node passes (per head-pair)
    const int NWAVE = 16384;
    int chunk = (int)(((Emax + NWAVE - 1) / NWAVE + 15) & ~15L);
    edge_pass<0><<<NWAVE / 4, 256, 0, stream>>>(Qb, Kb, Vb, Atab, Mtab, emeta, SC, VPh, Emax, chunk);
    node_pass<0><<<(N + 3) / 4, 256, 0, stream>>>(SC, VPh, ecnt, M, N);
    edge_pass<1><<<NWAVE / 4, 256, 0, stream>>>(Qb, Kb, Vb, Atab, Mtab, emeta, SC, VPh, Emax, chunk);
    node_pass<1><<<(N + 3) / 4, 256, 0, stream>>>(SC, VPh, ecnt, M, N);

    // user aggregation (reads embb; overwrites SC/emeta/ecnt region = dead)
    int nbU = (NU + 1023) / 1024;
    scan1<<<nbU, 1024, 0, stream>>>(ucnt, ucnt, bsumU, NU);
    scan2<<<1, 1024, 0, stream>>>(bsumU, nbU);
    scan3<<<nbU, 1024, 0, stream>>>(ucnt, bsumU, NU);
    fill_user<<<(NNZ + 255) / 256, 256, 0, stream>>>(irow, icol, ival, ucnt, pcol, pval, NNZ);
    user_gather<<<(NU + 7) / 8, 256, 0, stream>>>(embb, ucnt, pcol, pval, out_usr, NU);

    // entity output GEMM last (overwrites embb+Qb region = dead)
    mfma_gemm<float><<<gg, 256, 0, stream>>>(M, WtO, out_ent, N);
}

// Round 14
// 637.035 us; speedup vs baseline: 5.9630x; 1.0657x over previous
//
#include <hip/hip_runtime.h>
#include <hip/hip_bf16.h>
#include <math.h>

typedef __attribute__((ext_vector_type(8))) unsigned short u16x8;
typedef __attribute__((ext_vector_type(4))) unsigned short u16x4;
typedef __attribute__((ext_vector_type(8))) short bf16x8;   // MFMA A/B frag (8 bf16)
typedef __attribute__((ext_vector_type(4))) float f32x4;    // MFMA C/D frag

#define NRELMAX 32

__device__ __forceinline__ float b2f(unsigned short u) {
    return __uint_as_float(((unsigned)u) << 16);
}
__device__ __forceinline__ unsigned short f2b(float v) {
    __hip_bfloat16 b = __float2bfloat16(v);
    return *reinterpret_cast<unsigned short*>(&b);
}

// ---------- MFMA GEMM (m89-verified wiring) ----------
__device__ __forceinline__ bf16x8 lda_frag(const __hip_bfloat16* p) {
    return *(const bf16x8*)p;
}
__device__ __forceinline__ void st_o(__hip_bfloat16* p, float v) { *p = __float2bfloat16(v); }
__device__ __forceinline__ void st_o(float* p, float v) { *p = v; }

template <typename TO>
__global__ __launch_bounds__(256) void mfma_gemm(const __hip_bfloat16* __restrict__ A,
                                                 const __hip_bfloat16* __restrict__ Wt,
                                                 TO* __restrict__ out, int n)
{
    const int tid = threadIdx.x;
    const int w = tid >> 6;
    const int l = tid & 63;
    const int q = l >> 4;
    const int c16 = l & 15;
    const int wr = (w >> 1) * 64;
    const int wc = (w & 1) * 64;
    const long row0 = (long)blockIdx.x * 128;

    f32x4 acc[4][4] = {};
    #pragma unroll
    for (int ks = 0; ks < 4; ++ks) {
        bf16x8 af[4];
        #pragma unroll
        for (int rb = 0; rb < 4; ++rb) {
            long r = row0 + wr + rb * 16 + c16;
            if (r >= n) r = n - 1;
            af[rb] = lda_frag(A + r * 128 + ks * 32 + q * 8);
        }
        #pragma unroll
        for (int cb = 0; cb < 4; ++cb) {
            bf16x8 wf = *(const bf16x8*)(Wt + (size_t)(wc + cb * 16 + c16) * 128 + ks * 32 + q * 8);
            #pragma unroll
            for (int rb = 0; rb < 4; ++rb)
                acc[rb][cb] = __builtin_amdgcn_mfma_f32_16x16x32_bf16(af[rb], wf, acc[rb][cb], 0, 0, 0);
        }
    }
    #pragma unroll
    for (int rb = 0; rb < 4; ++rb) {
        #pragma unroll
        for (int r = 0; r < 4; ++r) {
            long row = row0 + wr + rb * 16 + q * 4 + r;
            if (row < n) {
                #pragma unroll
                for (int cb = 0; cb < 4; ++cb)
                    st_o(out + row * 128 + wc + cb * 16 + c16, acc[rb][cb][r]);
            }
        }
    }
}

// ---------- all-4 W transpose+convert ----------
__global__ __launch_bounds__(256) void trans_w4(
    const float* __restrict__ W0, const float* __restrict__ W1,
    const float* __restrict__ W2, const float* __restrict__ W3,
    __hip_bfloat16* __restrict__ T0, __hip_bfloat16* __restrict__ T1,
    __hip_bfloat16* __restrict__ T2, __hip_bfloat16* __restrict__ T3)
{
    int t = blockIdx.x * 256 + threadIdx.x;   // 65536 threads
    int w = t >> 14, r = t & 16383;
    const float* W = (w == 0) ? W0 : (w == 1) ? W1 : (w == 2) ? W2 : W3;
    __hip_bfloat16* T = (w == 0) ? T0 : (w == 1) ? T1 : (w == 2) ? T2 : T3;
    int k = r >> 7, c = r & 127;
    T[(size_t)c * 128 + k] = __float2bfloat16(W[(size_t)k * 128 + c]);
}

// ---------- emb f32 -> bf16 ----------
__global__ __launch_bounds__(256) void conv_emb(const float* __restrict__ emb,
                                                __hip_bfloat16* __restrict__ embb, long n4)
{
    long i = ((long)blockIdx.x * 256 + threadIdx.x) * 4;
    if (i >= n4 * 4) return;
    float4 v = *(const float4*)(emb + i);
    u16x4 o;
    o[0] = f2b(v.x); o[1] = f2b(v.y); o[2] = f2b(v.z); o[3] = f2b(v.w);
    *(u16x4*)(embb + i) = o;
}

// ---------- A/M tables -> bf16 frag layout ----------
__global__ __launch_bounds__(256) void conv_tab(const float* __restrict__ att,
                                                const float* __restrict__ msg,
                                                __hip_bfloat16* __restrict__ Atab,
                                                __hip_bfloat16* __restrict__ Mtab, int nrel)
{
    int t = blockIdx.x * 256 + threadIdx.x;
    int tot = nrel * 4096;
    if (t >= 2 * tot) return;
    const float* src = (t < tot) ? att : msg;
    __hip_bfloat16* dst = (t < tot) ? Atab : Mtab;
    int u = (t < tot) ? t : t - tot;
    int rel = u >> 12, rem = u & 4095;
    int h = rem >> 10;  rem &= 1023;
    int s2 = rem >> 9;  rem &= 511;
    int lane = rem >> 3, j = rem & 7;
    int g = lane >> 4, c = lane & 15;
    dst[u] = __float2bfloat16(src[(size_t)rel * 4096 + h * 1024 + s2 * 16 + (g * 8 + j) * 32 + c]);
}

// ---------- single-pass count with 8-way replicated counters + plocal ----------
__global__ __launch_bounds__(256) void count_rec(
    const int* __restrict__ head, const int* __restrict__ etyp,
    const int* __restrict__ irow,
    unsigned* __restrict__ ecnt8, unsigned* __restrict__ ucnt8,
    unsigned* __restrict__ rcnt, int* __restrict__ plocalE,
    int* __restrict__ plocalU, int E, int NNZ, int Np, int NUp)
{
    __shared__ unsigned lcnt[NRELMAX];
    const int tid = threadIdx.x;
    if (tid < NRELMAX) lcnt[tid] = 0;
    __syncthreads();
    int i = blockIdx.x * 256 + tid;
    unsigned rep = (unsigned)(blockIdx.x & 7);
    if (i < E) {
        unsigned p = atomicAdd(&ecnt8[rep * Np + head[i]], 1u);
        plocalE[i] = (int)(p | (rep << 28));
        atomicAdd(&lcnt[etyp[i] - 1], 1u);
    }
    if (i < NNZ) {
        unsigned p = atomicAdd(&ucnt8[rep * NUp + irow[i]], 1u);
        plocalU[i] = (int)(p | (rep << 28));
    }
    __syncthreads();
    if (tid < NRELMAX) {
        unsigned c = lcnt[tid];
        if (c) atomicAdd(&rcnt[tid], c);
    }
}

// ---------- per-key totals over replicas ----------
__global__ __launch_bounds__(256) void sum_rep(const unsigned* __restrict__ cnt8,
                                               unsigned* __restrict__ tot, int n, int stride)
{
    int i = blockIdx.x * 256 + threadIdx.x;
    if (i >= n) return;
    unsigned t = 0;
    #pragma unroll
    for (int r = 0; r < 8; ++r) t += cnt8[(size_t)r * stride + i];
    tot[i] = t;
}

// ---------- replicas -> per-replica bases (in place), given exclusive starts ----------
__global__ __launch_bounds__(256) void mk_repbase(unsigned* __restrict__ cnt8,
                                                  const unsigned* __restrict__ base,
                                                  int n, int stride)
{
    int i = blockIdx.x * 256 + threadIdx.x;
    if (i >= n) return;
    unsigned acc = base[i];
    #pragma unroll
    for (int r = 0; r < 8; ++r) {
        unsigned c = cnt8[(size_t)r * stride + i];
        cnt8[(size_t)r * stride + i] = acc;
        acc += c;
    }
}

// ---------- rel scan with 16-padding ----------
__global__ void rel_scan(const unsigned* __restrict__ rcnt, unsigned* __restrict__ rcur,
                         unsigned* __restrict__ rend, unsigned* __restrict__ rnext, int nrel)
{
    if (threadIdx.x == 0 && blockIdx.x == 0) {
        unsigned acc = 0;
        for (int r = 0; r < nrel; ++r) {
            rcur[r] = acc;
            rend[r] = acc + rcnt[r];
            acc += (rcnt[r] + 15u) & ~15u;
            rnext[r] = acc;
        }
    }
}

// ---------- fill pad slots with dummies (slot=-1) ----------
__global__ __launch_bounds__(256) void fill_pads(const unsigned* __restrict__ rend,
                                                 const unsigned* __restrict__ rnext,
                                                 int4* __restrict__ emeta, int nrel, long emax)
{
    for (int r = 0; r < nrel; ++r) {
        unsigned s = rend[r], e2 = rnext[r];
        for (unsigned i = s + threadIdx.x; i < e2; i += 256)
            emeta[i] = make_int4(0, 0, -1, r);
    }
    long ep = rnext[nrel - 1];
    for (long i = ep + threadIdx.x; i < emax; i += 256)
        emeta[i] = make_int4(0, 0, -1, nrel - 1);
}

// ---------- scans ----------
__global__ __launch_bounds__(1024) void scan1(const unsigned* __restrict__ in,
                                              unsigned* __restrict__ out,
                                              unsigned* __restrict__ bsum, int n)
{
    __shared__ unsigned sh[1024];
    int i = blockIdx.x * 1024 + threadIdx.x;
    unsigned v = (i < n) ? in[i] : 0u;
    sh[threadIdx.x] = v;
    __syncthreads();
    for (int off = 1; off < 1024; off <<= 1) {
        unsigned t = (threadIdx.x >= (unsigned)off) ? sh[threadIdx.x - off] : 0u;
        __syncthreads();
        sh[threadIdx.x] += t;
        __syncthreads();
    }
    if (i < n) out[i] = sh[threadIdx.x] - v;  // exclusive
    if (threadIdx.x == 1023) bsum[blockIdx.x] = sh[1023];
}

__global__ __launch_bounds__(1024) void scan2(unsigned* __restrict__ bsum, int nb)
{
    __shared__ unsigned sh[1024];
    unsigned v = (threadIdx.x < (unsigned)nb) ? bsum[threadIdx.x] : 0u;
    sh[threadIdx.x] = v;
    __syncthreads();
    for (int off = 1; off < 1024; off <<= 1) {
        unsigned t = (threadIdx.x >= (unsigned)off) ? sh[threadIdx.x - off] : 0u;
        __syncthreads();
        sh[threadIdx.x] += t;
        __syncthreads();
    }
    if (threadIdx.x < (unsigned)nb) bsum[threadIdx.x] = sh[threadIdx.x] - v;
}

__global__ __launch_bounds__(1024) void scan3(unsigned* __restrict__ out,
                                              const unsigned* __restrict__ bsum, int n)
{
    int i = blockIdx.x * 1024 + threadIdx.x;
    if (i < n) out[i] += bsum[blockIdx.x];
}

// ---------- atomic-free fills via plocal + repbase ----------
__global__ __launch_bounds__(256) void fill_user2(const int* __restrict__ irow,
                                                  const int* __restrict__ icol,
                                                  const float* __restrict__ ival,
                                                  const unsigned* __restrict__ repbaseU,
                                                  const int* __restrict__ plocalU,
                                                  int2* __restrict__ upair, int n, int NUp)
{
    int i = blockIdx.x * 256 + threadIdx.x;
    if (i >= n) return;
    unsigned pl = (unsigned)plocalU[i];
    unsigned rep = pl >> 28;
    unsigned pos = pl & 0x0FFFFFFFu;
    unsigned slot = repbaseU[(size_t)rep * NUp + irow[i]] + pos;
    upair[slot] = make_int2(icol[i], __float_as_int(ival[i]));
}

__global__ __launch_bounds__(256) void fill_both2(const int* __restrict__ head,
                                                  const int* __restrict__ tail,
                                                  const int* __restrict__ etyp,
                                                  const unsigned* __restrict__ repbaseE,
                                                  const int* __restrict__ plocalE,
                                                  unsigned* __restrict__ rcur,
                                                  int4* __restrict__ emeta, int n, int Np)
{
    __shared__ unsigned lcnt[NRELMAX];
    __shared__ unsigned lbase[NRELMAX];
    const int tid = threadIdx.x;
    if (tid < NRELMAX) lcnt[tid] = 0;
    __syncthreads();
    int i = blockIdx.x * 256 + tid;
    int r = 0;
    unsigned lpos = 0;
    if (i < n) {
        r = etyp[i] - 1;
        lpos = atomicAdd(&lcnt[r], 1u);
    }
    __syncthreads();
    if (tid < NRELMAX) {
        unsigned c = lcnt[tid];
        lbase[tid] = c ? atomicAdd(&rcur[tid], c) : 0u;
    }
    __syncthreads();
    if (i < n) {
        unsigned pl = (unsigned)plocalE[i];
        unsigned rep = pl >> 28;
        unsigned pos = pl & 0x0FFFFFFFu;
        int hn = head[i];
        unsigned slot = repbaseE[(size_t)rep * Np + hn] + pos;
        emeta[lbase[r] + lpos] = make_int4(hn, tail[i], (int)slot, r);
    }
}

// ---------- fused edge pass (per head-pair ROUND): score + V' ----------
template <int ROUND>
__global__ __launch_bounds__(256, 2) void edge_pass(
    const __hip_bfloat16* __restrict__ Qb, const __hip_bfloat16* __restrict__ Kb,
    const __hip_bfloat16* __restrict__ Vb,
    const __hip_bfloat16* __restrict__ Atab, const __hip_bfloat16* __restrict__ Mtab,
    const int4* __restrict__ emeta, float* __restrict__ SC,
    __hip_bfloat16* __restrict__ VPh, long Epad, int chunk)
{
    const int wv = (blockIdx.x * 256 + threadIdx.x) >> 6;
    const int l = threadIdx.x & 63;
    const int g = l >> 4;
    const int c = l & 15;
    long j0 = (long)wv * chunk;
    if (j0 >= Epad) return;
    long j1 = j0 + chunk; if (j1 > Epad) j1 = Epad;

    bf16x8 aK[2][2], aM[2][2];
    int currel = -1;
    for (long pos = j0; pos < j1; pos += 16) {
        const int4 md = emeta[pos + c];
        const int rel0 = __shfl(md.w, 0, 64);   // rel-uniform group by construction
        if (rel0 != currel) {
            currel = rel0;
            #pragma unroll
            for (int hl = 0; hl < 2; ++hl) {
                const int h = ROUND * 2 + hl;
                #pragma unroll
                for (int s2 = 0; s2 < 2; ++s2) {
                    size_t idx = ((((size_t)rel0 * 4 + h) * 2 + s2) * 64 + l) * 8;
                    aK[hl][s2] = *(const bf16x8*)(Atab + idx);
                    aM[hl][s2] = *(const bf16x8*)(Mtab + idx);
                }
            }
        }
        const int tn = md.y, hn = md.x, slot = md.z;
        #pragma unroll
        for (int hl = 0; hl < 2; ++hl) {
            const int h = ROUND * 2 + hl;
            bf16x8 bk = *(const bf16x8*)(Kb + (size_t)tn * 128 + h * 32 + g * 8);
            bf16x8 bv = *(const bf16x8*)(Vb + (size_t)tn * 128 + h * 32 + g * 8);
            f32x4 z = {0.f, 0.f, 0.f, 0.f};
            f32x4 klo = __builtin_amdgcn_mfma_f32_16x16x32_bf16(aK[hl][0], bk, z, 0, 0, 0);
            f32x4 khi = __builtin_amdgcn_mfma_f32_16x16x32_bf16(aK[hl][1], bk, z, 0, 0, 0);
            f32x4 vlo = __builtin_amdgcn_mfma_f32_16x16x32_bf16(aM[hl][0], bv, z, 0, 0, 0);
            f32x4 vhi = __builtin_amdgcn_mfma_f32_16x16x32_bf16(aM[hl][1], bv, z, 0, 0, 0);
            const __hip_bfloat16* qp = Qb + (size_t)hn * 128 + h * 32;
            u16x4 q1 = *(const u16x4*)(qp + g * 4);
            u16x4 q2 = *(const u16x4*)(qp + 16 + g * 4);
            float p = 0.f;
            #pragma unroll
            for (int r = 0; r < 4; ++r)
                p += b2f(q1[r]) * klo[r] + b2f(q2[r]) * khi[r];
            p += __shfl_xor(p, 16, 64);
            p += __shfl_xor(p, 32, 64);
            if (slot >= 0) {
                if (g == 0) SC[(size_t)slot * 4 + h] = p * 0.17677669529663687f;
                u16x4 plo, phi;
                #pragma unroll
                for (int r = 0; r < 4; ++r) { plo[r] = f2b(vlo[r]); phi[r] = f2b(vhi[r]); }
                __hip_bfloat16* dst = VPh + (size_t)slot * 64 + hl * 32;
                *(u16x4*)(dst + g * 4) = plo;
                *(u16x4*)(dst + 16 + g * 4) = phi;
            }
        }
    }
}

// ---------- node pass (per head-pair ROUND): start-boundary convention ----------
template <int ROUND>
__global__ __launch_bounds__(256) void node_pass(
    const float* __restrict__ SC, const __hip_bfloat16* __restrict__ VPh,
    const unsigned* __restrict__ estart, __hip_bfloat16* __restrict__ M, int n, int Etot)
{
    int node = (blockIdx.x * 256 + threadIdx.x) >> 6;
    if (node >= n) return;
    int l = threadIdx.x & 63;
    int half = l >> 5;
    const int h = ROUND * 2 + half;
    unsigned beg = estart[node];
    unsigned end = (node + 1 < n) ? estart[node + 1] : (unsigned)Etot;
    float mx = -INFINITY, dn = 0.f;
    for (unsigned j = beg; j < end; ++j) {
        float s = SC[(size_t)j * 4 + h];
        float m2 = fmaxf(mx, s);
        dn = dn * __expf(mx - m2) + __expf(s - m2);
        mx = m2;
    }
    float inv = (end > beg) ? 1.f / dn : 0.f;
    float acc = 0.f;
    for (unsigned j = beg; j < end; ++j) {
        float w = __expf(SC[(size_t)j * 4 + h] - mx) * inv;
        acc = fmaf(w, __bfloat162float(VPh[(size_t)j * 64 + l]), acc);
    }
    M[(size_t)node * 128 + ROUND * 64 + l] = __float2bfloat16(acc);
}

// ---------- per-user gather: 2 users/wave, unroll-4, int2 pairs ----------
__global__ __launch_bounds__(256) void user_gather(
    const __hip_bfloat16* __restrict__ embb, const unsigned* __restrict__ ustart,
    const int2* __restrict__ upair, float* __restrict__ out, int nu, int NNZ)
{
    int u = (blockIdx.x * 256 + threadIdx.x) >> 5;
    if (u >= nu) return;
    int l = threadIdx.x & 31;
    unsigned beg = ustart[u];
    unsigned end = (u + 1 < nu) ? ustart[u + 1] : (unsigned)NNZ;
    float a0 = 0.f, a1 = 0.f, a2 = 0.f, a3 = 0.f;
    float b0 = 0.f, b1 = 0.f, b2 = 0.f, b3 = 0.f;
    unsigned j = beg;
    for (; j + 3 < end; j += 4) {
        int2 p0 = upair[j], p1 = upair[j + 1], p2 = upair[j + 2], p3 = upair[j + 3];
        float v0 = __int_as_float(p0.y), v1 = __int_as_float(p1.y);
        float v2 = __int_as_float(p2.y), v3 = __int_as_float(p3.y);
        uint2 e0 = *(const uint2*)((const unsigned*)(embb + (size_t)p0.x * 128) + l * 2);
        uint2 e1 = *(const uint2*)((const unsigned*)(embb + (size_t)p1.x * 128) + l * 2);
        uint2 e2 = *(const uint2*)((const unsigned*)(embb + (size_t)p2.x * 128) + l * 2);
        uint2 e3 = *(const uint2*)((const unsigned*)(embb + (size_t)p3.x * 128) + l * 2);
        a0 = fmaf(b2f((unsigned short)(e0.x & 0xFFFF)), v0, a0);
        a1 = fmaf(b2f((unsigned short)(e0.x >> 16)), v0, a1);
        a2 = fmaf(b2f((unsigned short)(e0.y & 0xFFFF)), v0, a2);
        a3 = fmaf(b2f((unsigned short)(e0.y >> 16)), v0, a3);
        b0 = fmaf(b2f((unsigned short)(e1.x & 0xFFFF)), v1, b0);
        b1 = fmaf(b2f((unsigned short)(e1.x >> 16)), v1, b1);
        b2 = fmaf(b2f((unsigned short)(e1.y & 0xFFFF)), v1, b2);
        b3 = fmaf(b2f((unsigned short)(e1.y >> 16)), v1, b3);
        a0 = fmaf(b2f((unsigned short)(e2.x & 0xFFFF)), v2, a0);
        a1 = fmaf(b2f((unsigned short)(e2.x >> 16)), v2, a1);
        a2 = fmaf(b2f((unsigned short)(e2.y & 0xFFFF)), v2, a2);
        a3 = fmaf(b2f((unsigned short)(e2.y >> 16)), v2, a3);
        b0 = fmaf(b2f((unsigned short)(e3.x & 0xFFFF)), v3, b0);
        b1 = fmaf(b2f((unsigned short)(e3.x >> 16)), v3, b1);
        b2 = fmaf(b2f((unsigned short)(e3.y & 0xFFFF)), v3, b2);
        b3 = fmaf(b2f((unsigned short)(e3.y >> 16)), v3, b3);
    }
    for (; j < end; ++j) {
        int2 p0 = upair[j];
        float v0 = __int_as_float(p0.y);
        uint2 e0 = *(const uint2*)((const unsigned*)(embb + (size_t)p0.x * 128) + l * 2);
        a0 = fmaf(b2f((unsigned short)(e0.x & 0xFFFF)), v0, a0);
        a1 = fmaf(b2f((unsigned short)(e0.x >> 16)), v0, a1);
        a2 = fmaf(b2f((unsigned short)(e0.y & 0xFFFF)), v0, a2);
        a3 = fmaf(b2f((unsigned short)(e0.y >> 16)), v0, a3);
    }
    *(float4*)(out + (size_t)u * 128 + l * 4) =
        make_float4(a0 + b0, a1 + b1, a2 + b2, a3 + b3);
}

extern "C" void kernel_launch(void* const* d_in, const int* in_sizes, int n_in,
                              void* d_out, int out_size, void* d_ws, size_t ws_size,
                              hipStream_t stream)
{
    const float* emb = (const float*)d_in[0];
    const float* W_Q = (const float*)d_in[1];
    const float* W_K = (const float*)d_in[2];
    const float* W_V = (const float*)d_in[3];
    const float* W_O = (const float*)d_in[4];
    const float* att = (const float*)d_in[5];
    const float* msg = (const float*)d_in[6];
    const int* eidx  = (const int*)d_in[8];
    const int* etyp  = (const int*)d_in[9];
    const int* irow  = (const int*)d_in[10];
    const int* icol  = (const int*)d_in[11];
    const float* ival = (const float*)d_in[12];

    const int N    = in_sizes[0] / 128;
    const int E    = in_sizes[8] / 2;
    const int NNZ  = in_sizes[10];
    const int NU   = out_size / 128 - N;
    const int NREL = in_sizes[5] / 4096;

    const int* head = eidx;
    const int* tail = eidx + E;

    const int Np  = (N + 255) & ~255;
    const int NUp = (NU + 255) & ~255;

    // ---- d_ws layout (~162.4 MB; proven capacity >= 163.2 MB) ----
    const size_t NC = (size_t)N * 128;
    char* p = (char*)d_ws;
    __hip_bfloat16* VPh = (__hip_bfloat16*)p; p += (size_t)E * 64 * 2;  // 76.8 MB
    __hip_bfloat16* Kb  = (__hip_bfloat16*)p; p += NC * 2;              // 25.6 MB
    __hip_bfloat16* Vb  = (__hip_bfloat16*)p; p += NC * 2;              // 25.6 MB
    __hip_bfloat16* M   = (__hip_bfloat16*)p; p += NC * 2;              // 25.6 MB
    unsigned* rcnt  = (unsigned*)p; p += 32 * 4;
    unsigned* rcur  = (unsigned*)p; p += 32 * 4;
    unsigned* rend  = (unsigned*)p; p += 32 * 4;
    unsigned* rnext = (unsigned*)p; p += 32 * 4;
    unsigned* ucnt  = (unsigned*)p; p += (size_t)NUp * 4;   // exclusive starts
    unsigned* bsum  = (unsigned*)p; p += 1024 * 4;
    unsigned* bsumU = (unsigned*)p; p += 1024 * 4;
    int2* upair     = (int2*)p;     p += (size_t)NNZ * 8;   // (col, val) pairs
    __hip_bfloat16* WtQ = (__hip_bfloat16*)p; p += 16384 * 2;
    __hip_bfloat16* WtK = (__hip_bfloat16*)p; p += 16384 * 2;
    __hip_bfloat16* WtV = (__hip_bfloat16*)p; p += 16384 * 2;
    __hip_bfloat16* WtO = (__hip_bfloat16*)p; p += 16384 * 2;
    __hip_bfloat16* Atab = (__hip_bfloat16*)p; p += (size_t)NREL * 4096 * 2;
    __hip_bfloat16* Mtab = (__hip_bfloat16*)p; p += (size_t)NREL * 4096 * 2;

    // CSR-phase overlay inside VPh (dead until edge_pass):
    int* plocalU     = (int*)VPh;                      // NNZ
    int* plocalE     = plocalU + NNZ;                  // E
    unsigned* ucnt8  = (unsigned*)(plocalE + E);       // 8*NUp (becomes repbaseU)
    unsigned* ecnt8  = ucnt8 + (size_t)8 * NUp;        // 8*Np  (becomes repbaseE)

    // ---- d_out overlays (all regions fully rewritten by final kernels) ----
    float* out_ent = (float*)d_out;
    float* out_usr = out_ent + NC;
    __hip_bfloat16* embb = (__hip_bfloat16*)out_ent;                 // 25.6 MB
    __hip_bfloat16* Qb   = (__hip_bfloat16*)((char*)d_out + NC * 2); // 25.6 MB
    const long Emax = E + 512;
    float* SC   = out_usr;                                            // E*4 f32
    int4* emeta = (int4*)(out_usr + (size_t)E * 4);                   // Emax int4
    unsigned* ecnt = (unsigned*)((char*)emeta + (size_t)Emax * 16);   // N u32 (starts)

    hipMemsetAsync(rcnt, 0, 32 * 4, stream);
    hipMemsetAsync(ucnt8, 0, ((size_t)8 * NUp + (size_t)8 * Np) * 4, stream);

    // prep: weights, emb bf16, A/M frag tables
    trans_w4<<<256, 256, 0, stream>>>(W_Q, W_K, W_V, W_O, WtQ, WtK, WtV, WtO);
    conv_emb<<<(int)((NC / 4 + 255) / 256), 256, 0, stream>>>(emb, embb, (long)(NC / 4));
    conv_tab<<<(2 * NREL * 4096 + 255) / 256, 256, 0, stream>>>(att, msg, Atab, Mtab, NREL);

    // Q/K/V projections
    int gg = (N + 127) / 128;
    mfma_gemm<__hip_bfloat16><<<gg, 256, 0, stream>>>(embb, WtQ, Qb, N);
    mfma_gemm<__hip_bfloat16><<<gg, 256, 0, stream>>>(embb, WtK, Kb, N);
    mfma_gemm<__hip_bfloat16><<<gg, 256, 0, stream>>>(embb, WtV, Vb, N);

    // CSR build: one atomic pass, replicated counters, plocal record
    int gmax = ((NNZ > E ? NNZ : E) + 255) / 256;
    count_rec<<<gmax, 256, 0, stream>>>(head, etyp, irow, ecnt8, ucnt8, rcnt,
                                        plocalE, plocalU, E, NNZ, Np, NUp);
    rel_scan<<<1, 64, 0, stream>>>(rcnt, rcur, rend, rnext, NREL);
    fill_pads<<<1, 256, 0, stream>>>(rend, rnext, emeta, NREL, Emax);

    // totals -> exclusive scans -> per-replica bases
    sum_rep<<<(N + 255) / 256, 256, 0, stream>>>(ecnt8, ecnt, N, Np);
    sum_rep<<<(NU + 255) / 256, 256, 0, stream>>>(ucnt8, ucnt, NU, NUp);
    int nbE = (N + 1023) / 1024;
    scan1<<<nbE, 1024, 0, stream>>>(ecnt, ecnt, bsum, N);
    scan2<<<1, 1024, 0, stream>>>(bsum, nbE);
    scan3<<<nbE, 1024, 0, stream>>>(ecnt, bsum, N);
    int nbU = (NU + 1023) / 1024;
    scan1<<<nbU, 1024, 0, stream>>>(ucnt, ucnt, bsumU, NU);
    scan2<<<1, 1024, 0, stream>>>(bsumU, nbU);
    scan3<<<nbU, 1024, 0, stream>>>(ucnt, bsumU, NU);
    mk_repbase<<<(N + 255) / 256, 256, 0, stream>>>(ecnt8, ecnt, N, Np);
    mk_repbase<<<(NU + 255) / 256, 256, 0, stream>>>(ucnt8, ucnt, NU, NUp);

    // atomic-free fills (before edge_pass clobbers the VPh overlay)
    fill_user2<<<(NNZ + 255) / 256, 256, 0, stream>>>(irow, icol, ival, ucnt8,
                                                      plocalU, upair, NNZ, NUp);
    fill_both2<<<(E + 255) / 256, 256, 0, stream>>>(head, tail, etyp, ecnt8,
                                                    plocalE, rcur, emeta, E, Np);

    // fused edge + node passes (per head-pair)
    const int NWAVE = 16384;
    int chunk = (int)(((Emax + NWAVE - 1) / NWAVE + 15) & ~15L);
    edge_pass<0><<<NWAVE / 4, 256, 0, stream>>>(Qb, Kb, Vb, Atab, Mtab, emeta, SC, VPh, Emax, chunk);
    node_pass<0><<<(N + 3) / 4, 256, 0, stream>>>(SC, VPh, ecnt, M, N, E);
    edge_pass<1><<<NWAVE / 4, 256, 0, stream>>>(Qb, Kb, Vb, Atab, Mtab, emeta, SC, VPh, Emax, chunk);
    node_pass<1><<<(N + 3) / 4, 256, 0, stream>>>(SC, VPh, ecnt, M, N, E);

    // user aggregation (reads embb + upair; overwrites SC/emeta/ecnt = dead)
    user_gather<<<(NU + 7) / 8, 256, 0, stream>>>(embb, ucnt, upair, out_usr, NU, NNZ);

    // entity output GEMM last (overwrites embb+Qb region = dead)
    mfma_gemm<float><<<gg, 256, 0, stream>>>(M, WtO, out_ent, N);
}